// Round 1
// baseline (353.748 us; speedup 1.0000x reference)
//
#include <hip/hip_runtime.h>
#include <hip/hip_bf16.h>
#include <math.h>

// Problem constants (fixed by the reference)
constexpr int N_NODES = 10000;
constexpr int N_EDGES = 320000;
constexpr int IN_DIM  = 512;
constexpr int HID     = 64;
constexpr int H0      = 8;     // layer1 heads
constexpr int OUT_D   = 64;    // layer2 dim
constexpr float NEG_SLOPE = 0.2f;

// ---------------------------------------------------------------------------
// wave (64-lane) reductions
// ---------------------------------------------------------------------------
__device__ __forceinline__ float wred_max(float v) {
#pragma unroll
    for (int o = 32; o > 0; o >>= 1) v = fmaxf(v, __shfl_xor(v, o));
    return v;
}
__device__ __forceinline__ float wred_sum(float v) {
#pragma unroll
    for (int o = 32; o > 0; o >>= 1) v += __shfl_xor(v, o);
    return v;
}

__device__ __forceinline__ float lrelu(float x) {
    return x > 0.f ? x : NEG_SLOPE * x;
}
__device__ __forceinline__ float elu(float x) {
    return x > 0.f ? x : (expf(x) - 1.f);
}

// ---------------------------------------------------------------------------
// Tiled fp32 GEMM: C[M,N] = A[M,K] @ B[K,N].  BM=BN=64, BK=16, block=256,
// 4x4 microtile per thread. N and K must be multiples of 64/16; M guarded.
// ---------------------------------------------------------------------------
__global__ __launch_bounds__(256) void sgemm_kernel(
    const float* __restrict__ A, const float* __restrict__ B,
    float* __restrict__ C, int M, int N, int K) {
    constexpr int BM = 64, BN = 64, BK = 16;
    __shared__ float As[BK][BM + 4];
    __shared__ float Bs[BK][BN + 4];

    const int tid = threadIdx.x;
    const int block_m = blockIdx.x * BM;
    const int block_n = blockIdx.y * BN;

    // A-tile load mapping: 64 rows x 16 k; 1 float4 per thread
    const int a_row = tid >> 2;          // 0..63
    const int a_k   = (tid & 3) << 2;    // 0,4,8,12
    // B-tile load mapping: 16 k x 64 n; 1 float4 per thread
    const int b_k = tid >> 4;            // 0..15
    const int b_n = (tid & 15) << 2;     // 0..60

    const int ty = tid >> 4;             // 0..15 (m microtile)
    const int tx = tid & 15;             // 0..15 (n microtile)

    float acc[4][4];
#pragma unroll
    for (int i = 0; i < 4; i++)
#pragma unroll
        for (int j = 0; j < 4; j++) acc[i][j] = 0.f;

    for (int k0 = 0; k0 < K; k0 += BK) {
        const int gm = block_m + a_row;
        float4 av = make_float4(0.f, 0.f, 0.f, 0.f);
        if (gm < M) av = *(const float4*)&A[(size_t)gm * K + k0 + a_k];
        As[a_k + 0][a_row] = av.x;
        As[a_k + 1][a_row] = av.y;
        As[a_k + 2][a_row] = av.z;
        As[a_k + 3][a_row] = av.w;

        float4 bv = *(const float4*)&B[(size_t)(k0 + b_k) * N + block_n + b_n];
        *(float4*)&Bs[b_k][b_n] = bv;
        __syncthreads();

#pragma unroll
        for (int k = 0; k < BK; k++) {
            float4 a = *(const float4*)&As[k][ty * 4];
            float4 b = *(const float4*)&Bs[k][tx * 4];
            acc[0][0] += a.x * b.x; acc[0][1] += a.x * b.y; acc[0][2] += a.x * b.z; acc[0][3] += a.x * b.w;
            acc[1][0] += a.y * b.x; acc[1][1] += a.y * b.y; acc[1][2] += a.y * b.z; acc[1][3] += a.y * b.w;
            acc[2][0] += a.z * b.x; acc[2][1] += a.z * b.y; acc[2][2] += a.z * b.z; acc[2][3] += a.z * b.w;
            acc[3][0] += a.w * b.x; acc[3][1] += a.w * b.y; acc[3][2] += a.w * b.z; acc[3][3] += a.w * b.w;
        }
        __syncthreads();
    }

#pragma unroll
    for (int i = 0; i < 4; i++) {
        const int gm = block_m + ty * 4 + i;
        if (gm < M) {
            float4 v = make_float4(acc[i][0], acc[i][1], acc[i][2], acc[i][3]);
            *(float4*)&C[(size_t)gm * N + block_n + tx * 4] = v;
        }
    }
}

// ---------------------------------------------------------------------------
// el/er for layer1: feat (N,8,64) row-major; attn (8,64).
// One block per node; wave w handles heads w and w+4.
// ---------------------------------------------------------------------------
__global__ __launch_bounds__(256) void elr1_kernel(
    const float* __restrict__ feat, const float* __restrict__ al,
    const float* __restrict__ ar, float* __restrict__ el, float* __restrict__ er) {
    const int node = blockIdx.x;
    const int tid = threadIdx.x;
    const int wave = tid >> 6, lane = tid & 63;
#pragma unroll
    for (int j = 0; j < 2; j++) {
        const int h = wave + j * 4;
        const float f = feat[(size_t)node * 512 + h * 64 + lane];
        const float sl = wred_sum(f * al[h * 64 + lane]);
        const float sr = wred_sum(f * ar[h * 64 + lane]);
        if (lane == 0) {
            el[node * 8 + h] = sl;
            er[node * 8 + h] = sr;
        }
    }
}

// el/er for layer2: feat2 (N,64), attn (64). 4 nodes per block (1 per wave).
__global__ __launch_bounds__(256) void elr2_kernel(
    const float* __restrict__ feat, const float* __restrict__ al,
    const float* __restrict__ ar, float* __restrict__ el, float* __restrict__ er) {
    const int tid = threadIdx.x;
    const int wave = tid >> 6, lane = tid & 63;
    const int node = blockIdx.x * 4 + wave;
    if (node >= N_NODES) return;
    const float f = feat[(size_t)node * 64 + lane];
    const float sl = wred_sum(f * al[lane]);
    const float sr = wred_sum(f * ar[lane]);
    if (lane == 0) {
        el[node] = sl;
        er[node] = sr;
    }
}

// ---------------------------------------------------------------------------
// CSR build
// ---------------------------------------------------------------------------
__global__ void zero_counts_kernel(int* __restrict__ counts, int n) {
    const int i = blockIdx.x * 256 + threadIdx.x;
    if (i < n) counts[i] = 0;
}

__global__ void hist_kernel(const int* __restrict__ dst, int* __restrict__ counts, int e) {
    const int i = blockIdx.x * 256 + threadIdx.x;
    if (i < e) atomicAdd(&counts[dst[i]], 1);
}

// single-block exclusive/inclusive scan; writes offs[0..n] and cursor[0..n-1]
__global__ __launch_bounds__(1024) void scan_kernel(
    const int* __restrict__ counts, int* __restrict__ offs,
    int* __restrict__ cursor, int n) {
    __shared__ int tmp[1024];
    __shared__ int run_s;
    const int tid = threadIdx.x;
    if (tid == 0) run_s = 0;
    __syncthreads();
    for (int base = 0; base < n; base += 1024) {
        const int v = (base + tid < n) ? counts[base + tid] : 0;
        tmp[tid] = v;
        __syncthreads();
        for (int off = 1; off < 1024; off <<= 1) {
            const int t = (tid >= off) ? tmp[tid - off] : 0;
            __syncthreads();
            tmp[tid] += t;
            __syncthreads();
        }
        const int inc = tmp[tid];   // inclusive scan of this chunk
        const int run = run_s;
        if (base + tid < n) {
            offs[base + tid + 1] = run + inc;
            cursor[base + tid] = run + inc - v;
        }
        __syncthreads();
        if (tid == 1023) run_s = run + tmp[1023];
        __syncthreads();
    }
    if (tid == 0) offs[0] = 0;
}

__global__ void scatter_kernel(const int* __restrict__ src, const int* __restrict__ dst,
                               int* __restrict__ cursor, int* __restrict__ srcs, int e) {
    const int i = blockIdx.x * 256 + threadIdx.x;
    if (i < e) {
        const int d = dst[i];
        const int p = atomicAdd(&cursor[d], 1);
        srcs[p] = src[i];
    }
}

// ---------------------------------------------------------------------------
// Layer-1 aggregation: per dst node, edge-softmax over 8 heads, then
// out[dst,h,d] = sum_e alpha[e,h] * feat[src_e,h,d]; ELU; write (N,512).
// Block = 256 threads; thread owns flat dims tid and tid+256.
// ---------------------------------------------------------------------------
__global__ __launch_bounds__(256) void agg1_kernel(
    const float* __restrict__ feat, const float* __restrict__ el,
    const float* __restrict__ er, const int* __restrict__ offs,
    const int* __restrict__ srcs, float* __restrict__ xout) {
    constexpr int CH = 512;
    __shared__ int s_src[CH];
    __shared__ float s_alpha[CH * 8];
    __shared__ float s_red[4][8];
    __shared__ float s_m[8];
    __shared__ float s_inv[8];
    __shared__ float s_er[8];

    const int node = blockIdx.x;
    const int tid = threadIdx.x;
    const int wave = tid >> 6, lane = tid & 63;
    const int start = offs[node];
    const int deg = offs[node + 1] - start;

    if (deg == 0) {
        xout[(size_t)node * 512 + tid] = 0.f;
        xout[(size_t)node * 512 + 256 + tid] = 0.f;
        return;
    }
    if (tid < 8) s_er[tid] = er[node * 8 + tid];
    __syncthreads();

    // pass 1: per-head max
    float pm[8];
#pragma unroll
    for (int h = 0; h < 8; h++) pm[h] = -1e30f;
    for (int i = tid; i < deg; i += 256) {
        const int s = srcs[start + i];
        const float* elp = el + s * 8;
#pragma unroll
        for (int h = 0; h < 8; h++) {
            const float sc = lrelu(elp[h] + s_er[h]);
            pm[h] = fmaxf(pm[h], sc);
        }
    }
#pragma unroll
    for (int h = 0; h < 8; h++) pm[h] = wred_max(pm[h]);
    if (lane == 0) {
#pragma unroll
        for (int h = 0; h < 8; h++) s_red[wave][h] = pm[h];
    }
    __syncthreads();
    if (tid < 8) {
        s_m[tid] = fmaxf(fmaxf(s_red[0][tid], s_red[1][tid]),
                         fmaxf(s_red[2][tid], s_red[3][tid]));
    }
    __syncthreads();

    // pass 2: per-head sum of exp
    float ps[8];
#pragma unroll
    for (int h = 0; h < 8; h++) ps[h] = 0.f;
    for (int i = tid; i < deg; i += 256) {
        const int s = srcs[start + i];
        const float* elp = el + s * 8;
#pragma unroll
        for (int h = 0; h < 8; h++) {
            const float sc = lrelu(elp[h] + s_er[h]);
            ps[h] += __expf(sc - s_m[h]);
        }
    }
#pragma unroll
    for (int h = 0; h < 8; h++) ps[h] = wred_sum(ps[h]);
    if (lane == 0) {
#pragma unroll
        for (int h = 0; h < 8; h++) s_red[wave][h] = ps[h];
    }
    __syncthreads();
    if (tid < 8) {
        const float s = s_red[0][tid] + s_red[1][tid] + s_red[2][tid] + s_red[3][tid];
        s_inv[tid] = 1.f / s;
    }
    __syncthreads();

    // pass 3: weighted aggregation, chunked through LDS
    float acc0 = 0.f, acc1 = 0.f;
    const int h0 = tid >> 6;      // head of dim tid     (0..3)
    const int h1 = h0 + 4;        // head of dim tid+256 (4..7)
    for (int cs = 0; cs < deg; cs += CH) {
        const int n = min(CH, deg - cs);
        for (int i = tid; i < n; i += 256) s_src[i] = srcs[start + cs + i];
        __syncthreads();
        for (int idx = tid; idx < n * 8; idx += 256) {
            const int i = idx >> 3, h = idx & 7;
            const int s = s_src[i];
            const float sc = lrelu(el[s * 8 + h] + s_er[h]);
            s_alpha[idx] = __expf(sc - s_m[h]) * s_inv[h];
        }
        __syncthreads();
        for (int i = 0; i < n; i++) {
            const int s = s_src[i];
            const float* fp = feat + (size_t)s * 512;
            acc0 += s_alpha[i * 8 + h0] * fp[tid];
            acc1 += s_alpha[i * 8 + h1] * fp[256 + tid];
        }
        __syncthreads();
    }

    xout[(size_t)node * 512 + tid] = elu(acc0);
    xout[(size_t)node * 512 + 256 + tid] = elu(acc1);
}

// ---------------------------------------------------------------------------
// Layer-2 aggregation: 1 head, D=64. One wave (64-thread block) per node.
// Output written directly to d_out (mean over 1 head = identity).
// ---------------------------------------------------------------------------
__global__ __launch_bounds__(64) void agg2_kernel(
    const float* __restrict__ feat, const float* __restrict__ el,
    const float* __restrict__ er, const int* __restrict__ offs,
    const int* __restrict__ srcs, float* __restrict__ out) {
    constexpr int CH = 256;
    __shared__ int s_src[CH];
    __shared__ float s_alpha[CH];

    const int node = blockIdx.x;
    const int lane = threadIdx.x;
    const int start = offs[node];
    const int deg = offs[node + 1] - start;
    if (deg == 0) {
        out[(size_t)node * 64 + lane] = 0.f;
        return;
    }
    const float ern = er[node];

    float pm = -1e30f;
    for (int i = lane; i < deg; i += 64)
        pm = fmaxf(pm, lrelu(el[srcs[start + i]] + ern));
    pm = wred_max(pm);

    float ps = 0.f;
    for (int i = lane; i < deg; i += 64)
        ps += __expf(lrelu(el[srcs[start + i]] + ern) - pm);
    ps = wred_sum(ps);
    const float inv_s = 1.f / ps;

    float acc = 0.f;
    for (int cs = 0; cs < deg; cs += CH) {
        const int n = min(CH, deg - cs);
        for (int i = lane; i < n; i += 64) {
            const int s = srcs[start + cs + i];
            s_src[i] = s;
            s_alpha[i] = __expf(lrelu(el[s] + ern) - pm) * inv_s;
        }
        __syncthreads();
        for (int i = 0; i < n; i++)
            acc += s_alpha[i] * feat[(size_t)s_src[i] * 64 + lane];
        __syncthreads();
    }
    out[(size_t)node * 64 + lane] = acc;
}

// ---------------------------------------------------------------------------
extern "C" void kernel_launch(void* const* d_in, const int* in_sizes, int n_in,
                              void* d_out, int out_size, void* d_ws, size_t ws_size,
                              hipStream_t stream) {
    const float* h   = (const float*)d_in[0];
    const int*   src = (const int*)d_in[1];
    const int*   dst = (const int*)d_in[2];
    const float* W1  = (const float*)d_in[3];
    const float* al1 = (const float*)d_in[4];
    const float* ar1 = (const float*)d_in[5];
    const float* W2  = (const float*)d_in[6];
    const float* al2 = (const float*)d_in[7];
    const float* ar2 = (const float*)d_in[8];
    float* out = (float*)d_out;

    // workspace layout (floats / ints)
    float* feat1 = (float*)d_ws;                       // 10000*512
    float* x1    = feat1 + (size_t)N_NODES * 512;      // 10000*512
    float* feat2 = x1 + (size_t)N_NODES * 512;         // 10000*64
    float* el1   = feat2 + (size_t)N_NODES * 64;       // 10000*8
    float* er1   = el1 + N_NODES * 8;                  // 10000*8
    float* el2   = er1 + N_NODES * 8;                  // 10000
    float* er2   = el2 + N_NODES;                      // 10000
    int* counts  = (int*)(er2 + N_NODES);              // 10000
    int* offs    = counts + N_NODES;                   // 10001 (padded 10004)
    int* cursor  = offs + 10004;                       // 10000
    int* srcs    = cursor + N_NODES;                   // 320000

    // ---- CSR build ----
    zero_counts_kernel<<<(N_NODES + 255) / 256, 256, 0, stream>>>(counts, N_NODES);
    hist_kernel<<<(N_EDGES + 255) / 256, 256, 0, stream>>>(dst, counts, N_EDGES);
    scan_kernel<<<1, 1024, 0, stream>>>(counts, offs, cursor, N_NODES);
    scatter_kernel<<<(N_EDGES + 255) / 256, 256, 0, stream>>>(src, dst, cursor, srcs, N_EDGES);

    // ---- layer 1 ----
    {
        dim3 grid((N_NODES + 63) / 64, (H0 * HID) / 64);
        sgemm_kernel<<<grid, 256, 0, stream>>>(h, W1, feat1, N_NODES, H0 * HID, IN_DIM);
    }
    elr1_kernel<<<N_NODES, 256, 0, stream>>>(feat1, al1, ar1, el1, er1);
    agg1_kernel<<<N_NODES, 256, 0, stream>>>(feat1, el1, er1, offs, srcs, x1);

    // ---- layer 2 ----
    {
        dim3 grid((N_NODES + 63) / 64, OUT_D / 64);
        sgemm_kernel<<<grid, 256, 0, stream>>>(x1, W2, feat2, N_NODES, OUT_D, H0 * HID);
    }
    elr2_kernel<<<(N_NODES + 3) / 4, 256, 0, stream>>>(feat2, al2, ar2, el2, er2);
    agg2_kernel<<<N_NODES, 64, 0, stream>>>(feat2, el2, er2, offs, srcs, out);
}

// Round 2
// 306.703 us; speedup vs baseline: 1.1534x; 1.1534x over previous
//
#include <hip/hip_runtime.h>
#include <hip/hip_bf16.h>
#include <math.h>

typedef unsigned int u32;
typedef unsigned short ushort;

constexpr int N_NODES = 10000;
constexpr int N_EDGES = 320000;
constexpr int IN_DIM  = 512;
constexpr int HID     = 64;
constexpr int H0      = 8;
constexpr int OUT_D   = 64;
constexpr float NEG_SLOPE = 0.2f;

typedef __attribute__((ext_vector_type(8))) short short8;   // 8 x bf16 bits
typedef __attribute__((ext_vector_type(4))) float f32x4;

// ---------------------------------------------------------------------------
// helpers
// ---------------------------------------------------------------------------
__device__ __forceinline__ float wred_max(float v) {
#pragma unroll
    for (int o = 32; o > 0; o >>= 1) v = fmaxf(v, __shfl_xor(v, o));
    return v;
}
__device__ __forceinline__ float wred_sum(float v) {
#pragma unroll
    for (int o = 32; o > 0; o >>= 1) v += __shfl_xor(v, o);
    return v;
}
__device__ __forceinline__ float lrelu(float x) { return x > 0.f ? x : NEG_SLOPE * x; }
__device__ __forceinline__ float elu(float x)   { return x > 0.f ? x : (expf(x) - 1.f); }

// bf16 (RNE) split helpers via bit ops (inputs are finite)
__device__ __forceinline__ ushort f2bf(float x) {
    u32 b = __float_as_uint(x);
    b += 0x7FFFu + ((b >> 16) & 1u);
    return (ushort)(b >> 16);
}
__device__ __forceinline__ float bf2f(ushort u) {
    return __uint_as_float(((u32)u) << 16);
}

// async global->LDS, 16B per lane; LDS dest = wave-uniform base + lane*16
__device__ __forceinline__ void gload16(const void* g, void* l) {
    __builtin_amdgcn_global_load_lds(
        (__attribute__((address_space(1))) void*)g,
        (__attribute__((address_space(3))) void*)l, 16, 0, 0);
}

// ---------------------------------------------------------------------------
// fp32 -> (bf16 hi, bf16 lo), elementwise, float4-vectorized. n % 4 == 0.
// ---------------------------------------------------------------------------
__global__ void split4_kernel(const float4* __restrict__ x, ushort* __restrict__ hi,
                              ushort* __restrict__ lo, int n4) {
    const int i = blockIdx.x * 256 + threadIdx.x;
    if (i >= n4) return;
    const float4 v = x[i];
    ushort h0 = f2bf(v.x), h1 = f2bf(v.y), h2 = f2bf(v.z), h3 = f2bf(v.w);
    ushort l0 = f2bf(v.x - bf2f(h0)), l1 = f2bf(v.y - bf2f(h1));
    ushort l2 = f2bf(v.z - bf2f(h2)), l3 = f2bf(v.w - bf2f(h3));
    *(ushort4*)&hi[i * 4] = make_ushort4(h0, h1, h2, h3);
    *(ushort4*)&lo[i * 4] = make_ushort4(l0, l1, l2, l3);
}

// W (K x N, row-major) -> Wt_hi/Wt_lo (N x K, row-major), split
__global__ void tsplit_kernel(const float* __restrict__ W, ushort* __restrict__ thi,
                              ushort* __restrict__ tlo, int K, int N) {
    const int idx = blockIdx.x * 256 + threadIdx.x;
    if (idx >= K * N) return;
    const int n = idx / K, k = idx % K;
    const float v = W[(size_t)k * N + n];
    const ushort h = f2bf(v);
    thi[idx] = h;
    tlo[idx] = f2bf(v - bf2f(h));
}

// ---------------------------------------------------------------------------
// bf16x3 MFMA GEMM: C[M,N] = A[M,K] @ B[K,N], A given as hi/lo (M x K),
// B given transposed as hi/lo (N x K). 256 threads, single-buffered LDS,
// global_load_lds width-16 staging (m97 structure). K % 32 == 0.
// ---------------------------------------------------------------------------
template<int BM, int BN, int WM, int WN>
__global__ __launch_bounds__(256) void gemm_bf16x3_kernel(
    const ushort* __restrict__ Ahi, const ushort* __restrict__ Alo,
    const ushort* __restrict__ Bhi, const ushort* __restrict__ Blo,
    float* __restrict__ C, int M, int N, int K) {
    constexpr int BK = 32;
    constexpr int MT_M = WM / 16, MT_N = WN / 16;
    constexpr int WAVES_N = BN / WN;
    constexpr int RA = (BM * BK * 2) / 4096;   // staging rounds for A tiles
    constexpr int RB = (BN * BK * 2) / 4096;

    __shared__ __align__(16) ushort sAhi[BM * BK];
    __shared__ __align__(16) ushort sAlo[BM * BK];
    __shared__ __align__(16) ushort sBhi[BN * BK];
    __shared__ __align__(16) ushort sBlo[BN * BK];

    const int tid = threadIdx.x;
    const int wave = tid >> 6, lane = tid & 63;
    const int m0 = blockIdx.x * BM, n0 = blockIdx.y * BN;
    const int wm = wave / WAVES_N, wn = wave % WAVES_N;
    const int quad = lane >> 4, l15 = lane & 15;

    const int fb = wave * 1024 + lane * 16;  // flat byte offset, round 0

    size_t abyte[RA];
#pragma unroll
    for (int r = 0; r < RA; r++) {
        const int f = fb + r * 4096;
        int grow = m0 + (f >> 6);
        if (grow > M - 1) grow = M - 1;          // clamp: no OOB, rows discarded later
        abyte[r] = (size_t)grow * (K * 2) + (f & 63);
    }
    size_t bbyte[RB];
#pragma unroll
    for (int r = 0; r < RB; r++) {
        const int f = fb + r * 4096;
        bbyte[r] = (size_t)(n0 + (f >> 6)) * (K * 2) + (f & 63);
    }

    f32x4 acc[MT_M][MT_N] = {};

    for (int k0 = 0; k0 < K; k0 += BK) {
        __syncthreads();
        const size_t kb = (size_t)k0 * 2;
#pragma unroll
        for (int r = 0; r < RA; r++) {
            const int f = fb + r * 4096;
            gload16((const char*)Ahi + abyte[r] + kb, (char*)sAhi + f);
            gload16((const char*)Alo + abyte[r] + kb, (char*)sAlo + f);
        }
#pragma unroll
        for (int r = 0; r < RB; r++) {
            const int f = fb + r * 4096;
            gload16((const char*)Bhi + bbyte[r] + kb, (char*)sBhi + f);
            gload16((const char*)Blo + bbyte[r] + kb, (char*)sBlo + f);
        }
        __syncthreads();

        short8 ah[MT_M], al[MT_M], bh[MT_N], bl[MT_N];
#pragma unroll
        for (int mi = 0; mi < MT_M; mi++) {
            const int row = wm * WM + mi * 16 + l15;
            ah[mi] = *(const short8*)&sAhi[row * BK + quad * 8];
            al[mi] = *(const short8*)&sAlo[row * BK + quad * 8];
        }
#pragma unroll
        for (int ni = 0; ni < MT_N; ni++) {
            const int row = wn * WN + ni * 16 + l15;
            bh[ni] = *(const short8*)&sBhi[row * BK + quad * 8];
            bl[ni] = *(const short8*)&sBlo[row * BK + quad * 8];
        }
#pragma unroll
        for (int mi = 0; mi < MT_M; mi++)
#pragma unroll
            for (int ni = 0; ni < MT_N; ni++) {
                acc[mi][ni] = __builtin_amdgcn_mfma_f32_16x16x32_bf16(ah[mi], bh[ni], acc[mi][ni], 0, 0, 0);
                acc[mi][ni] = __builtin_amdgcn_mfma_f32_16x16x32_bf16(ah[mi], bl[ni], acc[mi][ni], 0, 0, 0);
                acc[mi][ni] = __builtin_amdgcn_mfma_f32_16x16x32_bf16(al[mi], bh[ni], acc[mi][ni], 0, 0, 0);
            }
    }

    // epilogue: D row = (lane>>4)*4 + reg, col = lane&15  [verified m89/m91]
#pragma unroll
    for (int mi = 0; mi < MT_M; mi++) {
#pragma unroll
        for (int r = 0; r < 4; r++) {
            const int grow = m0 + wm * WM + mi * 16 + quad * 4 + r;
            if (grow < M) {
#pragma unroll
                for (int ni = 0; ni < MT_N; ni++) {
                    const int gcol = n0 + wn * WN + ni * 16 + l15;
                    C[(size_t)grow * N + gcol] = acc[mi][ni][r];
                }
            }
        }
    }
}

// ---------------------------------------------------------------------------
// el/er layer1: feat (N,8,64); one block per node, wave w -> heads w, w+4
// ---------------------------------------------------------------------------
__global__ __launch_bounds__(256) void elr1_kernel(
    const float* __restrict__ feat, const float* __restrict__ al,
    const float* __restrict__ ar, float* __restrict__ el, float* __restrict__ er) {
    const int node = blockIdx.x;
    const int tid = threadIdx.x;
    const int wave = tid >> 6, lane = tid & 63;
#pragma unroll
    for (int j = 0; j < 2; j++) {
        const int h = wave + j * 4;
        const float f = feat[(size_t)node * 512 + h * 64 + lane];
        const float sl = wred_sum(f * al[h * 64 + lane]);
        const float sr = wred_sum(f * ar[h * 64 + lane]);
        if (lane == 0) { el[node * 8 + h] = sl; er[node * 8 + h] = sr; }
    }
}

__global__ __launch_bounds__(256) void elr2_kernel(
    const float* __restrict__ feat, const float* __restrict__ al,
    const float* __restrict__ ar, float* __restrict__ el, float* __restrict__ er) {
    const int tid = threadIdx.x;
    const int wave = tid >> 6, lane = tid & 63;
    const int node = blockIdx.x * 4 + wave;
    if (node >= N_NODES) return;
    const float f = feat[(size_t)node * 64 + lane];
    const float sl = wred_sum(f * al[lane]);
    const float sr = wred_sum(f * ar[lane]);
    if (lane == 0) { el[node] = sl; er[node] = sr; }
}

// ---------------------------------------------------------------------------
// CSR build
// ---------------------------------------------------------------------------
__global__ void zero_counts_kernel(int* __restrict__ counts, int n) {
    const int i = blockIdx.x * 256 + threadIdx.x;
    if (i < n) counts[i] = 0;
}

__global__ void hist_kernel(const int* __restrict__ dst, int* __restrict__ counts, int e) {
    const int i = blockIdx.x * 256 + threadIdx.x;
    if (i < e) atomicAdd(&counts[dst[i]], 1);
}

// fast single-block scan: 10 elems/thread in regs, wave shfl-scan, 1 LDS level
__global__ __launch_bounds__(1024) void scan_kernel(
    const int* __restrict__ counts, int* __restrict__ offs,
    int* __restrict__ cursor, int n) {
    __shared__ int wsum[16];
    const int tid = threadIdx.x;
    const int lane = tid & 63, wave = tid >> 6;
    const int base = tid * 10;
    int v[10];
    int s = 0;
#pragma unroll
    for (int i = 0; i < 10; i++) {
        v[i] = (base + i < n) ? counts[base + i] : 0;
        s += v[i];
    }
    int ps = s;  // inclusive wave scan of per-thread sums
#pragma unroll
    for (int o = 1; o < 64; o <<= 1) {
        const int t = __shfl_up(ps, o);
        if (lane >= o) ps += t;
    }
    if (lane == 63) wsum[wave] = ps;
    __syncthreads();
    if (tid < 16) {
        int t = wsum[tid];
#pragma unroll
        for (int o = 1; o < 16; o <<= 1) {
            const int u = __shfl_up(t, o);
            if (tid >= o) t += u;
        }
        wsum[tid] = t;
    }
    __syncthreads();
    const int wbase = (wave > 0) ? wsum[wave - 1] : 0;
    int run = wbase + ps - s;  // exclusive prefix of this thread's chunk
#pragma unroll
    for (int i = 0; i < 10; i++) {
        if (base + i < n) {
            cursor[base + i] = run;
            offs[base + i + 1] = run + v[i];
        }
        run += v[i];
    }
    if (tid == 0) offs[0] = 0;
}

__global__ void scatter_kernel(const int* __restrict__ src, const int* __restrict__ dst,
                               int* __restrict__ cursor, int* __restrict__ srcs, int e) {
    const int i = blockIdx.x * 256 + threadIdx.x;
    if (i < e) {
        const int d = dst[i];
        const int p = atomicAdd(&cursor[d], 1);
        srcs[p] = src[i];
    }
}

// ---------------------------------------------------------------------------
// Layer-1 aggregation. Thread owns float2 dims [2t, 2t+1]; writes bf16 hi/lo
// (x1 is consumed only by the bf16x3 GEMM of layer 2).
// ---------------------------------------------------------------------------
__global__ __launch_bounds__(256) void agg1_kernel(
    const float* __restrict__ feat, const float* __restrict__ el,
    const float* __restrict__ er, const int* __restrict__ offs,
    const int* __restrict__ srcs, ushort* __restrict__ xhi, ushort* __restrict__ xlo) {
    constexpr int CH = 512;
    __shared__ int s_src[CH];
    __shared__ float s_alpha[CH * 8];
    __shared__ float s_red[4][8];
    __shared__ float s_m[8];
    __shared__ float s_inv[8];
    __shared__ float s_er[8];

    const int node = blockIdx.x;
    const int tid = threadIdx.x;
    const int wave = tid >> 6, lane = tid & 63;
    const int start = offs[node];
    const int deg = offs[node + 1] - start;
    const int t2 = tid * 2;

    if (deg == 0) {
        xhi[(size_t)node * 512 + t2] = 0; xhi[(size_t)node * 512 + t2 + 1] = 0;
        xlo[(size_t)node * 512 + t2] = 0; xlo[(size_t)node * 512 + t2 + 1] = 0;
        return;
    }
    if (tid < 8) s_er[tid] = er[node * 8 + tid];
    __syncthreads();

    // pass 1: per-head max
    float pm[8];
#pragma unroll
    for (int h = 0; h < 8; h++) pm[h] = -1e30f;
    for (int i = tid; i < deg; i += 256) {
        const int s = srcs[start + i];
        const float4 e0 = *(const float4*)&el[s * 8];
        const float4 e1 = *(const float4*)&el[s * 8 + 4];
        pm[0] = fmaxf(pm[0], lrelu(e0.x + s_er[0]));
        pm[1] = fmaxf(pm[1], lrelu(e0.y + s_er[1]));
        pm[2] = fmaxf(pm[2], lrelu(e0.z + s_er[2]));
        pm[3] = fmaxf(pm[3], lrelu(e0.w + s_er[3]));
        pm[4] = fmaxf(pm[4], lrelu(e1.x + s_er[4]));
        pm[5] = fmaxf(pm[5], lrelu(e1.y + s_er[5]));
        pm[6] = fmaxf(pm[6], lrelu(e1.z + s_er[6]));
        pm[7] = fmaxf(pm[7], lrelu(e1.w + s_er[7]));
    }
#pragma unroll
    for (int h = 0; h < 8; h++) pm[h] = wred_max(pm[h]);
    if (lane == 0) {
#pragma unroll
        for (int h = 0; h < 8; h++) s_red[wave][h] = pm[h];
    }
    __syncthreads();
    if (tid < 8)
        s_m[tid] = fmaxf(fmaxf(s_red[0][tid], s_red[1][tid]),
                         fmaxf(s_red[2][tid], s_red[3][tid]));
    __syncthreads();

    // pass 2: per-head sum of exp
    float ps[8];
#pragma unroll
    for (int h = 0; h < 8; h++) ps[h] = 0.f;
    for (int i = tid; i < deg; i += 256) {
        const int s = srcs[start + i];
        const float4 e0 = *(const float4*)&el[s * 8];
        const float4 e1 = *(const float4*)&el[s * 8 + 4];
        ps[0] += __expf(lrelu(e0.x + s_er[0]) - s_m[0]);
        ps[1] += __expf(lrelu(e0.y + s_er[1]) - s_m[1]);
        ps[2] += __expf(lrelu(e0.z + s_er[2]) - s_m[2]);
        ps[3] += __expf(lrelu(e0.w + s_er[3]) - s_m[3]);
        ps[4] += __expf(lrelu(e1.x + s_er[4]) - s_m[4]);
        ps[5] += __expf(lrelu(e1.y + s_er[5]) - s_m[5]);
        ps[6] += __expf(lrelu(e1.z + s_er[6]) - s_m[6]);
        ps[7] += __expf(lrelu(e1.w + s_er[7]) - s_m[7]);
    }
#pragma unroll
    for (int h = 0; h < 8; h++) ps[h] = wred_sum(ps[h]);
    if (lane == 0) {
#pragma unroll
        for (int h = 0; h < 8; h++) s_red[wave][h] = ps[h];
    }
    __syncthreads();
    if (tid < 8)
        s_inv[tid] = 1.f / (s_red[0][tid] + s_red[1][tid] + s_red[2][tid] + s_red[3][tid]);
    __syncthreads();

    // pass 3: weighted aggregation (float2 per thread)
    float2 acc2 = make_float2(0.f, 0.f);
    const int hh = t2 >> 6;   // head of both dims (t2 even, same 64-block)
    for (int cs = 0; cs < deg; cs += CH) {
        const int n = min(CH, deg - cs);
        for (int i = tid; i < n; i += 256) s_src[i] = srcs[start + cs + i];
        __syncthreads();
        for (int idx = tid; idx < n * 8; idx += 256) {
            const int i = idx >> 3, h = idx & 7;
            const int s = s_src[i];
            const float sc = lrelu(el[s * 8 + h] + s_er[h]);
            s_alpha[idx] = __expf(sc - s_m[h]) * s_inv[h];
        }
        __syncthreads();
#pragma unroll 2
        for (int i = 0; i < n; i++) {
            const float a = s_alpha[i * 8 + hh];
            const float2 f = *(const float2*)&feat[(size_t)s_src[i] * 512 + t2];
            acc2.x += a * f.x;
            acc2.y += a * f.y;
        }
        __syncthreads();
    }

    const float o0 = elu(acc2.x), o1 = elu(acc2.y);
    const ushort h0 = f2bf(o0), h1 = f2bf(o1);
    xhi[(size_t)node * 512 + t2] = h0;
    xhi[(size_t)node * 512 + t2 + 1] = h1;
    xlo[(size_t)node * 512 + t2] = f2bf(o0 - bf2f(h0));
    xlo[(size_t)node * 512 + t2 + 1] = f2bf(o1 - bf2f(h1));
}

// ---------------------------------------------------------------------------
// Layer-2 aggregation: 1 head, D=64; one wave per node; writes d_out.
// ---------------------------------------------------------------------------
__global__ __launch_bounds__(64) void agg2_kernel(
    const float* __restrict__ feat, const float* __restrict__ el,
    const float* __restrict__ er, const int* __restrict__ offs,
    const int* __restrict__ srcs, float* __restrict__ out) {
    constexpr int CH = 256;
    __shared__ int s_src[CH];
    __shared__ float s_alpha[CH];

    const int node = blockIdx.x;
    const int lane = threadIdx.x;
    const int start = offs[node];
    const int deg = offs[node + 1] - start;
    if (deg == 0) { out[(size_t)node * 64 + lane] = 0.f; return; }
    const float ern = er[node];

    float pm = -1e30f;
    for (int i = lane; i < deg; i += 64)
        pm = fmaxf(pm, lrelu(el[srcs[start + i]] + ern));
    pm = wred_max(pm);

    float ps = 0.f;
    for (int i = lane; i < deg; i += 64)
        ps += __expf(lrelu(el[srcs[start + i]] + ern) - pm);
    ps = wred_sum(ps);
    const float inv_s = 1.f / ps;

    float acc = 0.f;
    for (int cs = 0; cs < deg; cs += CH) {
        const int n = min(CH, deg - cs);
        for (int i = lane; i < n; i += 64) {
            const int s = srcs[start + cs + i];
            s_src[i] = s;
            s_alpha[i] = __expf(lrelu(el[s] + ern) - pm) * inv_s;
        }
        __syncthreads();
#pragma unroll 2
        for (int i = 0; i < n; i++)
            acc += s_alpha[i] * feat[(size_t)s_src[i] * 64 + lane];
        __syncthreads();
    }
    out[(size_t)node * 64 + lane] = acc;
}

// ---------------------------------------------------------------------------
extern "C" void kernel_launch(void* const* d_in, const int* in_sizes, int n_in,
                              void* d_out, int out_size, void* d_ws, size_t ws_size,
                              hipStream_t stream) {
    const float* h   = (const float*)d_in[0];
    const int*   src = (const int*)d_in[1];
    const int*   dst = (const int*)d_in[2];
    const float* W1  = (const float*)d_in[3];
    const float* al1 = (const float*)d_in[4];
    const float* ar1 = (const float*)d_in[5];
    const float* W2  = (const float*)d_in[6];
    const float* al2 = (const float*)d_in[7];
    const float* ar2 = (const float*)d_in[8];
    float* out = (float*)d_out;

    // workspace carve (all chunks 16B-aligned)
    char* p = (char*)d_ws;
    float* feat1 = (float*)p;  p += (size_t)N_NODES * 512 * 4;   // 20.48 MB
    float* feat2 = (float*)p;  p += (size_t)N_NODES * 64 * 4;    // 2.56 MB
    float* el1   = (float*)p;  p += (size_t)N_NODES * 8 * 4;
    float* er1   = (float*)p;  p += (size_t)N_NODES * 8 * 4;
    float* el2   = (float*)p;  p += (size_t)N_NODES * 4;
    float* er2   = (float*)p;  p += (size_t)N_NODES * 4;
    ushort* xhi  = (ushort*)p; p += (size_t)N_NODES * 512 * 2;   // h_hi, reused as x1_hi
    ushort* xlo  = (ushort*)p; p += (size_t)N_NODES * 512 * 2;   // h_lo, reused as x1_lo
    ushort* w1thi = (ushort*)p; p += (size_t)512 * 512 * 2;
    ushort* w1tlo = (ushort*)p; p += (size_t)512 * 512 * 2;
    ushort* w2thi = (ushort*)p; p += (size_t)64 * 512 * 2;
    ushort* w2tlo = (ushort*)p; p += (size_t)64 * 512 * 2;
    int* counts  = (int*)p;    p += (size_t)N_NODES * 4;
    int* offs    = (int*)p;    p += (size_t)10004 * 4;
    int* cursor  = (int*)p;    p += (size_t)N_NODES * 4;
    int* srcs    = (int*)p;    p += (size_t)N_EDGES * 4;

    // ---- conversions ----
    split4_kernel<<<(N_NODES * 512 / 4 + 255) / 256, 256, 0, stream>>>(
        (const float4*)h, xhi, xlo, N_NODES * 512 / 4);
    tsplit_kernel<<<(512 * 512 + 255) / 256, 256, 0, stream>>>(W1, w1thi, w1tlo, 512, 512);
    tsplit_kernel<<<(512 * 64 + 255) / 256, 256, 0, stream>>>(W2, w2thi, w2tlo, 512, 64);

    // ---- CSR build ----
    zero_counts_kernel<<<(N_NODES + 255) / 256, 256, 0, stream>>>(counts, N_NODES);
    hist_kernel<<<(N_EDGES + 255) / 256, 256, 0, stream>>>(dst, counts, N_EDGES);
    scan_kernel<<<1, 1024, 0, stream>>>(counts, offs, cursor, N_NODES);
    scatter_kernel<<<(N_EDGES + 255) / 256, 256, 0, stream>>>(src, dst, cursor, srcs, N_EDGES);

    // ---- layer 1 ----
    {
        dim3 grid((N_NODES + 127) / 128, 512 / 128);
        gemm_bf16x3_kernel<128, 128, 64, 64><<<grid, 256, 0, stream>>>(
            xhi, xlo, w1thi, w1tlo, feat1, N_NODES, 512, 512);
    }
    elr1_kernel<<<N_NODES, 256, 0, stream>>>(feat1, al1, ar1, el1, er1);
    agg1_kernel<<<N_NODES, 256, 0, stream>>>(feat1, el1, er1, offs, srcs, xhi, xlo);

    // ---- layer 2 ----
    {
        dim3 grid((N_NODES + 127) / 128, 1);
        gemm_bf16x3_kernel<128, 64, 64, 32><<<grid, 256, 0, stream>>>(
            xhi, xlo, w2thi, w2tlo, feat2, N_NODES, 64, 512);
    }
    elr2_kernel<<<(N_NODES + 3) / 4, 256, 0, stream>>>(feat2, al2, ar2, el2, er2);
    agg2_kernel<<<N_NODES, 64, 0, stream>>>(feat2, el2, er2, offs, srcs, out);
}

// Round 3
// 259.223 us; speedup vs baseline: 1.3646x; 1.1832x over previous
//
#include <hip/hip_runtime.h>
#include <hip/hip_bf16.h>
#include <math.h>

typedef unsigned int u32;
typedef unsigned short ushort;

constexpr int N_NODES = 10000;
constexpr int N_EDGES = 320000;
constexpr float NEG_SLOPE = 0.2f;

typedef __attribute__((ext_vector_type(8))) short short8;   // 8 x bf16 bits
typedef __attribute__((ext_vector_type(4))) float f32x4;

// ---------------------------------------------------------------------------
// helpers
// ---------------------------------------------------------------------------
__device__ __forceinline__ float lrelu(float x) { return x > 0.f ? x : NEG_SLOPE * x; }
__device__ __forceinline__ float elu(float x)   { return x > 0.f ? x : (expf(x) - 1.f); }

// bf16 (RNE) split helpers via bit ops (inputs are finite)
__device__ __forceinline__ ushort f2bf(float x) {
    u32 b = __float_as_uint(x);
    b += 0x7FFFu + ((b >> 16) & 1u);
    return (ushort)(b >> 16);
}
__device__ __forceinline__ float bf2f(ushort u) {
    return __uint_as_float(((u32)u) << 16);
}

// async global->LDS, 16B per lane; LDS dest = wave-uniform base + lane*16
__device__ __forceinline__ void gload16(const void* g, void* l) {
    __builtin_amdgcn_global_load_lds(
        (__attribute__((address_space(1))) void*)g,
        (__attribute__((address_space(3))) void*)l, 16, 0, 0);
}

// ---------------------------------------------------------------------------
// fp32 -> (bf16 hi, bf16 lo) split (vectorized) + fused counts-zeroing tail.
// Blocks [0, nb_split) split; blocks [nb_split, ...) zero counts.
// ---------------------------------------------------------------------------
__global__ void split_zero_kernel(const float4* __restrict__ x, ushort* __restrict__ hi,
                                  ushort* __restrict__ lo, int n4, int nb_split,
                                  int* __restrict__ counts, int nc) {
    if ((int)blockIdx.x < nb_split) {
        const int i = blockIdx.x * 256 + threadIdx.x;
        if (i >= n4) return;
        const float4 v = x[i];
        ushort h0 = f2bf(v.x), h1 = f2bf(v.y), h2 = f2bf(v.z), h3 = f2bf(v.w);
        ushort l0 = f2bf(v.x - bf2f(h0)), l1 = f2bf(v.y - bf2f(h1));
        ushort l2 = f2bf(v.z - bf2f(h2)), l3 = f2bf(v.w - bf2f(h3));
        *(ushort4*)&hi[i * 4] = make_ushort4(h0, h1, h2, h3);
        *(ushort4*)&lo[i * 4] = make_ushort4(l0, l1, l2, l3);
    } else {
        const int j = ((int)blockIdx.x - nb_split) * 256 + threadIdx.x;
        if (j < nc) counts[j] = 0;
    }
}

// W (K x N, row-major) -> Wt_hi/Wt_lo (N x K, row-major), split
__global__ void tsplit_kernel(const float* __restrict__ W, ushort* __restrict__ thi,
                              ushort* __restrict__ tlo, int K, int N) {
    const int idx = blockIdx.x * 256 + threadIdx.x;
    if (idx >= K * N) return;
    const int n = idx / K, k = idx % K;
    const float v = W[(size_t)k * N + n];
    const ushort h = f2bf(v);
    thi[idx] = h;
    tlo[idx] = f2bf(v - bf2f(h));
}

// ---------------------------------------------------------------------------
// bf16x3 MFMA GEMM: C[M,N] = A[M,K] @ B[K,N]; A as hi/lo (M x K), B transposed
// hi/lo (N x K). Optional bf16 output. K % 32 == 0.
// ---------------------------------------------------------------------------
template<int BM, int BN, int WM, int WN, bool BF16OUT>
__global__ __launch_bounds__(256) void gemm_bf16x3_kernel(
    const ushort* __restrict__ Ahi, const ushort* __restrict__ Alo,
    const ushort* __restrict__ Bhi, const ushort* __restrict__ Blo,
    void* __restrict__ Cout, int M, int N, int K) {
    constexpr int BK = 32;
    constexpr int MT_M = WM / 16, MT_N = WN / 16;
    constexpr int WAVES_N = BN / WN;
    constexpr int RA = (BM * BK * 2) / 4096;
    constexpr int RB = (BN * BK * 2) / 4096;

    __shared__ __align__(16) ushort sAhi[BM * BK];
    __shared__ __align__(16) ushort sAlo[BM * BK];
    __shared__ __align__(16) ushort sBhi[BN * BK];
    __shared__ __align__(16) ushort sBlo[BN * BK];

    const int tid = threadIdx.x;
    const int wave = tid >> 6, lane = tid & 63;
    const int m0 = blockIdx.x * BM, n0 = blockIdx.y * BN;
    const int wm = wave / WAVES_N, wn = wave % WAVES_N;
    const int quad = lane >> 4, l15 = lane & 15;

    const int fb = wave * 1024 + lane * 16;

    size_t abyte[RA];
#pragma unroll
    for (int r = 0; r < RA; r++) {
        const int f = fb + r * 4096;
        int grow = m0 + (f >> 6);
        if (grow > M - 1) grow = M - 1;
        abyte[r] = (size_t)grow * (K * 2) + (f & 63);
    }
    size_t bbyte[RB];
#pragma unroll
    for (int r = 0; r < RB; r++) {
        const int f = fb + r * 4096;
        bbyte[r] = (size_t)(n0 + (f >> 6)) * (K * 2) + (f & 63);
    }

    f32x4 acc[MT_M][MT_N] = {};

    for (int k0 = 0; k0 < K; k0 += BK) {
        __syncthreads();
        const size_t kb = (size_t)k0 * 2;
#pragma unroll
        for (int r = 0; r < RA; r++) {
            const int f = fb + r * 4096;
            gload16((const char*)Ahi + abyte[r] + kb, (char*)sAhi + f);
            gload16((const char*)Alo + abyte[r] + kb, (char*)sAlo + f);
        }
#pragma unroll
        for (int r = 0; r < RB; r++) {
            const int f = fb + r * 4096;
            gload16((const char*)Bhi + bbyte[r] + kb, (char*)sBhi + f);
            gload16((const char*)Blo + bbyte[r] + kb, (char*)sBlo + f);
        }
        __syncthreads();

        short8 ah[MT_M], al[MT_M], bh[MT_N], bl[MT_N];
#pragma unroll
        for (int mi = 0; mi < MT_M; mi++) {
            const int row = wm * WM + mi * 16 + l15;
            ah[mi] = *(const short8*)&sAhi[row * BK + quad * 8];
            al[mi] = *(const short8*)&sAlo[row * BK + quad * 8];
        }
#pragma unroll
        for (int ni = 0; ni < MT_N; ni++) {
            const int row = wn * WN + ni * 16 + l15;
            bh[ni] = *(const short8*)&sBhi[row * BK + quad * 8];
            bl[ni] = *(const short8*)&sBlo[row * BK + quad * 8];
        }
#pragma unroll
        for (int mi = 0; mi < MT_M; mi++)
#pragma unroll
            for (int ni = 0; ni < MT_N; ni++) {
                acc[mi][ni] = __builtin_amdgcn_mfma_f32_16x16x32_bf16(ah[mi], bh[ni], acc[mi][ni], 0, 0, 0);
                acc[mi][ni] = __builtin_amdgcn_mfma_f32_16x16x32_bf16(ah[mi], bl[ni], acc[mi][ni], 0, 0, 0);
                acc[mi][ni] = __builtin_amdgcn_mfma_f32_16x16x32_bf16(al[mi], bh[ni], acc[mi][ni], 0, 0, 0);
            }
    }

    // epilogue: D row = (lane>>4)*4 + reg, col = lane&15  [verified m89/m91]
#pragma unroll
    for (int mi = 0; mi < MT_M; mi++) {
#pragma unroll
        for (int r = 0; r < 4; r++) {
            const int grow = m0 + wm * WM + mi * 16 + quad * 4 + r;
            if (grow < M) {
#pragma unroll
                for (int ni = 0; ni < MT_N; ni++) {
                    const int gcol = n0 + wn * WN + ni * 16 + l15;
                    if (BF16OUT)
                        ((ushort*)Cout)[(size_t)grow * N + gcol] = f2bf(acc[mi][ni][r]);
                    else
                        ((float*)Cout)[(size_t)grow * N + gcol] = acc[mi][ni][r];
                }
            }
        }
    }
}

// ---------------------------------------------------------------------------
// el/er layer1 from bf16 feat (N,512). Wave w: heads 2w (lanes 0-31) and
// 2w+1 (lanes 32-63); 32-lane butterfly reductions.
// ---------------------------------------------------------------------------
__global__ __launch_bounds__(256) void elr1_kernel(
    const ushort* __restrict__ feat, const float* __restrict__ al,
    const float* __restrict__ ar, float* __restrict__ el, float* __restrict__ er) {
    const int node = blockIdx.x;
    const int tid = threadIdx.x;
    const int wave = tid >> 6, lane = tid & 63;
    const int off = wave * 128 + lane * 2;
    const ushort2 u = *(const ushort2*)&feat[(size_t)node * 512 + off];
    const float f0 = bf2f(u.x), f1 = bf2f(u.y);
    float pl = f0 * al[off] + f1 * al[off + 1];
    float pr = f0 * ar[off] + f1 * ar[off + 1];
#pragma unroll
    for (int o = 1; o < 32; o <<= 1) {
        pl += __shfl_xor(pl, o);
        pr += __shfl_xor(pr, o);
    }
    const int h = wave * 2 + (lane >> 5);
    if ((lane & 31) == 0) {
        el[node * 8 + h] = pl;
        er[node * 8 + h] = pr;
    }
}

// el/er layer2: feat2 (N,64) fp32, attn (64). 4 nodes per block (1 per wave).
__global__ __launch_bounds__(256) void elr2_kernel(
    const float* __restrict__ feat, const float* __restrict__ al,
    const float* __restrict__ ar, float* __restrict__ el, float* __restrict__ er) {
    const int tid = threadIdx.x;
    const int wave = tid >> 6, lane = tid & 63;
    const int node = blockIdx.x * 4 + wave;
    if (node >= N_NODES) return;
    const float f = feat[(size_t)node * 64 + lane];
    float pl = f * al[lane];
    float pr = f * ar[lane];
#pragma unroll
    for (int o = 32; o > 0; o >>= 1) {
        pl += __shfl_xor(pl, o);
        pr += __shfl_xor(pr, o);
    }
    if (lane == 0) { el[node] = pl; er[node] = pr; }
}

// ---------------------------------------------------------------------------
// CSR build
// ---------------------------------------------------------------------------
__global__ void hist_kernel(const int* __restrict__ dst, int* __restrict__ counts, int e) {
    const int i = blockIdx.x * 256 + threadIdx.x;
    if (i < e) atomicAdd(&counts[dst[i]], 1);
}

// single-block scan: 10 elems/thread in regs, wave shfl-scan, 1 LDS level
__global__ __launch_bounds__(1024) void scan_kernel(
    const int* __restrict__ counts, int* __restrict__ offs,
    int* __restrict__ cursor, int n) {
    __shared__ int wsum[16];
    const int tid = threadIdx.x;
    const int lane = tid & 63, wave = tid >> 6;
    const int base = tid * 10;
    int v[10];
    int s = 0;
#pragma unroll
    for (int i = 0; i < 10; i++) {
        v[i] = (base + i < n) ? counts[base + i] : 0;
        s += v[i];
    }
    int ps = s;
#pragma unroll
    for (int o = 1; o < 64; o <<= 1) {
        const int t = __shfl_up(ps, o);
        if (lane >= o) ps += t;
    }
    if (lane == 63) wsum[wave] = ps;
    __syncthreads();
    if (tid < 16) {
        int t = wsum[tid];
#pragma unroll
        for (int o = 1; o < 16; o <<= 1) {
            const int u = __shfl_up(t, o);
            if (tid >= o) t += u;
        }
        wsum[tid] = t;
    }
    __syncthreads();
    const int wbase = (wave > 0) ? wsum[wave - 1] : 0;
    int run = wbase + ps - s;
#pragma unroll
    for (int i = 0; i < 10; i++) {
        if (base + i < n) {
            cursor[base + i] = run;
            offs[base + i + 1] = run + v[i];
        }
        run += v[i];
    }
    if (tid == 0) offs[0] = 0;
}

__global__ void scatter_kernel(const int* __restrict__ src, const int* __restrict__ dst,
                               int* __restrict__ cursor, int* __restrict__ srcs, int e) {
    const int i = blockIdx.x * 256 + threadIdx.x;
    if (i < e) {
        const int d = dst[i];
        const int p = atomicAdd(&cursor[d], 1);
        srcs[p] = src[i];
    }
}

// ---------------------------------------------------------------------------
// Layer-1 aggregation v3: no max pass (logits bounded), normalizer folded into
// the gather (ws accumulated per-thread). Gathers bf16 feat. One edge pass.
// ---------------------------------------------------------------------------
__global__ __launch_bounds__(256) void agg1_kernel(
    const ushort* __restrict__ feat, const float* __restrict__ el,
    const float* __restrict__ er, const int* __restrict__ offs,
    const int* __restrict__ srcs, ushort* __restrict__ xhi, ushort* __restrict__ xlo) {
    constexpr int CH = 512;
    __shared__ int s_src[CH];
    __shared__ float s_w[CH * 8];
    __shared__ float s_er[8];

    const int node = blockIdx.x;
    const int tid = threadIdx.x;
    const int start = offs[node];
    const int deg = offs[node + 1] - start;
    const int t2 = tid * 2;

    if (deg == 0) {
        *(ushort2*)&xhi[(size_t)node * 512 + t2] = make_ushort2(0, 0);
        *(ushort2*)&xlo[(size_t)node * 512 + t2] = make_ushort2(0, 0);
        return;
    }
    if (tid < 8) s_er[tid] = er[node * 8 + tid];

    float2 acc = make_float2(0.f, 0.f);
    float ws = 0.f;
    const int hh = t2 >> 6;   // head of this thread's dim pair

    for (int cs = 0; cs < deg; cs += CH) {
        const int n = min(CH, deg - cs);
        for (int i = tid; i < n; i += 256) s_src[i] = srcs[start + cs + i];
        __syncthreads();                       // also covers s_er (first iter)
        for (int idx = tid; idx < n * 8; idx += 256) {
            const int i = idx >> 3, h = idx & 7;
            s_w[idx] = __expf(lrelu(el[s_src[i] * 8 + h] + s_er[h]));
        }
        __syncthreads();
#pragma unroll 4
        for (int i = 0; i < n; i++) {
            const float a = s_w[i * 8 + hh];
            const ushort2 u = *(const ushort2*)&feat[(size_t)s_src[i] * 512 + t2];
            acc.x += a * bf2f(u.x);
            acc.y += a * bf2f(u.y);
            ws += a;
        }
        __syncthreads();
    }

    const float inv = 1.f / ws;
    const float o0 = elu(acc.x * inv), o1 = elu(acc.y * inv);
    const ushort h0 = f2bf(o0), h1 = f2bf(o1);
    *(ushort2*)&xhi[(size_t)node * 512 + t2] = make_ushort2(h0, h1);
    *(ushort2*)&xlo[(size_t)node * 512 + t2] =
        make_ushort2(f2bf(o0 - bf2f(h0)), f2bf(o1 - bf2f(h1)));
}

// ---------------------------------------------------------------------------
// Layer-2 aggregation v3: one wave per node (4 nodes / 256-block), no LDS,
// no barriers — w and src broadcast via shuffles; ws folded into the loop.
// ---------------------------------------------------------------------------
__global__ __launch_bounds__(256) void agg2_kernel(
    const float* __restrict__ feat, const float* __restrict__ el,
    const float* __restrict__ er, const int* __restrict__ offs,
    const int* __restrict__ srcs, float* __restrict__ out) {
    const int tid = threadIdx.x;
    const int wave = tid >> 6, lane = tid & 63;
    const int node = blockIdx.x * 4 + wave;
    if (node >= N_NODES) return;
    const int start = offs[node];
    const int deg = offs[node + 1] - start;
    if (deg == 0) { out[(size_t)node * 64 + lane] = 0.f; return; }
    const float ern = er[node];

    float acc = 0.f, ws = 0.f;
    for (int base = 0; base < deg; base += 64) {
        const int has = min(64, deg - base);
        int s = 0;
        float w = 0.f;
        if (lane < has) {
            s = srcs[start + base + lane];
            w = __expf(lrelu(el[s] + ern));
        }
        for (int j = 0; j < has; j++) {
            const float a = __shfl(w, j);
            const int sj = __shfl(s, j);
            acc += a * feat[(size_t)sj * 64 + lane];
            ws += a;
        }
    }
    out[(size_t)node * 64 + lane] = acc / ws;
}

// ---------------------------------------------------------------------------
extern "C" void kernel_launch(void* const* d_in, const int* in_sizes, int n_in,
                              void* d_out, int out_size, void* d_ws, size_t ws_size,
                              hipStream_t stream) {
    const float* h   = (const float*)d_in[0];
    const int*   src = (const int*)d_in[1];
    const int*   dst = (const int*)d_in[2];
    const float* W1  = (const float*)d_in[3];
    const float* al1 = (const float*)d_in[4];
    const float* ar1 = (const float*)d_in[5];
    const float* W2  = (const float*)d_in[6];
    const float* al2 = (const float*)d_in[7];
    const float* ar2 = (const float*)d_in[8];
    float* out = (float*)d_out;

    // workspace carve (16B-aligned chunks)
    char* p = (char*)d_ws;
    ushort* feat1bf = (ushort*)p; p += (size_t)N_NODES * 512 * 2;  // 10.24 MB
    float* feat2 = (float*)p;  p += (size_t)N_NODES * 64 * 4;      // 2.56 MB
    float* el1   = (float*)p;  p += (size_t)N_NODES * 8 * 4;
    float* er1   = (float*)p;  p += (size_t)N_NODES * 8 * 4;
    float* el2   = (float*)p;  p += (size_t)N_NODES * 4;
    float* er2   = (float*)p;  p += (size_t)N_NODES * 4;
    ushort* xhi  = (ushort*)p; p += (size_t)N_NODES * 512 * 2;     // h_hi, reused as x1_hi
    ushort* xlo  = (ushort*)p; p += (size_t)N_NODES * 512 * 2;     // h_lo, reused as x1_lo
    ushort* w1thi = (ushort*)p; p += (size_t)512 * 512 * 2;
    ushort* w1tlo = (ushort*)p; p += (size_t)512 * 512 * 2;
    ushort* w2thi = (ushort*)p; p += (size_t)64 * 512 * 2;
    ushort* w2tlo = (ushort*)p; p += (size_t)64 * 512 * 2;
    int* counts  = (int*)p;    p += (size_t)N_NODES * 4;
    int* offs    = (int*)p;    p += (size_t)10004 * 4;
    int* cursor  = (int*)p;    p += (size_t)N_NODES * 4;
    int* srcs    = (int*)p;    p += (size_t)N_EDGES * 4;

    // ---- conversions + zero counts (fused) ----
    {
        const int n4 = N_NODES * 512 / 4;
        const int nb_split = (n4 + 255) / 256;
        const int nb_zero = (N_NODES + 255) / 256;
        split_zero_kernel<<<nb_split + nb_zero, 256, 0, stream>>>(
            (const float4*)h, xhi, xlo, n4, nb_split, counts, N_NODES);
    }
    tsplit_kernel<<<(512 * 512 + 255) / 256, 256, 0, stream>>>(W1, w1thi, w1tlo, 512, 512);
    tsplit_kernel<<<(512 * 64 + 255) / 256, 256, 0, stream>>>(W2, w2thi, w2tlo, 512, 64);

    // ---- CSR build ----
    hist_kernel<<<(N_EDGES + 255) / 256, 256, 0, stream>>>(dst, counts, N_EDGES);
    scan_kernel<<<1, 1024, 0, stream>>>(counts, offs, cursor, N_NODES);
    scatter_kernel<<<(N_EDGES + 255) / 256, 256, 0, stream>>>(src, dst, cursor, srcs, N_EDGES);

    // ---- layer 1 ----
    {
        dim3 grid((N_NODES + 127) / 128, 512 / 128);
        gemm_bf16x3_kernel<128, 128, 64, 64, true><<<grid, 256, 0, stream>>>(
            xhi, xlo, w1thi, w1tlo, feat1bf, N_NODES, 512, 512);
    }
    elr1_kernel<<<N_NODES, 256, 0, stream>>>(feat1bf, al1, ar1, el1, er1);
    agg1_kernel<<<N_NODES, 256, 0, stream>>>(feat1bf, el1, er1, offs, srcs, xhi, xlo);

    // ---- layer 2 ----
    {
        dim3 grid((N_NODES + 127) / 128, 1);
        gemm_bf16x3_kernel<128, 64, 64, 32, false><<<grid, 256, 0, stream>>>(
            xhi, xlo, w2thi, w2tlo, feat2, N_NODES, 64, 512);
    }
    elr2_kernel<<<(N_NODES + 3) / 4, 256, 0, stream>>>(feat2, al2, ar2, el2, er2);
    agg2_kernel<<<(N_NODES + 3) / 4, 256, 0, stream>>>(feat2, el2, er2, offs, srcs, out);
}

// Round 4
// 252.478 us; speedup vs baseline: 1.4011x; 1.0267x over previous
//
#include <hip/hip_runtime.h>
#include <hip/hip_bf16.h>
#include <math.h>

typedef unsigned int u32;
typedef unsigned short ushort;

constexpr int N_NODES = 10000;
constexpr int N_EDGES = 320000;
constexpr float NEG_SLOPE = 0.2f;

typedef __attribute__((ext_vector_type(8))) short short8;   // 8 x bf16 bits
typedef __attribute__((ext_vector_type(4))) float f32x4;

// ---------------------------------------------------------------------------
// helpers
// ---------------------------------------------------------------------------
__device__ __forceinline__ float lrelu(float x) { return x > 0.f ? x : NEG_SLOPE * x; }
__device__ __forceinline__ float elu(float x)   { return x > 0.f ? x : (expf(x) - 1.f); }

__device__ __forceinline__ ushort f2bf(float x) {
    u32 b = __float_as_uint(x);
    b += 0x7FFFu + ((b >> 16) & 1u);
    return (ushort)(b >> 16);
}
__device__ __forceinline__ float bf2f(ushort u) {
    return __uint_as_float(((u32)u) << 16);
}

__device__ __forceinline__ void gload16(const void* g, void* l) {
    __builtin_amdgcn_global_load_lds(
        (__attribute__((address_space(1))) void*)g,
        (__attribute__((address_space(3))) void*)l, 16, 0, 0);
}

// ---------------------------------------------------------------------------
// prep: fused [split h] + [tsplit W1] + [tsplit W2] + [wl2/wr2] + [zero counts]
// block ranges (grid.x = 5000 + 1024 + 128 + 2 + 40 = 6194)
// ---------------------------------------------------------------------------
constexpr int NB_SPLIT = (N_NODES * 512 / 4) / 256;      // 5000
constexpr int NB_W1    = (512 * 512) / 256;              // 1024
constexpr int NB_W2    = (512 * 64) / 256;               // 128
constexpr int NB_WLR2  = 2;                              // 512 threads
constexpr int NB_ZERO  = (N_NODES + 255) / 256;          // 40

__global__ void prep_kernel(const float4* __restrict__ h4,
                            ushort* __restrict__ hhi, ushort* __restrict__ hlo,
                            const float* __restrict__ W1,
                            ushort* __restrict__ w1thi, ushort* __restrict__ w1tlo,
                            const float* __restrict__ W2,
                            ushort* __restrict__ w2thi, ushort* __restrict__ w2tlo,
                            const float* __restrict__ al2, const float* __restrict__ ar2,
                            float* __restrict__ wl2, float* __restrict__ wr2,
                            int* __restrict__ counts) {
    const int b = blockIdx.x;
    if (b < NB_SPLIT) {
        const int i = b * 256 + threadIdx.x;
        const float4 v = h4[i];
        ushort h0 = f2bf(v.x), h1 = f2bf(v.y), h2 = f2bf(v.z), h3 = f2bf(v.w);
        *(ushort4*)&hhi[i * 4] = make_ushort4(h0, h1, h2, h3);
        *(ushort4*)&hlo[i * 4] = make_ushort4(
            f2bf(v.x - bf2f(h0)), f2bf(v.y - bf2f(h1)),
            f2bf(v.z - bf2f(h2)), f2bf(v.w - bf2f(h3)));
    } else if (b < NB_SPLIT + NB_W1) {
        const int idx = (b - NB_SPLIT) * 256 + threadIdx.x;   // [0, 512*512)
        const int n = idx >> 9, k = idx & 511;                // K=512
        const float v = W1[(size_t)k * 512 + n];
        const ushort hh = f2bf(v);
        w1thi[idx] = hh;
        w1tlo[idx] = f2bf(v - bf2f(hh));
    } else if (b < NB_SPLIT + NB_W1 + NB_W2) {
        const int idx = (b - NB_SPLIT - NB_W1) * 256 + threadIdx.x;  // [0, 64*512)
        const int n = idx >> 9, k = idx & 511;
        const float v = W2[(size_t)k * 64 + n];
        const ushort hh = f2bf(v);
        w2thi[idx] = hh;
        w2tlo[idx] = f2bf(v - bf2f(hh));
    } else if (b < NB_SPLIT + NB_W1 + NB_W2 + NB_WLR2) {
        const int k = (b - NB_SPLIT - NB_W1 - NB_W2) * 256 + threadIdx.x;  // [0,512)
        float sl = 0.f, sr = 0.f;
#pragma unroll 8
        for (int d = 0; d < 64; d++) {
            const float w = W2[(size_t)k * 64 + d];
            sl += w * al2[d];
            sr += w * ar2[d];
        }
        wl2[k] = sl;
        wr2[k] = sr;
    } else {
        const int j = (b - NB_SPLIT - NB_W1 - NB_W2 - NB_WLR2) * 256 + threadIdx.x;
        if (j < N_NODES) counts[j] = 0;
    }
}

// ---------------------------------------------------------------------------
// bf16x3 MFMA GEMM (m97 structure): C[M,N] = A[M,K] @ B[K,N]; A hi/lo (MxK),
// B transposed hi/lo (NxK). K % 32 == 0.
// ---------------------------------------------------------------------------
template<int BM, int BN, int WM, int WN, bool BF16OUT>
__global__ __launch_bounds__(256) void gemm_bf16x3_kernel(
    const ushort* __restrict__ Ahi, const ushort* __restrict__ Alo,
    const ushort* __restrict__ Bhi, const ushort* __restrict__ Blo,
    void* __restrict__ Cout, int M, int N, int K) {
    constexpr int BK = 32;
    constexpr int MT_M = WM / 16, MT_N = WN / 16;
    constexpr int WAVES_N = BN / WN;
    constexpr int RA = (BM * BK * 2) / 4096;
    constexpr int RB = (BN * BK * 2) / 4096;

    __shared__ __align__(16) ushort sAhi[BM * BK];
    __shared__ __align__(16) ushort sAlo[BM * BK];
    __shared__ __align__(16) ushort sBhi[BN * BK];
    __shared__ __align__(16) ushort sBlo[BN * BK];

    const int tid = threadIdx.x;
    const int wave = tid >> 6, lane = tid & 63;
    const int m0 = blockIdx.x * BM, n0 = blockIdx.y * BN;
    const int wm = wave / WAVES_N, wn = wave % WAVES_N;
    const int quad = lane >> 4, l15 = lane & 15;

    const int fb = wave * 1024 + lane * 16;

    size_t abyte[RA];
#pragma unroll
    for (int r = 0; r < RA; r++) {
        const int f = fb + r * 4096;
        int grow = m0 + (f >> 6);
        if (grow > M - 1) grow = M - 1;
        abyte[r] = (size_t)grow * (K * 2) + (f & 63);
    }
    size_t bbyte[RB];
#pragma unroll
    for (int r = 0; r < RB; r++) {
        const int f = fb + r * 4096;
        bbyte[r] = (size_t)(n0 + (f >> 6)) * (K * 2) + (f & 63);
    }

    f32x4 acc[MT_M][MT_N] = {};

    for (int k0 = 0; k0 < K; k0 += BK) {
        __syncthreads();
        const size_t kb = (size_t)k0 * 2;
#pragma unroll
        for (int r = 0; r < RA; r++) {
            const int f = fb + r * 4096;
            gload16((const char*)Ahi + abyte[r] + kb, (char*)sAhi + f);
            gload16((const char*)Alo + abyte[r] + kb, (char*)sAlo + f);
        }
#pragma unroll
        for (int r = 0; r < RB; r++) {
            const int f = fb + r * 4096;
            gload16((const char*)Bhi + bbyte[r] + kb, (char*)sBhi + f);
            gload16((const char*)Blo + bbyte[r] + kb, (char*)sBlo + f);
        }
        __syncthreads();

        short8 ah[MT_M], al[MT_M], bh[MT_N], bl[MT_N];
#pragma unroll
        for (int mi = 0; mi < MT_M; mi++) {
            const int row = wm * WM + mi * 16 + l15;
            ah[mi] = *(const short8*)&sAhi[row * BK + quad * 8];
            al[mi] = *(const short8*)&sAlo[row * BK + quad * 8];
        }
#pragma unroll
        for (int ni = 0; ni < MT_N; ni++) {
            const int row = wn * WN + ni * 16 + l15;
            bh[ni] = *(const short8*)&sBhi[row * BK + quad * 8];
            bl[ni] = *(const short8*)&sBlo[row * BK + quad * 8];
        }
#pragma unroll
        for (int mi = 0; mi < MT_M; mi++)
#pragma unroll
            for (int ni = 0; ni < MT_N; ni++) {
                acc[mi][ni] = __builtin_amdgcn_mfma_f32_16x16x32_bf16(ah[mi], bh[ni], acc[mi][ni], 0, 0, 0);
                acc[mi][ni] = __builtin_amdgcn_mfma_f32_16x16x32_bf16(ah[mi], bl[ni], acc[mi][ni], 0, 0, 0);
                acc[mi][ni] = __builtin_amdgcn_mfma_f32_16x16x32_bf16(al[mi], bh[ni], acc[mi][ni], 0, 0, 0);
            }
    }

    // epilogue: D row = (lane>>4)*4 + reg, col = lane&15  [verified m89/m91]
#pragma unroll
    for (int mi = 0; mi < MT_M; mi++) {
#pragma unroll
        for (int r = 0; r < 4; r++) {
            const int grow = m0 + wm * WM + mi * 16 + quad * 4 + r;
            if (grow < M) {
#pragma unroll
                for (int ni = 0; ni < MT_N; ni++) {
                    const int gcol = n0 + wn * WN + ni * 16 + l15;
                    if (BF16OUT)
                        ((ushort*)Cout)[(size_t)grow * N + gcol] = f2bf(acc[mi][ni][r]);
                    else
                        ((float*)Cout)[(size_t)grow * N + gcol] = acc[mi][ni][r];
                }
            }
        }
    }
}

// ---------------------------------------------------------------------------
// el/er layer1 from bf16 feat (N,512). Wave w: heads 2w / 2w+1; 32-lane redns.
// ---------------------------------------------------------------------------
__global__ __launch_bounds__(256) void elr1_kernel(
    const ushort* __restrict__ feat, const float* __restrict__ al,
    const float* __restrict__ ar, float* __restrict__ el, float* __restrict__ er) {
    const int node = blockIdx.x;
    const int tid = threadIdx.x;
    const int wave = tid >> 6, lane = tid & 63;
    const int off = wave * 128 + lane * 2;
    const ushort2 u = *(const ushort2*)&feat[(size_t)node * 512 + off];
    const float f0 = bf2f(u.x), f1 = bf2f(u.y);
    float pl = f0 * al[off] + f1 * al[off + 1];
    float pr = f0 * ar[off] + f1 * ar[off + 1];
#pragma unroll
    for (int o = 1; o < 32; o <<= 1) {
        pl += __shfl_xor(pl, o);
        pr += __shfl_xor(pr, o);
    }
    const int h = wave * 2 + (lane >> 5);
    if ((lane & 31) == 0) {
        el[node * 8 + h] = pl;
        er[node * 8 + h] = pr;
    }
}

// ---------------------------------------------------------------------------
// CSR build
// ---------------------------------------------------------------------------
__global__ void hist_kernel(const int* __restrict__ dst, int* __restrict__ counts, int e) {
    const int i = blockIdx.x * 256 + threadIdx.x;
    if (i < e) atomicAdd(&counts[dst[i]], 1);
}

__global__ __launch_bounds__(1024) void scan_kernel(
    const int* __restrict__ counts, int* __restrict__ offs,
    int* __restrict__ cursor, int n) {
    __shared__ int wsum[16];
    const int tid = threadIdx.x;
    const int lane = tid & 63, wave = tid >> 6;
    const int base = tid * 10;
    int v[10];
    int s = 0;
#pragma unroll
    for (int i = 0; i < 10; i++) {
        v[i] = (base + i < n) ? counts[base + i] : 0;
        s += v[i];
    }
    int ps = s;
#pragma unroll
    for (int o = 1; o < 64; o <<= 1) {
        const int t = __shfl_up(ps, o);
        if (lane >= o) ps += t;
    }
    if (lane == 63) wsum[wave] = ps;
    __syncthreads();
    if (tid < 16) {
        int t = wsum[tid];
#pragma unroll
        for (int o = 1; o < 16; o <<= 1) {
            const int u = __shfl_up(t, o);
            if (tid >= o) t += u;
        }
        wsum[tid] = t;
    }
    __syncthreads();
    const int wbase = (wave > 0) ? wsum[wave - 1] : 0;
    int run = wbase + ps - s;
#pragma unroll
    for (int i = 0; i < 10; i++) {
        if (base + i < n) {
            cursor[base + i] = run;
            offs[base + i + 1] = run + v[i];
        }
        run += v[i];
    }
    if (tid == 0) offs[0] = 0;
}

__global__ void scatter_kernel(const int* __restrict__ src, const int* __restrict__ dst,
                               int* __restrict__ cursor, int* __restrict__ srcs, int e) {
    const int i = blockIdx.x * 256 + threadIdx.x;
    if (i < e) {
        const int d = dst[i];
        const int p = atomicAdd(&cursor[d], 1);
        srcs[p] = src[i];
    }
}

// ---------------------------------------------------------------------------
// Layer-1 aggregation v4: ONE WAVE PER NODE. Lane owns 8 dims (16B gather).
// Weight per edge recomputed per 8-lane head-group from one 32B el-row
// broadcast load. No LDS, no barriers. Epilogue fuses layer-2 el/er
// (el2 = x1 . wl2) and writes x1 as bf16 hi/lo split.
// ---------------------------------------------------------------------------
__global__ __launch_bounds__(256) void agg1_kernel(
    const ushort* __restrict__ feat, const float* __restrict__ el,
    const float* __restrict__ er, const int* __restrict__ offs,
    const int* __restrict__ srcs, ushort* __restrict__ xhi, ushort* __restrict__ xlo,
    const float* __restrict__ wl2, const float* __restrict__ wr2,
    float* __restrict__ el2, float* __restrict__ er2) {
    const int tid = threadIdx.x;
    const int wave = tid >> 6, lane = tid & 63;
    const int node = blockIdx.x * 4 + wave;     // grid = 2500, exact
    const int start = offs[node];
    const int deg = offs[node + 1] - start;
    const int d0 = lane * 8;                    // my 8 dims [d0, d0+8)
    const int myh = lane >> 3;                  // my head = d0/64

    if (deg == 0) {
        const ushort4 z = make_ushort4(0, 0, 0, 0);
        *(ushort4*)&xhi[(size_t)node * 512 + d0] = z;
        *(ushort4*)&xhi[(size_t)node * 512 + d0 + 4] = z;
        *(ushort4*)&xlo[(size_t)node * 512 + d0] = z;
        *(ushort4*)&xlo[(size_t)node * 512 + d0 + 4] = z;
        if (lane == 0) { el2[node] = 0.f; er2[node] = 0.f; }
        return;
    }

    // er[node, myh] via branchless select from two float4 broadcast loads
    const float4 ea = *(const float4*)&er[node * 8];
    const float4 eb = *(const float4*)&er[node * 8 + 4];
    float er_my = (myh & 4) ? ((myh & 2) ? ((myh & 1) ? eb.w : eb.z)
                                        : ((myh & 1) ? eb.y : eb.x))
                            : ((myh & 2) ? ((myh & 1) ? ea.w : ea.z)
                                        : ((myh & 1) ? ea.y : ea.x));

    float acc[8];
#pragma unroll
    for (int i = 0; i < 8; i++) acc[i] = 0.f;
    float ws = 0.f;

    int base = 0;
    for (; base + 64 <= deg; base += 64) {
        const int s = srcs[start + base + lane];
#pragma unroll 4
        for (int j = 0; j < 64; j++) {
            const int sj = __shfl(s, j);
            const float w = __expf(lrelu(el[sj * 8 + myh] + er_my));
            const short8 u = *(const short8*)&feat[(size_t)sj * 512 + d0];
#pragma unroll
            for (int i = 0; i < 8; i++)
                acc[i] += w * bf2f((ushort)u[i]);
            ws += w;
        }
    }
    const int has = deg - base;
    if (has > 0) {
        const int s = (lane < has) ? srcs[start + base + lane] : 0;
        for (int j = 0; j < has; j++) {
            const int sj = __shfl(s, j);
            const float w = __expf(lrelu(el[sj * 8 + myh] + er_my));
            const short8 u = *(const short8*)&feat[(size_t)sj * 512 + d0];
#pragma unroll
            for (int i = 0; i < 8; i++)
                acc[i] += w * bf2f((ushort)u[i]);
            ws += w;
        }
    }

    const float inv = 1.f / ws;
    float o[8];
#pragma unroll
    for (int i = 0; i < 8; i++) o[i] = elu(acc[i] * inv);

    // fused layer-2 logits: el2 = sum_d x1[d] * wl2[d]
    const float4 wla = *(const float4*)&wl2[d0];
    const float4 wlb = *(const float4*)&wl2[d0 + 4];
    const float4 wra = *(const float4*)&wr2[d0];
    const float4 wrb = *(const float4*)&wr2[d0 + 4];
    float pl = o[0] * wla.x + o[1] * wla.y + o[2] * wla.z + o[3] * wla.w
             + o[4] * wlb.x + o[5] * wlb.y + o[6] * wlb.z + o[7] * wlb.w;
    float pr = o[0] * wra.x + o[1] * wra.y + o[2] * wra.z + o[3] * wra.w
             + o[4] * wrb.x + o[5] * wrb.y + o[6] * wrb.z + o[7] * wrb.w;
#pragma unroll
    for (int off = 32; off > 0; off >>= 1) {
        pl += __shfl_xor(pl, off);
        pr += __shfl_xor(pr, off);
    }
    if (lane == 0) { el2[node] = pl; er2[node] = pr; }

    // write x1 as bf16 hi/lo (16B per lane each)
    ushort hi[8], lo[8];
#pragma unroll
    for (int i = 0; i < 8; i++) {
        hi[i] = f2bf(o[i]);
        lo[i] = f2bf(o[i] - bf2f(hi[i]));
    }
    *(ushort4*)&xhi[(size_t)node * 512 + d0]     = make_ushort4(hi[0], hi[1], hi[2], hi[3]);
    *(ushort4*)&xhi[(size_t)node * 512 + d0 + 4] = make_ushort4(hi[4], hi[5], hi[6], hi[7]);
    *(ushort4*)&xlo[(size_t)node * 512 + d0]     = make_ushort4(lo[0], lo[1], lo[2], lo[3]);
    *(ushort4*)&xlo[(size_t)node * 512 + d0 + 4] = make_ushort4(lo[4], lo[5], lo[6], lo[7]);
}

// ---------------------------------------------------------------------------
// Layer-2 aggregation: one wave per node; no LDS/barriers.
// ---------------------------------------------------------------------------
__global__ __launch_bounds__(256) void agg2_kernel(
    const float* __restrict__ feat, const float* __restrict__ el,
    const float* __restrict__ er, const int* __restrict__ offs,
    const int* __restrict__ srcs, float* __restrict__ out) {
    const int tid = threadIdx.x;
    const int wave = tid >> 6, lane = tid & 63;
    const int node = blockIdx.x * 4 + wave;
    const int start = offs[node];
    const int deg = offs[node + 1] - start;
    if (deg == 0) { out[(size_t)node * 64 + lane] = 0.f; return; }
    const float ern = er[node];

    float acc = 0.f, ws = 0.f;
    for (int base = 0; base < deg; base += 64) {
        const int has = min(64, deg - base);
        int s = 0;
        float w = 0.f;
        if (lane < has) {
            s = srcs[start + base + lane];
            w = __expf(lrelu(el[s] + ern));
        }
        for (int j = 0; j < has; j++) {
            const float a = __shfl(w, j);
            const int sj = __shfl(s, j);
            acc += a * feat[(size_t)sj * 64 + lane];
            ws += a;
        }
    }
    out[(size_t)node * 64 + lane] = acc / ws;
}

// ---------------------------------------------------------------------------
extern "C" void kernel_launch(void* const* d_in, const int* in_sizes, int n_in,
                              void* d_out, int out_size, void* d_ws, size_t ws_size,
                              hipStream_t stream) {
    const float* h   = (const float*)d_in[0];
    const int*   src = (const int*)d_in[1];
    const int*   dst = (const int*)d_in[2];
    const float* W1  = (const float*)d_in[3];
    const float* al1 = (const float*)d_in[4];
    const float* ar1 = (const float*)d_in[5];
    const float* W2  = (const float*)d_in[6];
    const float* al2 = (const float*)d_in[7];
    const float* ar2 = (const float*)d_in[8];
    float* out = (float*)d_out;

    // workspace carve (16B-aligned chunks)
    char* p = (char*)d_ws;
    ushort* feat1bf = (ushort*)p; p += (size_t)N_NODES * 512 * 2;  // 10.24 MB
    float* feat2 = (float*)p;  p += (size_t)N_NODES * 64 * 4;      // 2.56 MB
    float* el1   = (float*)p;  p += (size_t)N_NODES * 8 * 4;
    float* er1   = (float*)p;  p += (size_t)N_NODES * 8 * 4;
    float* el2   = (float*)p;  p += (size_t)N_NODES * 4;
    float* er2   = (float*)p;  p += (size_t)N_NODES * 4;
    ushort* xhi  = (ushort*)p; p += (size_t)N_NODES * 512 * 2;     // h_hi -> x1_hi
    ushort* xlo  = (ushort*)p; p += (size_t)N_NODES * 512 * 2;     // h_lo -> x1_lo
    ushort* w1thi = (ushort*)p; p += (size_t)512 * 512 * 2;
    ushort* w1tlo = (ushort*)p; p += (size_t)512 * 512 * 2;
    ushort* w2thi = (ushort*)p; p += (size_t)64 * 512 * 2;
    ushort* w2tlo = (ushort*)p; p += (size_t)64 * 512 * 2;
    float* wl2   = (float*)p;  p += (size_t)512 * 4;
    float* wr2   = (float*)p;  p += (size_t)512 * 4;
    int* counts  = (int*)p;    p += (size_t)N_NODES * 4;
    int* offs    = (int*)p;    p += (size_t)10004 * 4;
    int* cursor  = (int*)p;    p += (size_t)N_NODES * 4;
    int* srcs    = (int*)p;    p += (size_t)N_EDGES * 4;

    // ---- fused prep ----
    prep_kernel<<<NB_SPLIT + NB_W1 + NB_W2 + NB_WLR2 + NB_ZERO, 256, 0, stream>>>(
        (const float4*)h, xhi, xlo, W1, w1thi, w1tlo, W2, w2thi, w2tlo,
        al2, ar2, wl2, wr2, counts);

    // ---- CSR build ----
    hist_kernel<<<(N_EDGES + 255) / 256, 256, 0, stream>>>(dst, counts, N_EDGES);
    scan_kernel<<<1, 1024, 0, stream>>>(counts, offs, cursor, N_NODES);
    scatter_kernel<<<(N_EDGES + 255) / 256, 256, 0, stream>>>(src, dst, cursor, srcs, N_EDGES);

    // ---- layer 1: GEMM (BM=64 for load balance: grid 158x4=632) ----
    {
        dim3 grid((N_NODES + 63) / 64, 512 / 128);
        gemm_bf16x3_kernel<64, 128, 32, 64, true><<<grid, 256, 0, stream>>>(
            xhi, xlo, w1thi, w1tlo, feat1bf, N_NODES, 512, 512);
    }
    elr1_kernel<<<N_NODES, 256, 0, stream>>>(feat1bf, al1, ar1, el1, er1);
    agg1_kernel<<<N_NODES / 4, 256, 0, stream>>>(
        feat1bf, el1, er1, offs, srcs, xhi, xlo, wl2, wr2, el2, er2);

    // ---- layer 2 ----
    {
        dim3 grid((N_NODES + 63) / 64, 1);
        gemm_bf16x3_kernel<64, 64, 32, 32, false><<<grid, 256, 0, stream>>>(
            xhi, xlo, w2thi, w2tlo, feat2, N_NODES, 64, 512);
    }
    agg2_kernel<<<N_NODES / 4, 256, 0, stream>>>(feat2, el2, er2, offs, srcs, out);
}

// Round 5
// 234.732 us; speedup vs baseline: 1.5070x; 1.0756x over previous
//
#include <hip/hip_runtime.h>
#include <hip/hip_bf16.h>
#include <math.h>

typedef unsigned int u32;
typedef unsigned short ushort;

constexpr int N_NODES = 10000;
constexpr int N_EDGES = 320000;
constexpr float NEG_SLOPE = 0.2f;

typedef __attribute__((ext_vector_type(8))) short short8;   // 8 x bf16 bits
typedef __attribute__((ext_vector_type(4))) float f32x4;

// ---------------------------------------------------------------------------
// helpers
// ---------------------------------------------------------------------------
__device__ __forceinline__ float lrelu(float x) { return x > 0.f ? x : NEG_SLOPE * x; }
__device__ __forceinline__ float elu(float x)   { return x > 0.f ? x : (expf(x) - 1.f); }

__device__ __forceinline__ ushort f2bf(float x) {
    u32 b = __float_as_uint(x);
    b += 0x7FFFu + ((b >> 16) & 1u);
    return (ushort)(b >> 16);
}
__device__ __forceinline__ float bf2f(ushort u) {
    return __uint_as_float(((u32)u) << 16);
}

__device__ __forceinline__ void gload16(const void* g, void* l) {
    __builtin_amdgcn_global_load_lds(
        (__attribute__((address_space(1))) void*)g,
        (__attribute__((address_space(3))) void*)l, 16, 0, 0);
}

// ---------------------------------------------------------------------------
// prep: fused [split h] + [tsplit W1] + [tsplit W2] + [wl2/wr2] + [zero counts]
// ---------------------------------------------------------------------------
constexpr int NB_SPLIT = (N_NODES * 512 / 4) / 256;      // 5000
constexpr int NB_W1    = (512 * 512) / 256;              // 1024
constexpr int NB_W2    = (512 * 64) / 256;               // 128
constexpr int NB_WLR2  = 2;                              // 512 threads
constexpr int NB_ZERO  = (N_NODES + 255) / 256;          // 40

__global__ void prep_kernel(const float4* __restrict__ h4,
                            ushort* __restrict__ hhi, ushort* __restrict__ hlo,
                            const float* __restrict__ W1,
                            ushort* __restrict__ w1thi, ushort* __restrict__ w1tlo,
                            const float* __restrict__ W2,
                            ushort* __restrict__ w2thi, ushort* __restrict__ w2tlo,
                            const float* __restrict__ al2, const float* __restrict__ ar2,
                            float* __restrict__ wl2, float* __restrict__ wr2,
                            int* __restrict__ counts) {
    const int b = blockIdx.x;
    if (b < NB_SPLIT) {
        const int i = b * 256 + threadIdx.x;
        const float4 v = h4[i];
        ushort h0 = f2bf(v.x), h1 = f2bf(v.y), h2 = f2bf(v.z), h3 = f2bf(v.w);
        *(ushort4*)&hhi[i * 4] = make_ushort4(h0, h1, h2, h3);
        *(ushort4*)&hlo[i * 4] = make_ushort4(
            f2bf(v.x - bf2f(h0)), f2bf(v.y - bf2f(h1)),
            f2bf(v.z - bf2f(h2)), f2bf(v.w - bf2f(h3)));
    } else if (b < NB_SPLIT + NB_W1) {
        const int idx = (b - NB_SPLIT) * 256 + threadIdx.x;
        const int n = idx >> 9, k = idx & 511;
        const float v = W1[(size_t)k * 512 + n];
        const ushort hh = f2bf(v);
        w1thi[idx] = hh;
        w1tlo[idx] = f2bf(v - bf2f(hh));
    } else if (b < NB_SPLIT + NB_W1 + NB_W2) {
        const int idx = (b - NB_SPLIT - NB_W1) * 256 + threadIdx.x;
        const int n = idx >> 9, k = idx & 511;
        const float v = W2[(size_t)k * 64 + n];
        const ushort hh = f2bf(v);
        w2thi[idx] = hh;
        w2tlo[idx] = f2bf(v - bf2f(hh));
    } else if (b < NB_SPLIT + NB_W1 + NB_W2 + NB_WLR2) {
        const int k = (b - NB_SPLIT - NB_W1 - NB_W2) * 256 + threadIdx.x;
        float sl = 0.f, sr = 0.f;
#pragma unroll 8
        for (int d = 0; d < 64; d++) {
            const float w = W2[(size_t)k * 64 + d];
            sl += w * al2[d];
            sr += w * ar2[d];
        }
        wl2[k] = sl;
        wr2[k] = sr;
    } else {
        const int j = (b - NB_SPLIT - NB_W1 - NB_W2 - NB_WLR2) * 256 + threadIdx.x;
        if (j < N_NODES) counts[j] = 0;
    }
}

// ---------------------------------------------------------------------------
// bf16x3 MFMA GEMM; optional fused el/er epilogue (requires WN==64 so each
// wave's columns live in exactly one head: head = (n0 + wn*64)/64).
// ---------------------------------------------------------------------------
template<int BM, int BN, int WM, int WN, bool BF16OUT, bool FUSE_ELR>
__global__ __launch_bounds__(256) void gemm_bf16x3_kernel(
    const ushort* __restrict__ Ahi, const ushort* __restrict__ Alo,
    const ushort* __restrict__ Bhi, const ushort* __restrict__ Blo,
    void* __restrict__ Cout, int M, int N, int K,
    const float* __restrict__ attn_l, const float* __restrict__ attn_r,
    float* __restrict__ elp, float* __restrict__ erp) {
    constexpr int BK = 32;
    constexpr int MT_M = WM / 16, MT_N = WN / 16;
    constexpr int WAVES_N = BN / WN;
    constexpr int RA = (BM * BK * 2) / 4096;
    constexpr int RB = (BN * BK * 2) / 4096;

    __shared__ __align__(16) ushort sAhi[BM * BK];
    __shared__ __align__(16) ushort sAlo[BM * BK];
    __shared__ __align__(16) ushort sBhi[BN * BK];
    __shared__ __align__(16) ushort sBlo[BN * BK];

    const int tid = threadIdx.x;
    const int wave = tid >> 6, lane = tid & 63;
    const int m0 = blockIdx.x * BM, n0 = blockIdx.y * BN;
    const int wm = wave / WAVES_N, wn = wave % WAVES_N;
    const int quad = lane >> 4, l15 = lane & 15;

    const int fb = wave * 1024 + lane * 16;

    size_t abyte[RA];
#pragma unroll
    for (int r = 0; r < RA; r++) {
        const int f = fb + r * 4096;
        int grow = m0 + (f >> 6);
        if (grow > M - 1) grow = M - 1;
        abyte[r] = (size_t)grow * (K * 2) + (f & 63);
    }
    size_t bbyte[RB];
#pragma unroll
    for (int r = 0; r < RB; r++) {
        const int f = fb + r * 4096;
        bbyte[r] = (size_t)(n0 + (f >> 6)) * (K * 2) + (f & 63);
    }

    f32x4 acc[MT_M][MT_N] = {};

    for (int k0 = 0; k0 < K; k0 += BK) {
        __syncthreads();
        const size_t kb = (size_t)k0 * 2;
#pragma unroll
        for (int r = 0; r < RA; r++) {
            const int f = fb + r * 4096;
            gload16((const char*)Ahi + abyte[r] + kb, (char*)sAhi + f);
            gload16((const char*)Alo + abyte[r] + kb, (char*)sAlo + f);
        }
#pragma unroll
        for (int r = 0; r < RB; r++) {
            const int f = fb + r * 4096;
            gload16((const char*)Bhi + bbyte[r] + kb, (char*)sBhi + f);
            gload16((const char*)Blo + bbyte[r] + kb, (char*)sBlo + f);
        }
        __syncthreads();

        short8 ah[MT_M], al[MT_M], bh[MT_N], bl[MT_N];
#pragma unroll
        for (int mi = 0; mi < MT_M; mi++) {
            const int row = wm * WM + mi * 16 + l15;
            ah[mi] = *(const short8*)&sAhi[row * BK + quad * 8];
            al[mi] = *(const short8*)&sAlo[row * BK + quad * 8];
        }
#pragma unroll
        for (int ni = 0; ni < MT_N; ni++) {
            const int row = wn * WN + ni * 16 + l15;
            bh[ni] = *(const short8*)&sBhi[row * BK + quad * 8];
            bl[ni] = *(const short8*)&sBlo[row * BK + quad * 8];
        }
#pragma unroll
        for (int mi = 0; mi < MT_M; mi++)
#pragma unroll
            for (int ni = 0; ni < MT_N; ni++) {
                acc[mi][ni] = __builtin_amdgcn_mfma_f32_16x16x32_bf16(ah[mi], bh[ni], acc[mi][ni], 0, 0, 0);
                acc[mi][ni] = __builtin_amdgcn_mfma_f32_16x16x32_bf16(ah[mi], bl[ni], acc[mi][ni], 0, 0, 0);
                acc[mi][ni] = __builtin_amdgcn_mfma_f32_16x16x32_bf16(al[mi], bh[ni], acc[mi][ni], 0, 0, 0);
            }
    }

    // epilogue: D row = (lane>>4)*4 + reg, col = lane&15  [verified m89/m91]
#pragma unroll
    for (int mi = 0; mi < MT_M; mi++) {
#pragma unroll
        for (int r = 0; r < 4; r++) {
            const int grow = m0 + wm * WM + mi * 16 + quad * 4 + r;
            if (grow < M) {
#pragma unroll
                for (int ni = 0; ni < MT_N; ni++) {
                    const int gcol = n0 + wn * WN + ni * 16 + l15;
                    if (BF16OUT)
                        ((ushort*)Cout)[(size_t)grow * N + gcol] = f2bf(acc[mi][ni][r]);
                    else
                        ((float*)Cout)[(size_t)grow * N + gcol] = acc[mi][ni][r];
                }
            }
        }
    }

    if (FUSE_ELR) {
        // this wave's columns all belong to one head (WN == 64)
        const int head = (n0 + wn * 64) >> 6;
        float alv[MT_N], arv[MT_N];
#pragma unroll
        for (int ni = 0; ni < MT_N; ni++) {
            alv[ni] = attn_l[head * 64 + ni * 16 + l15];
            arv[ni] = attn_r[head * 64 + ni * 16 + l15];
        }
#pragma unroll
        for (int mi = 0; mi < MT_M; mi++) {
#pragma unroll
            for (int r = 0; r < 4; r++) {
                float pl = 0.f, pr = 0.f;
#pragma unroll
                for (int ni = 0; ni < MT_N; ni++) {
                    pl += acc[mi][ni][r] * alv[ni];
                    pr += acc[mi][ni][r] * arv[ni];
                }
#pragma unroll
                for (int o = 1; o < 16; o <<= 1) {
                    pl += __shfl_xor(pl, o);
                    pr += __shfl_xor(pr, o);
                }
                const int grow = m0 + wm * WM + mi * 16 + quad * 4 + r;
                if (l15 == 0 && grow < M) {
                    elp[grow * 8 + head] = pl;
                    erp[grow * 8 + head] = pr;
                }
            }
        }
    }
}

// ---------------------------------------------------------------------------
// CSR build
// ---------------------------------------------------------------------------
__global__ void hist_kernel(const int* __restrict__ dst, int* __restrict__ counts, int e) {
    const int i = blockIdx.x * 256 + threadIdx.x;
    if (i < e) atomicAdd(&counts[dst[i]], 1);
}

__global__ __launch_bounds__(1024) void scan_kernel(
    const int* __restrict__ counts, int* __restrict__ offs,
    int* __restrict__ cursor, int n) {
    __shared__ int wsum[16];
    const int tid = threadIdx.x;
    const int lane = tid & 63, wave = tid >> 6;
    const int base = tid * 10;
    int v[10];
    int s = 0;
#pragma unroll
    for (int i = 0; i < 10; i++) {
        v[i] = (base + i < n) ? counts[base + i] : 0;
        s += v[i];
    }
    int ps = s;
#pragma unroll
    for (int o = 1; o < 64; o <<= 1) {
        const int t = __shfl_up(ps, o);
        if (lane >= o) ps += t;
    }
    if (lane == 63) wsum[wave] = ps;
    __syncthreads();
    if (tid < 16) {
        int t = wsum[tid];
#pragma unroll
        for (int o = 1; o < 16; o <<= 1) {
            const int u = __shfl_up(t, o);
            if (tid >= o) t += u;
        }
        wsum[tid] = t;
    }
    __syncthreads();
    const int wbase = (wave > 0) ? wsum[wave - 1] : 0;
    int run = wbase + ps - s;
#pragma unroll
    for (int i = 0; i < 10; i++) {
        if (base + i < n) {
            cursor[base + i] = run;
            offs[base + i + 1] = run + v[i];
        }
        run += v[i];
    }
    if (tid == 0) offs[0] = 0;
}

__global__ void scatter_kernel(const int* __restrict__ src, const int* __restrict__ dst,
                               int* __restrict__ cursor, int* __restrict__ srcs, int e) {
    const int i = blockIdx.x * 256 + threadIdx.x;
    if (i < e) {
        const int d = dst[i];
        const int p = atomicAdd(&cursor[d], 1);
        srcs[p] = src[i];
    }
}

// ---------------------------------------------------------------------------
// Layer-1 aggregation v5: one wave per node, explicit 4-deep software
// pipeline (4 shfl + 4 el loads + 4 16B gathers issued before consumption).
// Epilogue fuses layer-2 logits and bf16 hi/lo split of x1.
// ---------------------------------------------------------------------------
__global__ __launch_bounds__(256) void agg1_kernel(
    const ushort* __restrict__ feat, const float* __restrict__ el,
    const float* __restrict__ er, const int* __restrict__ offs,
    const int* __restrict__ srcs, ushort* __restrict__ xhi, ushort* __restrict__ xlo,
    const float* __restrict__ wl2, const float* __restrict__ wr2,
    float* __restrict__ el2, float* __restrict__ er2) {
    const int tid = threadIdx.x;
    const int wave = tid >> 6, lane = tid & 63;
    const int node = blockIdx.x * 4 + wave;     // grid = 2500, exact
    const int start = offs[node];
    const int deg = offs[node + 1] - start;
    const int d0 = lane * 8;
    const int myh = lane >> 3;

    if (deg == 0) {
        const ushort4 z = make_ushort4(0, 0, 0, 0);
        *(ushort4*)&xhi[(size_t)node * 512 + d0] = z;
        *(ushort4*)&xhi[(size_t)node * 512 + d0 + 4] = z;
        *(ushort4*)&xlo[(size_t)node * 512 + d0] = z;
        *(ushort4*)&xlo[(size_t)node * 512 + d0 + 4] = z;
        if (lane == 0) { el2[node] = 0.f; er2[node] = 0.f; }
        return;
    }

    // er[node, myh] via branchless select from two float4 broadcast loads
    const float4 ea = *(const float4*)&er[node * 8];
    const float4 eb = *(const float4*)&er[node * 8 + 4];
    const float er_my = (myh & 4) ? ((myh & 2) ? ((myh & 1) ? eb.w : eb.z)
                                              : ((myh & 1) ? eb.y : eb.x))
                                  : ((myh & 2) ? ((myh & 1) ? ea.w : ea.z)
                                              : ((myh & 1) ? ea.y : ea.x));

    float acc[8];
#pragma unroll
    for (int i = 0; i < 8; i++) acc[i] = 0.f;
    float ws = 0.f;

    for (int base = 0; base < deg; base += 64) {
        const int has = min(64, deg - base);
        const int s = srcs[start + base + min(lane, has - 1)];
        int j = 0;
        for (; j + 4 <= has; j += 4) {
            // stage 1: all broadcasts + all loads (independent, fill vmcnt queue)
            const int s0 = __shfl(s, j),     s1 = __shfl(s, j + 1);
            const int s2 = __shfl(s, j + 2), s3 = __shfl(s, j + 3);
            const float e0 = el[s0 * 8 + myh], e1 = el[s1 * 8 + myh];
            const float e2 = el[s2 * 8 + myh], e3 = el[s3 * 8 + myh];
            const short8 u0 = *(const short8*)&feat[(size_t)s0 * 512 + d0];
            const short8 u1 = *(const short8*)&feat[(size_t)s1 * 512 + d0];
            const short8 u2 = *(const short8*)&feat[(size_t)s2 * 512 + d0];
            const short8 u3 = *(const short8*)&feat[(size_t)s3 * 512 + d0];
            // stage 2: consume
            const float w0 = __expf(lrelu(e0 + er_my));
            const float w1 = __expf(lrelu(e1 + er_my));
            const float w2 = __expf(lrelu(e2 + er_my));
            const float w3 = __expf(lrelu(e3 + er_my));
#pragma unroll
            for (int i = 0; i < 8; i++) {
                acc[i] += w0 * bf2f((ushort)u0[i]) + w1 * bf2f((ushort)u1[i])
                        + w2 * bf2f((ushort)u2[i]) + w3 * bf2f((ushort)u3[i]);
            }
            ws += (w0 + w1) + (w2 + w3);
        }
        for (; j < has; j++) {
            const int sj = __shfl(s, j);
            const float w = __expf(lrelu(el[sj * 8 + myh] + er_my));
            const short8 u = *(const short8*)&feat[(size_t)sj * 512 + d0];
#pragma unroll
            for (int i = 0; i < 8; i++)
                acc[i] += w * bf2f((ushort)u[i]);
            ws += w;
        }
    }

    const float inv = 1.f / ws;
    float o[8];
#pragma unroll
    for (int i = 0; i < 8; i++) o[i] = elu(acc[i] * inv);

    // fused layer-2 logits
    const float4 wla = *(const float4*)&wl2[d0];
    const float4 wlb = *(const float4*)&wl2[d0 + 4];
    const float4 wra = *(const float4*)&wr2[d0];
    const float4 wrb = *(const float4*)&wr2[d0 + 4];
    float pl = o[0] * wla.x + o[1] * wla.y + o[2] * wla.z + o[3] * wla.w
             + o[4] * wlb.x + o[5] * wlb.y + o[6] * wlb.z + o[7] * wlb.w;
    float pr = o[0] * wra.x + o[1] * wra.y + o[2] * wra.z + o[3] * wra.w
             + o[4] * wrb.x + o[5] * wrb.y + o[6] * wrb.z + o[7] * wrb.w;
#pragma unroll
    for (int off = 32; off > 0; off >>= 1) {
        pl += __shfl_xor(pl, off);
        pr += __shfl_xor(pr, off);
    }
    if (lane == 0) { el2[node] = pl; er2[node] = pr; }

    ushort hi[8], lo[8];
#pragma unroll
    for (int i = 0; i < 8; i++) {
        hi[i] = f2bf(o[i]);
        lo[i] = f2bf(o[i] - bf2f(hi[i]));
    }
    *(ushort4*)&xhi[(size_t)node * 512 + d0]     = make_ushort4(hi[0], hi[1], hi[2], hi[3]);
    *(ushort4*)&xhi[(size_t)node * 512 + d0 + 4] = make_ushort4(hi[4], hi[5], hi[6], hi[7]);
    *(ushort4*)&xlo[(size_t)node * 512 + d0]     = make_ushort4(lo[0], lo[1], lo[2], lo[3]);
    *(ushort4*)&xlo[(size_t)node * 512 + d0 + 4] = make_ushort4(lo[4], lo[5], lo[6], lo[7]);
}

// ---------------------------------------------------------------------------
// Layer-2 aggregation v5: one wave per node, 4-deep pipeline.
// ---------------------------------------------------------------------------
__global__ __launch_bounds__(256) void agg2_kernel(
    const float* __restrict__ feat, const float* __restrict__ el,
    const float* __restrict__ er, const int* __restrict__ offs,
    const int* __restrict__ srcs, float* __restrict__ out) {
    const int tid = threadIdx.x;
    const int wave = tid >> 6, lane = tid & 63;
    const int node = blockIdx.x * 4 + wave;
    const int start = offs[node];
    const int deg = offs[node + 1] - start;
    if (deg == 0) { out[(size_t)node * 64 + lane] = 0.f; return; }
    const float ern = er[node];

    float acc = 0.f, ws = 0.f;
    for (int base = 0; base < deg; base += 64) {
        const int has = min(64, deg - base);
        const int idx = start + base + min(lane, has - 1);
        const int s = srcs[idx];
        const float w = __expf(lrelu(el[s] + ern));
        int j = 0;
        for (; j + 4 <= has; j += 4) {
            const float a0 = __shfl(w, j),     a1 = __shfl(w, j + 1);
            const float a2 = __shfl(w, j + 2), a3 = __shfl(w, j + 3);
            const int s0 = __shfl(s, j),     s1 = __shfl(s, j + 1);
            const int s2 = __shfl(s, j + 2), s3 = __shfl(s, j + 3);
            const float f0 = feat[(size_t)s0 * 64 + lane];
            const float f1 = feat[(size_t)s1 * 64 + lane];
            const float f2 = feat[(size_t)s2 * 64 + lane];
            const float f3 = feat[(size_t)s3 * 64 + lane];
            acc += a0 * f0 + a1 * f1 + a2 * f2 + a3 * f3;
            ws += (a0 + a1) + (a2 + a3);
        }
        for (; j < has; j++) {
            const float a = __shfl(w, j);
            const int sj = __shfl(s, j);
            acc += a * feat[(size_t)sj * 64 + lane];
            ws += a;
        }
    }
    out[(size_t)node * 64 + lane] = acc / ws;
}

// ---------------------------------------------------------------------------
extern "C" void kernel_launch(void* const* d_in, const int* in_sizes, int n_in,
                              void* d_out, int out_size, void* d_ws, size_t ws_size,
                              hipStream_t stream) {
    const float* h   = (const float*)d_in[0];
    const int*   src = (const int*)d_in[1];
    const int*   dst = (const int*)d_in[2];
    const float* W1  = (const float*)d_in[3];
    const float* al1 = (const float*)d_in[4];
    const float* ar1 = (const float*)d_in[5];
    const float* W2  = (const float*)d_in[6];
    const float* al2 = (const float*)d_in[7];
    const float* ar2 = (const float*)d_in[8];
    float* out = (float*)d_out;

    // workspace carve (16B-aligned chunks)
    char* p = (char*)d_ws;
    ushort* feat1bf = (ushort*)p; p += (size_t)N_NODES * 512 * 2;  // 10.24 MB
    float* feat2 = (float*)p;  p += (size_t)N_NODES * 64 * 4;      // 2.56 MB
    float* el1   = (float*)p;  p += (size_t)N_NODES * 8 * 4;
    float* er1   = (float*)p;  p += (size_t)N_NODES * 8 * 4;
    float* el2   = (float*)p;  p += (size_t)N_NODES * 4;
    float* er2   = (float*)p;  p += (size_t)N_NODES * 4;
    ushort* xhi  = (ushort*)p; p += (size_t)N_NODES * 512 * 2;     // h_hi -> x1_hi
    ushort* xlo  = (ushort*)p; p += (size_t)N_NODES * 512 * 2;     // h_lo -> x1_lo
    ushort* w1thi = (ushort*)p; p += (size_t)512 * 512 * 2;
    ushort* w1tlo = (ushort*)p; p += (size_t)512 * 512 * 2;
    ushort* w2thi = (ushort*)p; p += (size_t)64 * 512 * 2;
    ushort* w2tlo = (ushort*)p; p += (size_t)64 * 512 * 2;
    float* wl2   = (float*)p;  p += (size_t)512 * 4;
    float* wr2   = (float*)p;  p += (size_t)512 * 4;
    int* counts  = (int*)p;    p += (size_t)N_NODES * 4;
    int* offs    = (int*)p;    p += (size_t)10004 * 4;
    int* cursor  = (int*)p;    p += (size_t)N_NODES * 4;
    int* srcs    = (int*)p;    p += (size_t)N_EDGES * 4;

    // ---- fused prep ----
    prep_kernel<<<NB_SPLIT + NB_W1 + NB_W2 + NB_WLR2 + NB_ZERO, 256, 0, stream>>>(
        (const float4*)h, xhi, xlo, W1, w1thi, w1tlo, W2, w2thi, w2tlo,
        al2, ar2, wl2, wr2, counts);

    // ---- CSR build ----
    hist_kernel<<<(N_EDGES + 255) / 256, 256, 0, stream>>>(dst, counts, N_EDGES);
    scan_kernel<<<1, 1024, 0, stream>>>(counts, offs, cursor, N_NODES);
    scatter_kernel<<<(N_EDGES + 255) / 256, 256, 0, stream>>>(src, dst, cursor, srcs, N_EDGES);

    // ---- layer 1: GEMM with fused el/er epilogue ----
    {
        dim3 grid((N_NODES + 63) / 64, 512 / 128);
        gemm_bf16x3_kernel<64, 128, 32, 64, true, true><<<grid, 256, 0, stream>>>(
            xhi, xlo, w1thi, w1tlo, feat1bf, N_NODES, 512, 512, al1, ar1, el1, er1);
    }
    agg1_kernel<<<N_NODES / 4, 256, 0, stream>>>(
        feat1bf, el1, er1, offs, srcs, xhi, xlo, wl2, wr2, el2, er2);

    // ---- layer 2 ----
    {
        dim3 grid((N_NODES + 63) / 64, 1);
        gemm_bf16x3_kernel<64, 64, 32, 32, false, false><<<grid, 256, 0, stream>>>(
            xhi, xlo, w2thi, w2tlo, feat2, N_NODES, 64, 512, nullptr, nullptr, nullptr, nullptr);
    }
    agg2_kernel<<<N_NODES / 4, 256, 0, stream>>>(feat2, el2, er2, offs, srcs, out);
}

// Round 6
// 231.440 us; speedup vs baseline: 1.5285x; 1.0142x over previous
//
#include <hip/hip_runtime.h>
#include <hip/hip_bf16.h>
#include <math.h>

typedef unsigned int u32;
typedef unsigned short ushort;

constexpr int N_NODES = 10000;
constexpr int N_EDGES = 320000;
constexpr float NEG_SLOPE = 0.2f;

typedef __attribute__((ext_vector_type(8))) short short8;   // 8 x bf16 bits
typedef __attribute__((ext_vector_type(4))) float f32x4;

// ---------------------------------------------------------------------------
// helpers
// ---------------------------------------------------------------------------
__device__ __forceinline__ float lrelu(float x) { return x > 0.f ? x : NEG_SLOPE * x; }
__device__ __forceinline__ float elu(float x)   { return x > 0.f ? x : (expf(x) - 1.f); }

__device__ __forceinline__ ushort f2bf(float x) {
    u32 b = __float_as_uint(x);
    b += 0x7FFFu + ((b >> 16) & 1u);
    return (ushort)(b >> 16);
}
__device__ __forceinline__ float bf2f(ushort u) {
    return __uint_as_float(((u32)u) << 16);
}

__device__ __forceinline__ void gload16(const void* g, void* l) {
    __builtin_amdgcn_global_load_lds(
        (__attribute__((address_space(1))) void*)g,
        (__attribute__((address_space(3))) void*)l, 16, 0, 0);
}

// ---------------------------------------------------------------------------
// prep: fused [split h] + [tiled-transpose+split W1] + [same W2] + [wl2/wr2]
//       + [zero counts]
// ---------------------------------------------------------------------------
constexpr int NB_SPLIT = (N_NODES * 512 / 4) / 256;      // 5000
constexpr int NB_T1    = 64;                             // W1: 8x8 tiles of 64x64
constexpr int NB_T2    = 8;                              // W2: 8x1 tiles
constexpr int NB_WLR2  = 2;                              // 512 threads
constexpr int NB_ZERO  = (N_NODES + 255) / 256;          // 40

__global__ void prep_kernel(const float4* __restrict__ h4,
                            ushort* __restrict__ hhi, ushort* __restrict__ hlo,
                            const float* __restrict__ W1,
                            ushort* __restrict__ w1thi, ushort* __restrict__ w1tlo,
                            const float* __restrict__ W2,
                            ushort* __restrict__ w2thi, ushort* __restrict__ w2tlo,
                            const float* __restrict__ al2, const float* __restrict__ ar2,
                            float* __restrict__ wl2, float* __restrict__ wr2,
                            int* __restrict__ counts) {
    __shared__ float smem[64][65];
    const int b = blockIdx.x;
    if (b < NB_SPLIT) {
        const int i = b * 256 + threadIdx.x;
        const float4 v = h4[i];
        ushort h0 = f2bf(v.x), h1 = f2bf(v.y), h2 = f2bf(v.z), h3 = f2bf(v.w);
        *(ushort4*)&hhi[i * 4] = make_ushort4(h0, h1, h2, h3);
        *(ushort4*)&hlo[i * 4] = make_ushort4(
            f2bf(v.x - bf2f(h0)), f2bf(v.y - bf2f(h1)),
            f2bf(v.z - bf2f(h2)), f2bf(v.w - bf2f(h3)));
    } else if (b < NB_SPLIT + NB_T1 + NB_T2) {
        // tiled transpose+split: out[n*512+k] = W[k*N+n], 64x64 tiles
        const bool isW1 = b < NB_SPLIT + NB_T1;
        const float* W = isW1 ? W1 : W2;
        ushort* thi = isW1 ? w1thi : w2thi;
        ushort* tlo = isW1 ? w1tlo : w2tlo;
        const int N  = isW1 ? 512 : 64;
        const int t  = isW1 ? (b - NB_SPLIT) : (b - NB_SPLIT - NB_T1);
        const int ti = isW1 ? (t & 7) : t;    // K-tile
        const int tj = isW1 ? (t >> 3) : 0;   // N-tile
        const int c  = threadIdx.x & 63;
        const int r0 = threadIdx.x >> 6;      // 0..3
#pragma unroll
        for (int p = 0; p < 16; p++) {
            const int r = p * 4 + r0;
            smem[r][c] = W[(size_t)(ti * 64 + r) * N + tj * 64 + c];  // coalesced over c
        }
        __syncthreads();
#pragma unroll
        for (int p = 0; p < 16; p++) {
            const int rr = p * 4 + r0;
            const float v = smem[c][rr];      // stride-65 read: conflict-free
            const ushort hh = f2bf(v);
            thi[(size_t)(tj * 64 + rr) * 512 + ti * 64 + c] = hh;
            tlo[(size_t)(tj * 64 + rr) * 512 + ti * 64 + c] = f2bf(v - bf2f(hh));
        }
    } else if (b < NB_SPLIT + NB_T1 + NB_T2 + NB_WLR2) {
        const int k = (b - NB_SPLIT - NB_T1 - NB_T2) * 256 + threadIdx.x;  // [0,512)
        float sl = 0.f, sr = 0.f;
#pragma unroll 8
        for (int d = 0; d < 64; d++) {
            const float w = W2[(size_t)k * 64 + d];
            sl += w * al2[d];
            sr += w * ar2[d];
        }
        wl2[k] = sl;
        wr2[k] = sr;
    } else {
        const int j = (b - NB_SPLIT - NB_T1 - NB_T2 - NB_WLR2) * 256 + threadIdx.x;
        if (j < N_NODES) counts[j] = 0;
    }
}

// ---------------------------------------------------------------------------
// bf16x3 MFMA GEMM; optional fused el/er epilogue (requires WN==64 so each
// wave's columns live in exactly one head: head = (n0 + wn*64)/64).
// ---------------------------------------------------------------------------
template<int BM, int BN, int WM, int WN, bool BF16OUT, bool FUSE_ELR>
__global__ __launch_bounds__(256) void gemm_bf16x3_kernel(
    const ushort* __restrict__ Ahi, const ushort* __restrict__ Alo,
    const ushort* __restrict__ Bhi, const ushort* __restrict__ Blo,
    void* __restrict__ Cout, int M, int N, int K,
    const float* __restrict__ attn_l, const float* __restrict__ attn_r,
    float* __restrict__ elp, float* __restrict__ erp) {
    constexpr int BK = 32;
    constexpr int MT_M = WM / 16, MT_N = WN / 16;
    constexpr int WAVES_N = BN / WN;
    constexpr int RA = (BM * BK * 2) / 4096;
    constexpr int RB = (BN * BK * 2) / 4096;

    __shared__ __align__(16) ushort sAhi[BM * BK];
    __shared__ __align__(16) ushort sAlo[BM * BK];
    __shared__ __align__(16) ushort sBhi[BN * BK];
    __shared__ __align__(16) ushort sBlo[BN * BK];

    const int tid = threadIdx.x;
    const int wave = tid >> 6, lane = tid & 63;
    const int m0 = blockIdx.x * BM, n0 = blockIdx.y * BN;
    const int wm = wave / WAVES_N, wn = wave % WAVES_N;
    const int quad = lane >> 4, l15 = lane & 15;

    const int fb = wave * 1024 + lane * 16;

    size_t abyte[RA];
#pragma unroll
    for (int r = 0; r < RA; r++) {
        const int f = fb + r * 4096;
        int grow = m0 + (f >> 6);
        if (grow > M - 1) grow = M - 1;
        abyte[r] = (size_t)grow * (K * 2) + (f & 63);
    }
    size_t bbyte[RB];
#pragma unroll
    for (int r = 0; r < RB; r++) {
        const int f = fb + r * 4096;
        bbyte[r] = (size_t)(n0 + (f >> 6)) * (K * 2) + (f & 63);
    }

    f32x4 acc[MT_M][MT_N] = {};

    for (int k0 = 0; k0 < K; k0 += BK) {
        __syncthreads();
        const size_t kb = (size_t)k0 * 2;
#pragma unroll
        for (int r = 0; r < RA; r++) {
            const int f = fb + r * 4096;
            gload16((const char*)Ahi + abyte[r] + kb, (char*)sAhi + f);
            gload16((const char*)Alo + abyte[r] + kb, (char*)sAlo + f);
        }
#pragma unroll
        for (int r = 0; r < RB; r++) {
            const int f = fb + r * 4096;
            gload16((const char*)Bhi + bbyte[r] + kb, (char*)sBhi + f);
            gload16((const char*)Blo + bbyte[r] + kb, (char*)sBlo + f);
        }
        __syncthreads();

        short8 ah[MT_M], al[MT_M], bh[MT_N], bl[MT_N];
#pragma unroll
        for (int mi = 0; mi < MT_M; mi++) {
            const int row = wm * WM + mi * 16 + l15;
            ah[mi] = *(const short8*)&sAhi[row * BK + quad * 8];
            al[mi] = *(const short8*)&sAlo[row * BK + quad * 8];
        }
#pragma unroll
        for (int ni = 0; ni < MT_N; ni++) {
            const int row = wn * WN + ni * 16 + l15;
            bh[ni] = *(const short8*)&sBhi[row * BK + quad * 8];
            bl[ni] = *(const short8*)&sBlo[row * BK + quad * 8];
        }
#pragma unroll
        for (int mi = 0; mi < MT_M; mi++)
#pragma unroll
            for (int ni = 0; ni < MT_N; ni++) {
                acc[mi][ni] = __builtin_amdgcn_mfma_f32_16x16x32_bf16(ah[mi], bh[ni], acc[mi][ni], 0, 0, 0);
                acc[mi][ni] = __builtin_amdgcn_mfma_f32_16x16x32_bf16(ah[mi], bl[ni], acc[mi][ni], 0, 0, 0);
                acc[mi][ni] = __builtin_amdgcn_mfma_f32_16x16x32_bf16(al[mi], bh[ni], acc[mi][ni], 0, 0, 0);
            }
    }

    // epilogue: D row = (lane>>4)*4 + reg, col = lane&15  [verified m89/m91]
#pragma unroll
    for (int mi = 0; mi < MT_M; mi++) {
#pragma unroll
        for (int r = 0; r < 4; r++) {
            const int grow = m0 + wm * WM + mi * 16 + quad * 4 + r;
            if (grow < M) {
#pragma unroll
                for (int ni = 0; ni < MT_N; ni++) {
                    const int gcol = n0 + wn * WN + ni * 16 + l15;
                    if (BF16OUT)
                        ((ushort*)Cout)[(size_t)grow * N + gcol] = f2bf(acc[mi][ni][r]);
                    else
                        ((float*)Cout)[(size_t)grow * N + gcol] = acc[mi][ni][r];
                }
            }
        }
    }

    if (FUSE_ELR) {
        const int head = (n0 + wn * 64) >> 6;
        float alv[MT_N], arv[MT_N];
#pragma unroll
        for (int ni = 0; ni < MT_N; ni++) {
            alv[ni] = attn_l[head * 64 + ni * 16 + l15];
            arv[ni] = attn_r[head * 64 + ni * 16 + l15];
        }
#pragma unroll
        for (int mi = 0; mi < MT_M; mi++) {
#pragma unroll
            for (int r = 0; r < 4; r++) {
                float pl = 0.f, pr = 0.f;
#pragma unroll
                for (int ni = 0; ni < MT_N; ni++) {
                    pl += acc[mi][ni][r] * alv[ni];
                    pr += acc[mi][ni][r] * arv[ni];
                }
#pragma unroll
                for (int o = 1; o < 16; o <<= 1) {
                    pl += __shfl_xor(pl, o);
                    pr += __shfl_xor(pr, o);
                }
                const int grow = m0 + wm * WM + mi * 16 + quad * 4 + r;
                if (l15 == 0 && grow < M) {
                    elp[grow * 8 + head] = pl;
                    erp[grow * 8 + head] = pr;
                }
            }
        }
    }
}

// ---------------------------------------------------------------------------
// CSR build
// ---------------------------------------------------------------------------
__global__ void hist_kernel(const int* __restrict__ dst, int* __restrict__ counts, int e) {
    const int i = blockIdx.x * 256 + threadIdx.x;
    if (i < e) atomicAdd(&counts[dst[i]], 1);
}

__global__ __launch_bounds__(1024) void scan_kernel(
    const int* __restrict__ counts, int* __restrict__ offs,
    int* __restrict__ cursor, int n) {
    __shared__ int wsum[16];
    const int tid = threadIdx.x;
    const int lane = tid & 63, wave = tid >> 6;
    const int base = tid * 10;
    int v[10];
    int s = 0;
#pragma unroll
    for (int i = 0; i < 10; i++) {
        v[i] = (base + i < n) ? counts[base + i] : 0;
        s += v[i];
    }
    int ps = s;
#pragma unroll
    for (int o = 1; o < 64; o <<= 1) {
        const int t = __shfl_up(ps, o);
        if (lane >= o) ps += t;
    }
    if (lane == 63) wsum[wave] = ps;
    __syncthreads();
    if (tid < 16) {
        int t = wsum[tid];
#pragma unroll
        for (int o = 1; o < 16; o <<= 1) {
            const int u = __shfl_up(t, o);
            if (tid >= o) t += u;
        }
        wsum[tid] = t;
    }
    __syncthreads();
    const int wbase = (wave > 0) ? wsum[wave - 1] : 0;
    int run = wbase + ps - s;
#pragma unroll
    for (int i = 0; i < 10; i++) {
        if (base + i < n) {
            cursor[base + i] = run;
            offs[base + i + 1] = run + v[i];
        }
        run += v[i];
    }
    if (tid == 0) offs[0] = 0;
}

__global__ void scatter_kernel(const int* __restrict__ src, const int* __restrict__ dst,
                               int* __restrict__ cursor, int* __restrict__ srcs, int e) {
    const int i = blockIdx.x * 256 + threadIdx.x;
    if (i < e) {
        const int d = dst[i];
        const int p = atomicAdd(&cursor[d], 1);
        srcs[p] = src[i];
    }
}

// ---------------------------------------------------------------------------
// Layer-1 aggregation v6: one wave per node, 8-deep software pipeline
// (8 shfl + 8 el loads + 8 16B gathers in flight). Fused layer-2 logits +
// bf16 hi/lo split of x1 in the epilogue.
// ---------------------------------------------------------------------------
__global__ __launch_bounds__(256) void agg1_kernel(
    const ushort* __restrict__ feat, const float* __restrict__ el,
    const float* __restrict__ er, const int* __restrict__ offs,
    const int* __restrict__ srcs, ushort* __restrict__ xhi, ushort* __restrict__ xlo,
    const float* __restrict__ wl2, const float* __restrict__ wr2,
    float* __restrict__ el2, float* __restrict__ er2) {
    const int tid = threadIdx.x;
    const int wave = tid >> 6, lane = tid & 63;
    const int node = blockIdx.x * 4 + wave;     // grid = 2500, exact
    const int start = offs[node];
    const int deg = offs[node + 1] - start;
    const int d0 = lane * 8;
    const int myh = lane >> 3;

    if (deg == 0) {
        const ushort4 z = make_ushort4(0, 0, 0, 0);
        *(ushort4*)&xhi[(size_t)node * 512 + d0] = z;
        *(ushort4*)&xhi[(size_t)node * 512 + d0 + 4] = z;
        *(ushort4*)&xlo[(size_t)node * 512 + d0] = z;
        *(ushort4*)&xlo[(size_t)node * 512 + d0 + 4] = z;
        if (lane == 0) { el2[node] = 0.f; er2[node] = 0.f; }
        return;
    }

    const float4 ea = *(const float4*)&er[node * 8];
    const float4 eb = *(const float4*)&er[node * 8 + 4];
    const float er_my = (myh & 4) ? ((myh & 2) ? ((myh & 1) ? eb.w : eb.z)
                                              : ((myh & 1) ? eb.y : eb.x))
                                  : ((myh & 2) ? ((myh & 1) ? ea.w : ea.z)
                                              : ((myh & 1) ? ea.y : ea.x));

    float acc[8];
#pragma unroll
    for (int i = 0; i < 8; i++) acc[i] = 0.f;
    float ws = 0.f;

    for (int base = 0; base < deg; base += 64) {
        const int has = min(64, deg - base);
        const int s = srcs[start + base + min(lane, has - 1)];
        int j = 0;
        for (; j + 8 <= has; j += 8) {
            int sq[8];
#pragma unroll
            for (int q = 0; q < 8; q++) sq[q] = __shfl(s, j + q);
            float eq[8];
#pragma unroll
            for (int q = 0; q < 8; q++) eq[q] = el[sq[q] * 8 + myh];
            short8 uq[8];
#pragma unroll
            for (int q = 0; q < 8; q++)
                uq[q] = *(const short8*)&feat[(size_t)sq[q] * 512 + d0];
            float wq[8];
#pragma unroll
            for (int q = 0; q < 8; q++) wq[q] = __expf(lrelu(eq[q] + er_my));
#pragma unroll
            for (int q = 0; q < 8; q++) {
#pragma unroll
                for (int i = 0; i < 8; i++)
                    acc[i] += wq[q] * bf2f((ushort)uq[q][i]);
                ws += wq[q];
            }
        }
        for (; j < has; j++) {
            const int sj = __shfl(s, j);
            const float w = __expf(lrelu(el[sj * 8 + myh] + er_my));
            const short8 u = *(const short8*)&feat[(size_t)sj * 512 + d0];
#pragma unroll
            for (int i = 0; i < 8; i++)
                acc[i] += w * bf2f((ushort)u[i]);
            ws += w;
        }
    }

    const float inv = 1.f / ws;
    float o[8];
#pragma unroll
    for (int i = 0; i < 8; i++) o[i] = elu(acc[i] * inv);

    // fused layer-2 logits
    const float4 wla = *(const float4*)&wl2[d0];
    const float4 wlb = *(const float4*)&wl2[d0 + 4];
    const float4 wra = *(const float4*)&wr2[d0];
    const float4 wrb = *(const float4*)&wr2[d0 + 4];
    float pl = o[0] * wla.x + o[1] * wla.y + o[2] * wla.z + o[3] * wla.w
             + o[4] * wlb.x + o[5] * wlb.y + o[6] * wlb.z + o[7] * wlb.w;
    float pr = o[0] * wra.x + o[1] * wra.y + o[2] * wra.z + o[3] * wra.w
             + o[4] * wrb.x + o[5] * wrb.y + o[6] * wrb.z + o[7] * wrb.w;
#pragma unroll
    for (int off = 32; off > 0; off >>= 1) {
        pl += __shfl_xor(pl, off);
        pr += __shfl_xor(pr, off);
    }
    if (lane == 0) { el2[node] = pl; er2[node] = pr; }

    ushort hi[8], lo[8];
#pragma unroll
    for (int i = 0; i < 8; i++) {
        hi[i] = f2bf(o[i]);
        lo[i] = f2bf(o[i] - bf2f(hi[i]));
    }
    *(ushort4*)&xhi[(size_t)node * 512 + d0]     = make_ushort4(hi[0], hi[1], hi[2], hi[3]);
    *(ushort4*)&xhi[(size_t)node * 512 + d0 + 4] = make_ushort4(hi[4], hi[5], hi[6], hi[7]);
    *(ushort4*)&xlo[(size_t)node * 512 + d0]     = make_ushort4(lo[0], lo[1], lo[2], lo[3]);
    *(ushort4*)&xlo[(size_t)node * 512 + d0 + 4] = make_ushort4(lo[4], lo[5], lo[6], lo[7]);
}

// ---------------------------------------------------------------------------
// Layer-2 aggregation v6: one wave per node, 8-deep pipeline.
// ---------------------------------------------------------------------------
__global__ __launch_bounds__(256) void agg2_kernel(
    const float* __restrict__ feat, const float* __restrict__ el,
    const float* __restrict__ er, const int* __restrict__ offs,
    const int* __restrict__ srcs, float* __restrict__ out) {
    const int tid = threadIdx.x;
    const int wave = tid >> 6, lane = tid & 63;
    const int node = blockIdx.x * 4 + wave;
    const int start = offs[node];
    const int deg = offs[node + 1] - start;
    if (deg == 0) { out[(size_t)node * 64 + lane] = 0.f; return; }
    const float ern = er[node];

    float acc = 0.f, ws = 0.f;
    for (int base = 0; base < deg; base += 64) {
        const int has = min(64, deg - base);
        const int s = srcs[start + base + min(lane, has - 1)];
        const float w = __expf(lrelu(el[s] + ern));
        int j = 0;
        for (; j + 8 <= has; j += 8) {
            float aq[8]; int sq[8];
#pragma unroll
            for (int q = 0; q < 8; q++) { aq[q] = __shfl(w, j + q); sq[q] = __shfl(s, j + q); }
            float fq[8];
#pragma unroll
            for (int q = 0; q < 8; q++) fq[q] = feat[(size_t)sq[q] * 64 + lane];
#pragma unroll
            for (int q = 0; q < 8; q++) { acc += aq[q] * fq[q]; ws += aq[q]; }
        }
        for (; j < has; j++) {
            const float a = __shfl(w, j);
            const int sj = __shfl(s, j);
            acc += a * feat[(size_t)sj * 64 + lane];
            ws += a;
        }
    }
    out[(size_t)node * 64 + lane] = acc / ws;
}

// ---------------------------------------------------------------------------
extern "C" void kernel_launch(void* const* d_in, const int* in_sizes, int n_in,
                              void* d_out, int out_size, void* d_ws, size_t ws_size,
                              hipStream_t stream) {
    const float* h   = (const float*)d_in[0];
    const int*   src = (const int*)d_in[1];
    const int*   dst = (const int*)d_in[2];
    const float* W1  = (const float*)d_in[3];
    const float* al1 = (const float*)d_in[4];
    const float* ar1 = (const float*)d_in[5];
    const float* W2  = (const float*)d_in[6];
    const float* al2 = (const float*)d_in[7];
    const float* ar2 = (const float*)d_in[8];
    float* out = (float*)d_out;

    // workspace carve (16B-aligned chunks)
    char* p = (char*)d_ws;
    ushort* feat1bf = (ushort*)p; p += (size_t)N_NODES * 512 * 2;  // 10.24 MB
    float* feat2 = (float*)p;  p += (size_t)N_NODES * 64 * 4;      // 2.56 MB
    float* el1   = (float*)p;  p += (size_t)N_NODES * 8 * 4;
    float* er1   = (float*)p;  p += (size_t)N_NODES * 8 * 4;
    float* el2   = (float*)p;  p += (size_t)N_NODES * 4;
    float* er2   = (float*)p;  p += (size_t)N_NODES * 4;
    ushort* xhi  = (ushort*)p; p += (size_t)N_NODES * 512 * 2;     // h_hi -> x1_hi
    ushort* xlo  = (ushort*)p; p += (size_t)N_NODES * 512 * 2;     // h_lo -> x1_lo
    ushort* w1thi = (ushort*)p; p += (size_t)512 * 512 * 2;
    ushort* w1tlo = (ushort*)p; p += (size_t)512 * 512 * 2;
    ushort* w2thi = (ushort*)p; p += (size_t)64 * 512 * 2;
    ushort* w2tlo = (ushort*)p; p += (size_t)64 * 512 * 2;
    float* wl2   = (float*)p;  p += (size_t)512 * 4;
    float* wr2   = (float*)p;  p += (size_t)512 * 4;
    int* counts  = (int*)p;    p += (size_t)N_NODES * 4;
    int* offs    = (int*)p;    p += (size_t)10004 * 4;
    int* cursor  = (int*)p;    p += (size_t)N_NODES * 4;
    int* srcs    = (int*)p;    p += (size_t)N_EDGES * 4;

    // ---- fused prep ----
    prep_kernel<<<NB_SPLIT + NB_T1 + NB_T2 + NB_WLR2 + NB_ZERO, 256, 0, stream>>>(
        (const float4*)h, xhi, xlo, W1, w1thi, w1tlo, W2, w2thi, w2tlo,
        al2, ar2, wl2, wr2, counts);

    // ---- CSR build ----
    hist_kernel<<<(N_EDGES + 255) / 256, 256, 0, stream>>>(dst, counts, N_EDGES);
    scan_kernel<<<1, 1024, 0, stream>>>(counts, offs, cursor, N_NODES);
    scatter_kernel<<<(N_EDGES + 255) / 256, 256, 0, stream>>>(src, dst, cursor, srcs, N_EDGES);

    // ---- layer 1: GEMM with fused el/er epilogue ----
    {
        dim3 grid((N_NODES + 63) / 64, 512 / 128);
        gemm_bf16x3_kernel<64, 128, 32, 64, true, true><<<grid, 256, 0, stream>>>(
            xhi, xlo, w1thi, w1tlo, feat1bf, N_NODES, 512, 512, al1, ar1, el1, er1);
    }
    agg1_kernel<<<N_NODES / 4, 256, 0, stream>>>(
        feat1bf, el1, er1, offs, srcs, xhi, xlo, wl2, wr2, el2, er2);

    // ---- layer 2 ----
    {
        dim3 grid((N_NODES + 63) / 64, 1);
        gemm_bf16x3_kernel<64, 64, 32, 32, false, false><<<grid, 256, 0, stream>>>(
            xhi, xlo, w2thi, w2tlo, feat2, N_NODES, 64, 512, nullptr, nullptr, nullptr, nullptr);
    }
    agg2_kernel<<<N_NODES / 4, 256, 0, stream>>>(feat2, el2, er2, offs, srcs, out);
}

// Round 7
// 217.843 us; speedup vs baseline: 1.6239x; 1.0624x over previous
//
#include <hip/hip_runtime.h>
#include <hip/hip_bf16.h>
#include <math.h>

typedef unsigned int u32;
typedef unsigned short ushort;

constexpr int N_NODES = 10000;
constexpr int N_EDGES = 320000;
constexpr float NEG_SLOPE = 0.2f;

typedef __attribute__((ext_vector_type(8))) short short8;    // 8 x bf16 bits
typedef __attribute__((ext_vector_type(4))) float f32x4;
typedef __attribute__((ext_vector_type(16))) float f32x16;

// ---------------------------------------------------------------------------
// helpers
// ---------------------------------------------------------------------------
__device__ __forceinline__ float lrelu(float x) { return x > 0.f ? x : NEG_SLOPE * x; }
__device__ __forceinline__ float elu(float x)   { return x > 0.f ? x : (expf(x) - 1.f); }

__device__ __forceinline__ ushort f2bf(float x) {
    u32 b = __float_as_uint(x);
    b += 0x7FFFu + ((b >> 16) & 1u);
    return (ushort)(b >> 16);
}
__device__ __forceinline__ float bf2f(ushort u) {
    return __uint_as_float(((u32)u) << 16);
}

__device__ __forceinline__ void gload16(const void* g, void* l) {
    __builtin_amdgcn_global_load_lds(
        (__attribute__((address_space(1))) void*)g,
        (__attribute__((address_space(3))) void*)l, 16, 0, 0);
}

// ---------------------------------------------------------------------------
// prep: fused [split h] + [tiled-transpose+split W1] + [same W2] + [wl2/wr2]
//       + [zero counts]
// ---------------------------------------------------------------------------
constexpr int NB_SPLIT = (N_NODES * 512 / 4) / 256;      // 5000
constexpr int NB_T1    = 64;                             // W1: 8x8 tiles of 64x64
constexpr int NB_T2    = 8;                              // W2: 8x1 tiles
constexpr int NB_WLR2  = 2;                              // 512 threads
constexpr int NB_ZERO  = (N_NODES + 255) / 256;          // 40

__global__ void prep_kernel(const float4* __restrict__ h4,
                            ushort* __restrict__ hhi, ushort* __restrict__ hlo,
                            const float* __restrict__ W1,
                            ushort* __restrict__ w1thi, ushort* __restrict__ w1tlo,
                            const float* __restrict__ W2,
                            ushort* __restrict__ w2thi, ushort* __restrict__ w2tlo,
                            const float* __restrict__ al2, const float* __restrict__ ar2,
                            float* __restrict__ wl2, float* __restrict__ wr2,
                            int* __restrict__ counts) {
    __shared__ float smem[64][65];
    const int b = blockIdx.x;
    if (b < NB_SPLIT) {
        const int i = b * 256 + threadIdx.x;
        const float4 v = h4[i];
        ushort h0 = f2bf(v.x), h1 = f2bf(v.y), h2 = f2bf(v.z), h3 = f2bf(v.w);
        *(ushort4*)&hhi[i * 4] = make_ushort4(h0, h1, h2, h3);
        *(ushort4*)&hlo[i * 4] = make_ushort4(
            f2bf(v.x - bf2f(h0)), f2bf(v.y - bf2f(h1)),
            f2bf(v.z - bf2f(h2)), f2bf(v.w - bf2f(h3)));
    } else if (b < NB_SPLIT + NB_T1 + NB_T2) {
        const bool isW1 = b < NB_SPLIT + NB_T1;
        const float* W = isW1 ? W1 : W2;
        ushort* thi = isW1 ? w1thi : w2thi;
        ushort* tlo = isW1 ? w1tlo : w2tlo;
        const int N  = isW1 ? 512 : 64;
        const int t  = isW1 ? (b - NB_SPLIT) : (b - NB_SPLIT - NB_T1);
        const int ti = isW1 ? (t & 7) : t;    // K-tile
        const int tj = isW1 ? (t >> 3) : 0;   // N-tile
        const int c  = threadIdx.x & 63;
        const int r0 = threadIdx.x >> 6;      // 0..3
#pragma unroll
        for (int p = 0; p < 16; p++) {
            const int r = p * 4 + r0;
            smem[r][c] = W[(size_t)(ti * 64 + r) * N + tj * 64 + c];
        }
        __syncthreads();
#pragma unroll
        for (int p = 0; p < 16; p++) {
            const int rr = p * 4 + r0;
            const float v = smem[c][rr];
            const ushort hh = f2bf(v);
            thi[(size_t)(tj * 64 + rr) * 512 + ti * 64 + c] = hh;
            tlo[(size_t)(tj * 64 + rr) * 512 + ti * 64 + c] = f2bf(v - bf2f(hh));
        }
    } else if (b < NB_SPLIT + NB_T1 + NB_T2 + NB_WLR2) {
        const int k = (b - NB_SPLIT - NB_T1 - NB_T2) * 256 + threadIdx.x;
        float sl = 0.f, sr = 0.f;
#pragma unroll 8
        for (int d = 0; d < 64; d++) {
            const float w = W2[(size_t)k * 64 + d];
            sl += w * al2[d];
            sr += w * ar2[d];
        }
        wl2[k] = sl;
        wr2[k] = sr;
    } else {
        const int j = (b - NB_SPLIT - NB_T1 - NB_T2 - NB_WLR2) * 256 + threadIdx.x;
        if (j < N_NODES) counts[j] = 0;
    }
}

// ---------------------------------------------------------------------------
// GEMM1 (layer 1): 32x32x16 bf16 MFMA, bf16x3 split, BM=64 BN=128 BK=32,
// bf16 output + fused el/er epilogue.
// waves: 2x2 (wm=wave>>1, wn=wave&1); per wave: 1x2 tiles of 32x32.
// A as hi/lo (M x K), B transposed hi/lo (N x K).
// C layout (m74/m101): col=lane&31, row=(reg&3)+8*(reg>>2)+4*(lane>>5).
// ---------------------------------------------------------------------------
__global__ __launch_bounds__(256) void gemm1_kernel(
    const ushort* __restrict__ Ahi, const ushort* __restrict__ Alo,
    const ushort* __restrict__ Bhi, const ushort* __restrict__ Blo,
    ushort* __restrict__ Cout, int M,
    const float* __restrict__ attn_l, const float* __restrict__ attn_r,
    float* __restrict__ elp, float* __restrict__ erp) {
    constexpr int BM = 64, BN = 128, BK = 32, K = 512, N = 512;

    __shared__ __align__(16) ushort sAhi[BM * BK];
    __shared__ __align__(16) ushort sAlo[BM * BK];
    __shared__ __align__(16) ushort sBhi[BN * BK];
    __shared__ __align__(16) ushort sBlo[BN * BK];

    const int tid = threadIdx.x;
    const int wave = tid >> 6, lane = tid & 63;
    const int m0 = blockIdx.x * BM, n0 = blockIdx.y * BN;
    const int wm = wave >> 1, wn = wave & 1;
    const int l31 = lane & 31, lh = lane >> 5;   // half: 0/1

    const int fb = wave * 1024 + lane * 16;      // flat byte offset per round

    // A tile: 64 rows x 32 k x 2B = 4096 B -> 1 round; B tile: 8192 B -> 2
    int arow = m0 + (fb >> 6);
    if (arow > M - 1) arow = M - 1;
    const size_t abyte = (size_t)arow * (K * 2) + (fb & 63);
    size_t bbyte[2];
#pragma unroll
    for (int r = 0; r < 2; r++) {
        const int f = fb + r * 4096;
        bbyte[r] = (size_t)(n0 + (f >> 6)) * (K * 2) + (f & 63);
    }

    f32x16 acc[2] = {};

    for (int k0 = 0; k0 < K; k0 += BK) {
        __syncthreads();
        const size_t kb = (size_t)k0 * 2;
        gload16((const char*)Ahi + abyte + kb, (char*)sAhi + fb);
        gload16((const char*)Alo + abyte + kb, (char*)sAlo + fb);
#pragma unroll
        for (int r = 0; r < 2; r++) {
            const int f = fb + r * 4096;
            gload16((const char*)Bhi + bbyte[r] + kb, (char*)sBhi + f);
            gload16((const char*)Blo + bbyte[r] + kb, (char*)sBlo + f);
        }
        __syncthreads();

#pragma unroll
        for (int ks = 0; ks < 2; ks++) {          // two 16-wide K steps
            const int koff = ks * 16 + lh * 8;
            const int arw = wm * 32 + l31;
            const short8 ah = *(const short8*)&sAhi[arw * BK + koff];
            const short8 al = *(const short8*)&sAlo[arw * BK + koff];
            short8 bh[2], bl[2];
#pragma unroll
            for (int ni = 0; ni < 2; ni++) {
                const int brw = wn * 64 + ni * 32 + l31;
                bh[ni] = *(const short8*)&sBhi[brw * BK + koff];
                bl[ni] = *(const short8*)&sBlo[brw * BK + koff];
            }
#pragma unroll
            for (int ni = 0; ni < 2; ni++) {
                acc[ni] = __builtin_amdgcn_mfma_f32_32x32x16_bf16(ah, bh[ni], acc[ni], 0, 0, 0);
                acc[ni] = __builtin_amdgcn_mfma_f32_32x32x16_bf16(ah, bl[ni], acc[ni], 0, 0, 0);
                acc[ni] = __builtin_amdgcn_mfma_f32_32x32x16_bf16(al, bh[ni], acc[ni], 0, 0, 0);
            }
        }
    }

    // ---- epilogue: bf16 C write ----
#pragma unroll
    for (int reg = 0; reg < 16; reg++) {
        const int grow = m0 + wm * 32 + (reg & 3) + 8 * (reg >> 2) + 4 * lh;
        if (grow < M) {
#pragma unroll
            for (int ni = 0; ni < 2; ni++) {
                const int gcol = n0 + wn * 64 + ni * 32 + l31;
                Cout[(size_t)grow * N + gcol] = f2bf(acc[ni][reg]);
            }
        }
    }

    // ---- fused el/er (head per wave: WN=64 spans exactly one head) ----
    const int head = (n0 + wn * 64) >> 6;
    float alv[2], arv[2];
#pragma unroll
    for (int ni = 0; ni < 2; ni++) {
        alv[ni] = attn_l[head * 64 + ni * 32 + l31];
        arv[ni] = attn_r[head * 64 + ni * 32 + l31];
    }
#pragma unroll
    for (int reg = 0; reg < 16; reg++) {
        float pl = acc[0][reg] * alv[0] + acc[1][reg] * alv[1];
        float pr = acc[0][reg] * arv[0] + acc[1][reg] * arv[1];
#pragma unroll
        for (int o = 1; o < 32; o <<= 1) {        // reduce within each 32-half
            pl += __shfl_xor(pl, o);
            pr += __shfl_xor(pr, o);
        }
        const int grow = m0 + wm * 32 + (reg & 3) + 8 * (reg >> 2) + 4 * lh;
        if (l31 == 0 && grow < M) {
            elp[grow * 8 + head] = pl;
            erp[grow * 8 + head] = pr;
        }
    }
}

// ---------------------------------------------------------------------------
// GEMM2 (layer 2): 16x16x32 bf16x3, BM=64 BN=64, fp32 out (unchanged shape).
// ---------------------------------------------------------------------------
__global__ __launch_bounds__(256) void gemm2_kernel(
    const ushort* __restrict__ Ahi, const ushort* __restrict__ Alo,
    const ushort* __restrict__ Bhi, const ushort* __restrict__ Blo,
    float* __restrict__ Cout, int M) {
    constexpr int BM = 64, BN = 64, BK = 32, K = 512, N = 64;
    constexpr int WM = 32, WN = 32, MT_M = 2, MT_N = 2;

    __shared__ __align__(16) ushort sAhi[BM * BK];
    __shared__ __align__(16) ushort sAlo[BM * BK];
    __shared__ __align__(16) ushort sBhi[BN * BK];
    __shared__ __align__(16) ushort sBlo[BN * BK];

    const int tid = threadIdx.x;
    const int wave = tid >> 6, lane = tid & 63;
    const int m0 = blockIdx.x * BM;
    const int wm = wave >> 1, wn = wave & 1;
    const int quad = lane >> 4, l15 = lane & 15;

    const int fb = wave * 1024 + lane * 16;

    int arow = m0 + (fb >> 6);
    if (arow > M - 1) arow = M - 1;
    const size_t abyte = (size_t)arow * (K * 2) + (fb & 63);
    const size_t bbyte = (size_t)(fb >> 6) * (K * 2) + (fb & 63);

    f32x4 acc[MT_M][MT_N] = {};

    for (int k0 = 0; k0 < K; k0 += BK) {
        __syncthreads();
        const size_t kb = (size_t)k0 * 2;
        gload16((const char*)Ahi + abyte + kb, (char*)sAhi + fb);
        gload16((const char*)Alo + abyte + kb, (char*)sAlo + fb);
        gload16((const char*)Bhi + bbyte + kb, (char*)sBhi + fb);
        gload16((const char*)Blo + bbyte + kb, (char*)sBlo + fb);
        __syncthreads();

        short8 ah[MT_M], al[MT_M], bh[MT_N], bl[MT_N];
#pragma unroll
        for (int mi = 0; mi < MT_M; mi++) {
            const int row = wm * WM + mi * 16 + l15;
            ah[mi] = *(const short8*)&sAhi[row * BK + quad * 8];
            al[mi] = *(const short8*)&sAlo[row * BK + quad * 8];
        }
#pragma unroll
        for (int ni = 0; ni < MT_N; ni++) {
            const int row = wn * WN + ni * 16 + l15;
            bh[ni] = *(const short8*)&sBhi[row * BK + quad * 8];
            bl[ni] = *(const short8*)&sBlo[row * BK + quad * 8];
        }
#pragma unroll
        for (int mi = 0; mi < MT_M; mi++)
#pragma unroll
            for (int ni = 0; ni < MT_N; ni++) {
                acc[mi][ni] = __builtin_amdgcn_mfma_f32_16x16x32_bf16(ah[mi], bh[ni], acc[mi][ni], 0, 0, 0);
                acc[mi][ni] = __builtin_amdgcn_mfma_f32_16x16x32_bf16(ah[mi], bl[ni], acc[mi][ni], 0, 0, 0);
                acc[mi][ni] = __builtin_amdgcn_mfma_f32_16x16x32_bf16(al[mi], bh[ni], acc[mi][ni], 0, 0, 0);
            }
    }

#pragma unroll
    for (int mi = 0; mi < MT_M; mi++) {
#pragma unroll
        for (int r = 0; r < 4; r++) {
            const int grow = m0 + wm * WM + mi * 16 + quad * 4 + r;
            if (grow < M) {
#pragma unroll
                for (int ni = 0; ni < MT_N; ni++) {
                    const int gcol = wn * WN + ni * 16 + l15;
                    Cout[(size_t)grow * N + gcol] = acc[mi][ni][r];
                }
            }
        }
    }
}

// ---------------------------------------------------------------------------
// CSR build: hist also records each edge's rank within its dst (atomic return
// value) so scatter needs NO atomics.
// ---------------------------------------------------------------------------
__global__ void hist_kernel(const int* __restrict__ dst, int* __restrict__ counts,
                            int* __restrict__ rank, int e) {
    const int i = blockIdx.x * 256 + threadIdx.x;
    if (i < e) rank[i] = atomicAdd(&counts[dst[i]], 1);
}

__global__ __launch_bounds__(1024) void scan_kernel(
    const int* __restrict__ counts, int* __restrict__ offs, int n) {
    __shared__ int wsum[16];
    const int tid = threadIdx.x;
    const int lane = tid & 63, wave = tid >> 6;
    const int base = tid * 10;
    int v[10];
    int s = 0;
#pragma unroll
    for (int i = 0; i < 10; i++) {
        v[i] = (base + i < n) ? counts[base + i] : 0;
        s += v[i];
    }
    int ps = s;
#pragma unroll
    for (int o = 1; o < 64; o <<= 1) {
        const int t = __shfl_up(ps, o);
        if (lane >= o) ps += t;
    }
    if (lane == 63) wsum[wave] = ps;
    __syncthreads();
    if (tid < 16) {
        int t = wsum[tid];
#pragma unroll
        for (int o = 1; o < 16; o <<= 1) {
            const int u = __shfl_up(t, o);
            if (tid >= o) t += u;
        }
        wsum[tid] = t;
    }
    __syncthreads();
    const int wbase = (wave > 0) ? wsum[wave - 1] : 0;
    int run = wbase + ps - s;
#pragma unroll
    for (int i = 0; i < 10; i++) {
        if (base + i < n) offs[base + i + 1] = run + v[i];
        run += v[i];
    }
    if (tid == 0) offs[0] = 0;
}

__global__ void scatter_kernel(const int* __restrict__ src, const int* __restrict__ dst,
                               const int* __restrict__ rank, const int* __restrict__ offs,
                               int* __restrict__ srcs, int e) {
    const int i = blockIdx.x * 256 + threadIdx.x;
    if (i < e) srcs[offs[dst[i]] + rank[i]] = src[i];
}

// ---------------------------------------------------------------------------
// Layer-1 aggregation: one wave per node, 8-deep software pipeline.
// Fused layer-2 logits + bf16 hi/lo split of x1.
// ---------------------------------------------------------------------------
__global__ __launch_bounds__(256) void agg1_kernel(
    const ushort* __restrict__ feat, const float* __restrict__ el,
    const float* __restrict__ er, const int* __restrict__ offs,
    const int* __restrict__ srcs, ushort* __restrict__ xhi, ushort* __restrict__ xlo,
    const float* __restrict__ wl2, const float* __restrict__ wr2,
    float* __restrict__ el2, float* __restrict__ er2) {
    const int tid = threadIdx.x;
    const int wave = tid >> 6, lane = tid & 63;
    const int node = blockIdx.x * 4 + wave;
    const int start = offs[node];
    const int deg = offs[node + 1] - start;
    const int d0 = lane * 8;
    const int myh = lane >> 3;

    if (deg == 0) {
        const ushort4 z = make_ushort4(0, 0, 0, 0);
        *(ushort4*)&xhi[(size_t)node * 512 + d0] = z;
        *(ushort4*)&xhi[(size_t)node * 512 + d0 + 4] = z;
        *(ushort4*)&xlo[(size_t)node * 512 + d0] = z;
        *(ushort4*)&xlo[(size_t)node * 512 + d0 + 4] = z;
        if (lane == 0) { el2[node] = 0.f; er2[node] = 0.f; }
        return;
    }

    const float4 ea = *(const float4*)&er[node * 8];
    const float4 eb = *(const float4*)&er[node * 8 + 4];
    const float er_my = (myh & 4) ? ((myh & 2) ? ((myh & 1) ? eb.w : eb.z)
                                              : ((myh & 1) ? eb.y : eb.x))
                                  : ((myh & 2) ? ((myh & 1) ? ea.w : ea.z)
                                              : ((myh & 1) ? ea.y : ea.x));

    float acc[8];
#pragma unroll
    for (int i = 0; i < 8; i++) acc[i] = 0.f;
    float ws = 0.f;

    for (int base = 0; base < deg; base += 64) {
        const int has = min(64, deg - base);
        const int s = srcs[start + base + min(lane, has - 1)];
        int j = 0;
        for (; j + 8 <= has; j += 8) {
            int sq[8];
#pragma unroll
            for (int q = 0; q < 8; q++) sq[q] = __shfl(s, j + q);
            float eq[8];
#pragma unroll
            for (int q = 0; q < 8; q++) eq[q] = el[sq[q] * 8 + myh];
            short8 uq[8];
#pragma unroll
            for (int q = 0; q < 8; q++)
                uq[q] = *(const short8*)&feat[(size_t)sq[q] * 512 + d0];
            float wq[8];
#pragma unroll
            for (int q = 0; q < 8; q++) wq[q] = __expf(lrelu(eq[q] + er_my));
#pragma unroll
            for (int q = 0; q < 8; q++) {
#pragma unroll
                for (int i = 0; i < 8; i++)
                    acc[i] += wq[q] * bf2f((ushort)uq[q][i]);
                ws += wq[q];
            }
        }
        for (; j < has; j++) {
            const int sj = __shfl(s, j);
            const float w = __expf(lrelu(el[sj * 8 + myh] + er_my));
            const short8 u = *(const short8*)&feat[(size_t)sj * 512 + d0];
#pragma unroll
            for (int i = 0; i < 8; i++)
                acc[i] += w * bf2f((ushort)u[i]);
            ws += w;
        }
    }

    const float inv = 1.f / ws;
    float o[8];
#pragma unroll
    for (int i = 0; i < 8; i++) o[i] = elu(acc[i] * inv);

    const float4 wla = *(const float4*)&wl2[d0];
    const float4 wlb = *(const float4*)&wl2[d0 + 4];
    const float4 wra = *(const float4*)&wr2[d0];
    const float4 wrb = *(const float4*)&wr2[d0 + 4];
    float pl = o[0] * wla.x + o[1] * wla.y + o[2] * wla.z + o[3] * wla.w
             + o[4] * wlb.x + o[5] * wlb.y + o[6] * wlb.z + o[7] * wlb.w;
    float pr = o[0] * wra.x + o[1] * wra.y + o[2] * wra.z + o[3] * wra.w
             + o[4] * wrb.x + o[5] * wrb.y + o[6] * wrb.z + o[7] * wrb.w;
#pragma unroll
    for (int off = 32; off > 0; off >>= 1) {
        pl += __shfl_xor(pl, off);
        pr += __shfl_xor(pr, off);
    }
    if (lane == 0) { el2[node] = pl; er2[node] = pr; }

    ushort hi[8], lo[8];
#pragma unroll
    for (int i = 0; i < 8; i++) {
        hi[i] = f2bf(o[i]);
        lo[i] = f2bf(o[i] - bf2f(hi[i]));
    }
    *(ushort4*)&xhi[(size_t)node * 512 + d0]     = make_ushort4(hi[0], hi[1], hi[2], hi[3]);
    *(ushort4*)&xhi[(size_t)node * 512 + d0 + 4] = make_ushort4(hi[4], hi[5], hi[6], hi[7]);
    *(ushort4*)&xlo[(size_t)node * 512 + d0]     = make_ushort4(lo[0], lo[1], lo[2], lo[3]);
    *(ushort4*)&xlo[(size_t)node * 512 + d0 + 4] = make_ushort4(lo[4], lo[5], lo[6], lo[7]);
}

// ---------------------------------------------------------------------------
// Layer-2 aggregation: one wave per node, 8-deep pipeline.
// ---------------------------------------------------------------------------
__global__ __launch_bounds__(256) void agg2_kernel(
    const float* __restrict__ feat, const float* __restrict__ el,
    const float* __restrict__ er, const int* __restrict__ offs,
    const int* __restrict__ srcs, float* __restrict__ out) {
    const int tid = threadIdx.x;
    const int wave = tid >> 6, lane = tid & 63;
    const int node = blockIdx.x * 4 + wave;
    const int start = offs[node];
    const int deg = offs[node + 1] - start;
    if (deg == 0) { out[(size_t)node * 64 + lane] = 0.f; return; }
    const float ern = er[node];

    float acc = 0.f, ws = 0.f;
    for (int base = 0; base < deg; base += 64) {
        const int has = min(64, deg - base);
        const int s = srcs[start + base + min(lane, has - 1)];
        const float w = __expf(lrelu(el[s] + ern));
        int j = 0;
        for (; j + 8 <= has; j += 8) {
            float aq[8]; int sq[8];
#pragma unroll
            for (int q = 0; q < 8; q++) { aq[q] = __shfl(w, j + q); sq[q] = __shfl(s, j + q); }
            float fq[8];
#pragma unroll
            for (int q = 0; q < 8; q++) fq[q] = feat[(size_t)sq[q] * 64 + lane];
#pragma unroll
            for (int q = 0; q < 8; q++) { acc += aq[q] * fq[q]; ws += aq[q]; }
        }
        for (; j < has; j++) {
            const float a = __shfl(w, j);
            const int sj = __shfl(s, j);
            acc += a * feat[(size_t)sj * 64 + lane];
            ws += a;
        }
    }
    out[(size_t)node * 64 + lane] = acc / ws;
}

// ---------------------------------------------------------------------------
extern "C" void kernel_launch(void* const* d_in, const int* in_sizes, int n_in,
                              void* d_out, int out_size, void* d_ws, size_t ws_size,
                              hipStream_t stream) {
    const float* h   = (const float*)d_in[0];
    const int*   src = (const int*)d_in[1];
    const int*   dst = (const int*)d_in[2];
    const float* W1  = (const float*)d_in[3];
    const float* al1 = (const float*)d_in[4];
    const float* ar1 = (const float*)d_in[5];
    const float* W2  = (const float*)d_in[6];
    const float* al2 = (const float*)d_in[7];
    const float* ar2 = (const float*)d_in[8];
    float* out = (float*)d_out;

    // workspace carve (16B-aligned chunks)
    char* p = (char*)d_ws;
    ushort* feat1bf = (ushort*)p; p += (size_t)N_NODES * 512 * 2;  // 10.24 MB
    float* feat2 = (float*)p;  p += (size_t)N_NODES * 64 * 4;      // 2.56 MB
    float* el1   = (float*)p;  p += (size_t)N_NODES * 8 * 4;
    float* er1   = (float*)p;  p += (size_t)N_NODES * 8 * 4;
    float* el2   = (float*)p;  p += (size_t)N_NODES * 4;
    float* er2   = (float*)p;  p += (size_t)N_NODES * 4;
    ushort* xhi  = (ushort*)p; p += (size_t)N_NODES * 512 * 2;     // h_hi -> x1_hi
    ushort* xlo  = (ushort*)p; p += (size_t)N_NODES * 512 * 2;     // h_lo -> x1_lo
    ushort* w1thi = (ushort*)p; p += (size_t)512 * 512 * 2;
    ushort* w1tlo = (ushort*)p; p += (size_t)512 * 512 * 2;
    ushort* w2thi = (ushort*)p; p += (size_t)64 * 512 * 2;
    ushort* w2tlo = (ushort*)p; p += (size_t)64 * 512 * 2;
    float* wl2   = (float*)p;  p += (size_t)512 * 4;
    float* wr2   = (float*)p;  p += (size_t)512 * 4;
    int* counts  = (int*)p;    p += (size_t)N_NODES * 4;
    int* offs    = (int*)p;    p += (size_t)10004 * 4;
    int* rank    = (int*)p;    p += (size_t)N_EDGES * 4;
    int* srcs    = (int*)p;    p += (size_t)N_EDGES * 4;

    // ---- fused prep ----
    prep_kernel<<<NB_SPLIT + NB_T1 + NB_T2 + NB_WLR2 + NB_ZERO, 256, 0, stream>>>(
        (const float4*)h, xhi, xlo, W1, w1thi, w1tlo, W2, w2thi, w2tlo,
        al2, ar2, wl2, wr2, counts);

    // ---- CSR build (rank trick: scatter is atomic-free) ----
    hist_kernel<<<(N_EDGES + 255) / 256, 256, 0, stream>>>(dst, counts, rank, N_EDGES);
    scan_kernel<<<1, 1024, 0, stream>>>(counts, offs, N_NODES);
    scatter_kernel<<<(N_EDGES + 255) / 256, 256, 0, stream>>>(src, dst, rank, offs, srcs, N_EDGES);

    // ---- layer 1: 32x32x16 GEMM with fused el/er epilogue ----
    {
        dim3 grid((N_NODES + 63) / 64, 512 / 128);
        gemm1_kernel<<<grid, 256, 0, stream>>>(
            xhi, xlo, w1thi, w1tlo, feat1bf, N_NODES, al1, ar1, el1, er1);
    }
    agg1_kernel<<<N_NODES / 4, 256, 0, stream>>>(
        feat1bf, el1, er1, offs, srcs, xhi, xlo, wl2, wr2, el2, er2);

    // ---- layer 2 ----
    gemm2_kernel<<<(N_NODES + 63) / 64, 256, 0, stream>>>(
        xhi, xlo, w2thi, w2tlo, feat2, N_NODES);
    agg2_kernel<<<N_NODES / 4, 256, 0, stream>>>(feat2, el2, er2, offs, srcs, out);
}

// Round 8
// 213.467 us; speedup vs baseline: 1.6572x; 1.0205x over previous
//
#include <hip/hip_runtime.h>
#include <hip/hip_bf16.h>
#include <math.h>

typedef unsigned int u32;
typedef unsigned short ushort;

constexpr int N_NODES = 10000;
constexpr int N_EDGES = 320000;
constexpr float NEG_SLOPE = 0.2f;

typedef __attribute__((ext_vector_type(8))) short short8;    // 8 x bf16 bits
typedef __attribute__((ext_vector_type(4))) float f32x4;
typedef __attribute__((ext_vector_type(16))) float f32x16;

// ---------------------------------------------------------------------------
// helpers
// ---------------------------------------------------------------------------
__device__ __forceinline__ float lrelu(float x) { return x > 0.f ? x : NEG_SLOPE * x; }
__device__ __forceinline__ float elu(float x)   { return x > 0.f ? x : (expf(x) - 1.f); }

__device__ __forceinline__ ushort f2bf(float x) {
    u32 b = __float_as_uint(x);
    b += 0x7FFFu + ((b >> 16) & 1u);
    return (ushort)(b >> 16);
}
__device__ __forceinline__ float bf2f(ushort u) {
    return __uint_as_float(((u32)u) << 16);
}

__device__ __forceinline__ void gload16(const void* g, void* l) {
    __builtin_amdgcn_global_load_lds(
        (__attribute__((address_space(1))) void*)g,
        (__attribute__((address_space(3))) void*)l, 16, 0, 0);
}

// ---------------------------------------------------------------------------
// kernel 0: zero counts + wl2/wr2 precompute (must precede fused prep+hist)
// ---------------------------------------------------------------------------
constexpr int NBZ_CNT = (N_NODES + 255) / 256;   // 40
__global__ void zero_kernel(int* __restrict__ counts,
                            const float* __restrict__ W2,
                            const float* __restrict__ al2, const float* __restrict__ ar2,
                            float* __restrict__ wl2, float* __restrict__ wr2) {
    const int b = blockIdx.x;
    if (b < NBZ_CNT) {
        const int j = b * 256 + threadIdx.x;
        if (j < N_NODES) counts[j] = 0;
    } else {
        const int k = (b - NBZ_CNT) * 256 + threadIdx.x;  // [0,512)
        float sl = 0.f, sr = 0.f;
#pragma unroll 8
        for (int d = 0; d < 64; d++) {
            const float w = W2[(size_t)k * 64 + d];
            sl += w * al2[d];
            sr += w * ar2[d];
        }
        wl2[k] = sl;
        wr2[k] = sr;
    }
}

// ---------------------------------------------------------------------------
// kernel 1: fused [split h] + [transpose+split W1/W2] + [hist(+rank)]
// hist overlaps the split work (counts pre-zeroed by zero_kernel).
// ---------------------------------------------------------------------------
constexpr int NB_SPLIT = (N_NODES * 512 / 4) / 256;      // 5000
constexpr int NB_T1    = 64;                             // W1: 8x8 tiles of 64x64
constexpr int NB_T2    = 8;                              // W2: 8x1 tiles
constexpr int NB_HIST  = (N_EDGES + 255) / 256;          // 1250

__global__ void prep_kernel(const float4* __restrict__ h4,
                            ushort* __restrict__ hhi, ushort* __restrict__ hlo,
                            const float* __restrict__ W1,
                            ushort* __restrict__ w1thi, ushort* __restrict__ w1tlo,
                            const float* __restrict__ W2,
                            ushort* __restrict__ w2thi, ushort* __restrict__ w2tlo,
                            const int* __restrict__ dst, int* __restrict__ counts,
                            int* __restrict__ rank) {
    __shared__ float smem[64][65];
    const int b = blockIdx.x;
    if (b < NB_HIST) {
        // histogram first (memory/atomic-bound; overlaps split blocks)
        const int i = b * 256 + threadIdx.x;
        if (i < N_EDGES) rank[i] = atomicAdd(&counts[dst[i]], 1);
    } else if (b < NB_HIST + NB_SPLIT) {
        const int i = (b - NB_HIST) * 256 + threadIdx.x;
        const float4 v = h4[i];
        ushort h0 = f2bf(v.x), h1 = f2bf(v.y), h2 = f2bf(v.z), h3 = f2bf(v.w);
        *(ushort4*)&hhi[i * 4] = make_ushort4(h0, h1, h2, h3);
        *(ushort4*)&hlo[i * 4] = make_ushort4(
            f2bf(v.x - bf2f(h0)), f2bf(v.y - bf2f(h1)),
            f2bf(v.z - bf2f(h2)), f2bf(v.w - bf2f(h3)));
    } else {
        const bool isW1 = b < NB_HIST + NB_SPLIT + NB_T1;
        const float* W = isW1 ? W1 : W2;
        ushort* thi = isW1 ? w1thi : w2thi;
        ushort* tlo = isW1 ? w1tlo : w2tlo;
        const int N  = isW1 ? 512 : 64;
        const int t  = isW1 ? (b - NB_HIST - NB_SPLIT) : (b - NB_HIST - NB_SPLIT - NB_T1);
        const int ti = isW1 ? (t & 7) : t;    // K-tile
        const int tj = isW1 ? (t >> 3) : 0;   // N-tile
        const int c  = threadIdx.x & 63;
        const int r0 = threadIdx.x >> 6;      // 0..3
#pragma unroll
        for (int p = 0; p < 16; p++) {
            const int r = p * 4 + r0;
            smem[r][c] = W[(size_t)(ti * 64 + r) * N + tj * 64 + c];
        }
        __syncthreads();
#pragma unroll
        for (int p = 0; p < 16; p++) {
            const int rr = p * 4 + r0;
            const float v = smem[c][rr];
            const ushort hh = f2bf(v);
            thi[(size_t)(tj * 64 + rr) * 512 + ti * 64 + c] = hh;
            tlo[(size_t)(tj * 64 + rr) * 512 + ti * 64 + c] = f2bf(v - bf2f(hh));
        }
    }
}

// ---------------------------------------------------------------------------
// scan: single block, 10 elems/thread, shfl-scan
// ---------------------------------------------------------------------------
__global__ __launch_bounds__(1024) void scan_kernel(
    const int* __restrict__ counts, int* __restrict__ offs, int n) {
    __shared__ int wsum[16];
    const int tid = threadIdx.x;
    const int lane = tid & 63, wave = tid >> 6;
    const int base = tid * 10;
    int v[10];
    int s = 0;
#pragma unroll
    for (int i = 0; i < 10; i++) {
        v[i] = (base + i < n) ? counts[base + i] : 0;
        s += v[i];
    }
    int ps = s;
#pragma unroll
    for (int o = 1; o < 64; o <<= 1) {
        const int t = __shfl_up(ps, o);
        if (lane >= o) ps += t;
    }
    if (lane == 63) wsum[wave] = ps;
    __syncthreads();
    if (tid < 16) {
        int t = wsum[tid];
#pragma unroll
        for (int o = 1; o < 16; o <<= 1) {
            const int u = __shfl_up(t, o);
            if (tid >= o) t += u;
        }
        wsum[tid] = t;
    }
    __syncthreads();
    const int wbase = (wave > 0) ? wsum[wave - 1] : 0;
    int run = wbase + ps - s;
#pragma unroll
    for (int i = 0; i < 10; i++) {
        if (base + i < n) offs[base + i + 1] = run + v[i];
        run += v[i];
    }
    if (tid == 0) offs[0] = 0;
}

// ---------------------------------------------------------------------------
// kernel 3: fused [GEMM1 32x32x16 + el/er epilogue] + [scatter] by block range.
// gemm blocks: bid < 628 (157 x 4); scatter blocks: the rest (1250).
// scatter is atomic-free (rank trick) and overlaps GEMM compute.
// ---------------------------------------------------------------------------
constexpr int NB_GEMM1 = ((N_NODES + 63) / 64) * 4;      // 628
constexpr int NB_SCAT  = (N_EDGES + 255) / 256;          // 1250

__global__ __launch_bounds__(256) void gemm1_scatter_kernel(
    const ushort* __restrict__ Ahi, const ushort* __restrict__ Alo,
    const ushort* __restrict__ Bhi, const ushort* __restrict__ Blo,
    ushort* __restrict__ Cout, int M,
    const float* __restrict__ attn_l, const float* __restrict__ attn_r,
    float* __restrict__ elp, float* __restrict__ erp,
    const int* __restrict__ src, const int* __restrict__ dst,
    const int* __restrict__ rank, const int* __restrict__ offs,
    int* __restrict__ srcs) {
    constexpr int BM = 64, BN = 128, BK = 32, K = 512, N = 512;

    if ((int)blockIdx.x >= NB_GEMM1) {
        const int i = ((int)blockIdx.x - NB_GEMM1) * 256 + threadIdx.x;
        if (i < N_EDGES) srcs[offs[dst[i]] + rank[i]] = src[i];
        return;
    }

    __shared__ __align__(16) ushort sAhi[BM * BK];
    __shared__ __align__(16) ushort sAlo[BM * BK];
    __shared__ __align__(16) ushort sBhi[BN * BK];
    __shared__ __align__(16) ushort sBlo[BN * BK];

    const int tid = threadIdx.x;
    const int wave = tid >> 6, lane = tid & 63;
    const int m0 = ((int)blockIdx.x >> 2) * BM, n0 = ((int)blockIdx.x & 3) * BN;
    const int wm = wave >> 1, wn = wave & 1;
    const int l31 = lane & 31, lh = lane >> 5;

    const int fb = wave * 1024 + lane * 16;

    int arow = m0 + (fb >> 6);
    if (arow > M - 1) arow = M - 1;
    const size_t abyte = (size_t)arow * (K * 2) + (fb & 63);
    size_t bbyte[2];
#pragma unroll
    for (int r = 0; r < 2; r++) {
        const int f = fb + r * 4096;
        bbyte[r] = (size_t)(n0 + (f >> 6)) * (K * 2) + (f & 63);
    }

    f32x16 acc[2] = {};

    for (int k0 = 0; k0 < K; k0 += BK) {
        __syncthreads();
        const size_t kb = (size_t)k0 * 2;
        gload16((const char*)Ahi + abyte + kb, (char*)sAhi + fb);
        gload16((const char*)Alo + abyte + kb, (char*)sAlo + fb);
#pragma unroll
        for (int r = 0; r < 2; r++) {
            const int f = fb + r * 4096;
            gload16((const char*)Bhi + bbyte[r] + kb, (char*)sBhi + f);
            gload16((const char*)Blo + bbyte[r] + kb, (char*)sBlo + f);
        }
        __syncthreads();

#pragma unroll
        for (int ks = 0; ks < 2; ks++) {
            const int koff = ks * 16 + lh * 8;
            const int arw = wm * 32 + l31;
            const short8 ah = *(const short8*)&sAhi[arw * BK + koff];
            const short8 al = *(const short8*)&sAlo[arw * BK + koff];
            short8 bh[2], bl[2];
#pragma unroll
            for (int ni = 0; ni < 2; ni++) {
                const int brw = wn * 64 + ni * 32 + l31;
                bh[ni] = *(const short8*)&sBhi[brw * BK + koff];
                bl[ni] = *(const short8*)&sBlo[brw * BK + koff];
            }
#pragma unroll
            for (int ni = 0; ni < 2; ni++) {
                acc[ni] = __builtin_amdgcn_mfma_f32_32x32x16_bf16(ah, bh[ni], acc[ni], 0, 0, 0);
                acc[ni] = __builtin_amdgcn_mfma_f32_32x32x16_bf16(ah, bl[ni], acc[ni], 0, 0, 0);
                acc[ni] = __builtin_amdgcn_mfma_f32_32x32x16_bf16(al, bh[ni], acc[ni], 0, 0, 0);
            }
        }
    }

    // C layout (m74/m101): col=lane&31, row=(reg&3)+8*(reg>>2)+4*(lane>>5)
#pragma unroll
    for (int reg = 0; reg < 16; reg++) {
        const int grow = m0 + wm * 32 + (reg & 3) + 8 * (reg >> 2) + 4 * lh;
        if (grow < M) {
#pragma unroll
            for (int ni = 0; ni < 2; ni++) {
                const int gcol = n0 + wn * 64 + ni * 32 + l31;
                Cout[(size_t)grow * N + gcol] = f2bf(acc[ni][reg]);
            }
        }
    }

    const int head = (n0 + wn * 64) >> 6;
    float alv[2], arv[2];
#pragma unroll
    for (int ni = 0; ni < 2; ni++) {
        alv[ni] = attn_l[head * 64 + ni * 32 + l31];
        arv[ni] = attn_r[head * 64 + ni * 32 + l31];
    }
#pragma unroll
    for (int reg = 0; reg < 16; reg++) {
        float pl = acc[0][reg] * alv[0] + acc[1][reg] * alv[1];
        float pr = acc[0][reg] * arv[0] + acc[1][reg] * arv[1];
#pragma unroll
        for (int o = 1; o < 32; o <<= 1) {
            pl += __shfl_xor(pl, o);
            pr += __shfl_xor(pr, o);
        }
        const int grow = m0 + wm * 32 + (reg & 3) + 8 * (reg >> 2) + 4 * lh;
        if (l31 == 0 && grow < M) {
            elp[grow * 8 + head] = pl;
            erp[grow * 8 + head] = pr;
        }
    }
}

// ---------------------------------------------------------------------------
// GEMM2 (layer 2): 16x16x32 bf16x3, BM=64 BN=64, fp32 out.
// ---------------------------------------------------------------------------
__global__ __launch_bounds__(256) void gemm2_kernel(
    const ushort* __restrict__ Ahi, const ushort* __restrict__ Alo,
    const ushort* __restrict__ Bhi, const ushort* __restrict__ Blo,
    float* __restrict__ Cout, int M) {
    constexpr int BM = 64, BN = 64, BK = 32, K = 512, N = 64;
    constexpr int WM = 32, WN = 32, MT_M = 2, MT_N = 2;

    __shared__ __align__(16) ushort sAhi[BM * BK];
    __shared__ __align__(16) ushort sAlo[BM * BK];
    __shared__ __align__(16) ushort sBhi[BN * BK];
    __shared__ __align__(16) ushort sBlo[BN * BK];

    const int tid = threadIdx.x;
    const int wave = tid >> 6, lane = tid & 63;
    const int m0 = blockIdx.x * BM;
    const int wm = wave >> 1, wn = wave & 1;
    const int quad = lane >> 4, l15 = lane & 15;

    const int fb = wave * 1024 + lane * 16;

    int arow = m0 + (fb >> 6);
    if (arow > M - 1) arow = M - 1;
    const size_t abyte = (size_t)arow * (K * 2) + (fb & 63);
    const size_t bbyte = (size_t)(fb >> 6) * (K * 2) + (fb & 63);

    f32x4 acc[MT_M][MT_N] = {};

    for (int k0 = 0; k0 < K; k0 += BK) {
        __syncthreads();
        const size_t kb = (size_t)k0 * 2;
        gload16((const char*)Ahi + abyte + kb, (char*)sAhi + fb);
        gload16((const char*)Alo + abyte + kb, (char*)sAlo + fb);
        gload16((const char*)Bhi + bbyte + kb, (char*)sBhi + fb);
        gload16((const char*)Blo + bbyte + kb, (char*)sBlo + fb);
        __syncthreads();

        short8 ah[MT_M], al[MT_M], bh[MT_N], bl[MT_N];
#pragma unroll
        for (int mi = 0; mi < MT_M; mi++) {
            const int row = wm * WM + mi * 16 + l15;
            ah[mi] = *(const short8*)&sAhi[row * BK + quad * 8];
            al[mi] = *(const short8*)&sAlo[row * BK + quad * 8];
        }
#pragma unroll
        for (int ni = 0; ni < MT_N; ni++) {
            const int row = wn * WN + ni * 16 + l15;
            bh[ni] = *(const short8*)&sBhi[row * BK + quad * 8];
            bl[ni] = *(const short8*)&sBlo[row * BK + quad * 8];
        }
#pragma unroll
        for (int mi = 0; mi < MT_M; mi++)
#pragma unroll
            for (int ni = 0; ni < MT_N; ni++) {
                acc[mi][ni] = __builtin_amdgcn_mfma_f32_16x16x32_bf16(ah[mi], bh[ni], acc[mi][ni], 0, 0, 0);
                acc[mi][ni] = __builtin_amdgcn_mfma_f32_16x16x32_bf16(ah[mi], bl[ni], acc[mi][ni], 0, 0, 0);
                acc[mi][ni] = __builtin_amdgcn_mfma_f32_16x16x32_bf16(al[mi], bh[ni], acc[mi][ni], 0, 0, 0);
            }
    }

#pragma unroll
    for (int mi = 0; mi < MT_M; mi++) {
#pragma unroll
        for (int r = 0; r < 4; r++) {
            const int grow = m0 + wm * WM + mi * 16 + quad * 4 + r;
            if (grow < M) {
#pragma unroll
                for (int ni = 0; ni < MT_N; ni++) {
                    const int gcol = wn * WN + ni * 16 + l15;
                    Cout[(size_t)grow * N + gcol] = acc[mi][ni][r];
                }
            }
        }
    }
}

// ---------------------------------------------------------------------------
// Layer-1 aggregation: one wave per node, 8-deep software pipeline.
// Fused layer-2 logits + bf16 hi/lo split of x1.
// ---------------------------------------------------------------------------
__global__ __launch_bounds__(256) void agg1_kernel(
    const ushort* __restrict__ feat, const float* __restrict__ el,
    const float* __restrict__ er, const int* __restrict__ offs,
    const int* __restrict__ srcs, ushort* __restrict__ xhi, ushort* __restrict__ xlo,
    const float* __restrict__ wl2, const float* __restrict__ wr2,
    float* __restrict__ el2, float* __restrict__ er2) {
    const int tid = threadIdx.x;
    const int wave = tid >> 6, lane = tid & 63;
    const int node = blockIdx.x * 4 + wave;
    const int start = offs[node];
    const int deg = offs[node + 1] - start;
    const int d0 = lane * 8;
    const int myh = lane >> 3;

    if (deg == 0) {
        const ushort4 z = make_ushort4(0, 0, 0, 0);
        *(ushort4*)&xhi[(size_t)node * 512 + d0] = z;
        *(ushort4*)&xhi[(size_t)node * 512 + d0 + 4] = z;
        *(ushort4*)&xlo[(size_t)node * 512 + d0] = z;
        *(ushort4*)&xlo[(size_t)node * 512 + d0 + 4] = z;
        if (lane == 0) { el2[node] = 0.f; er2[node] = 0.f; }
        return;
    }

    const float4 ea = *(const float4*)&er[node * 8];
    const float4 eb = *(const float4*)&er[node * 8 + 4];
    const float er_my = (myh & 4) ? ((myh & 2) ? ((myh & 1) ? eb.w : eb.z)
                                              : ((myh & 1) ? eb.y : eb.x))
                                  : ((myh & 2) ? ((myh & 1) ? ea.w : ea.z)
                                              : ((myh & 1) ? ea.y : ea.x));

    float acc[8];
#pragma unroll
    for (int i = 0; i < 8; i++) acc[i] = 0.f;
    float ws = 0.f;

    for (int base = 0; base < deg; base += 64) {
        const int has = min(64, deg - base);
        const int s = srcs[start + base + min(lane, has - 1)];
        int j = 0;
        for (; j + 8 <= has; j += 8) {
            int sq[8];
#pragma unroll
            for (int q = 0; q < 8; q++) sq[q] = __shfl(s, j + q);
            float eq[8];
#pragma unroll
            for (int q = 0; q < 8; q++) eq[q] = el[sq[q] * 8 + myh];
            short8 uq[8];
#pragma unroll
            for (int q = 0; q < 8; q++)
                uq[q] = *(const short8*)&feat[(size_t)sq[q] * 512 + d0];
            float wq[8];
#pragma unroll
            for (int q = 0; q < 8; q++) wq[q] = __expf(lrelu(eq[q] + er_my));
#pragma unroll
            for (int q = 0; q < 8; q++) {
#pragma unroll
                for (int i = 0; i < 8; i++)
                    acc[i] += wq[q] * bf2f((ushort)uq[q][i]);
                ws += wq[q];
            }
        }
        for (; j < has; j++) {
            const int sj = __shfl(s, j);
            const float w = __expf(lrelu(el[sj * 8 + myh] + er_my));
            const short8 u = *(const short8*)&feat[(size_t)sj * 512 + d0];
#pragma unroll
            for (int i = 0; i < 8; i++)
                acc[i] += w * bf2f((ushort)u[i]);
            ws += w;
        }
    }

    const float inv = 1.f / ws;
    float o[8];
#pragma unroll
    for (int i = 0; i < 8; i++) o[i] = elu(acc[i] * inv);

    const float4 wla = *(const float4*)&wl2[d0];
    const float4 wlb = *(const float4*)&wl2[d0 + 4];
    const float4 wra = *(const float4*)&wr2[d0];
    const float4 wrb = *(const float4*)&wr2[d0 + 4];
    float pl = o[0] * wla.x + o[1] * wla.y + o[2] * wla.z + o[3] * wla.w
             + o[4] * wlb.x + o[5] * wlb.y + o[6] * wlb.z + o[7] * wlb.w;
    float pr = o[0] * wra.x + o[1] * wra.y + o[2] * wra.z + o[3] * wra.w
             + o[4] * wrb.x + o[5] * wrb.y + o[6] * wrb.z + o[7] * wrb.w;
#pragma unroll
    for (int off = 32; off > 0; off >>= 1) {
        pl += __shfl_xor(pl, off);
        pr += __shfl_xor(pr, off);
    }
    if (lane == 0) { el2[node] = pl; er2[node] = pr; }

    ushort hi[8], lo[8];
#pragma unroll
    for (int i = 0; i < 8; i++) {
        hi[i] = f2bf(o[i]);
        lo[i] = f2bf(o[i] - bf2f(hi[i]));
    }
    *(ushort4*)&xhi[(size_t)node * 512 + d0]     = make_ushort4(hi[0], hi[1], hi[2], hi[3]);
    *(ushort4*)&xhi[(size_t)node * 512 + d0 + 4] = make_ushort4(hi[4], hi[5], hi[6], hi[7]);
    *(ushort4*)&xlo[(size_t)node * 512 + d0]     = make_ushort4(lo[0], lo[1], lo[2], lo[3]);
    *(ushort4*)&xlo[(size_t)node * 512 + d0 + 4] = make_ushort4(lo[4], lo[5], lo[6], lo[7]);
}

// ---------------------------------------------------------------------------
// Layer-2 aggregation: one wave per node, 8-deep pipeline.
// ---------------------------------------------------------------------------
__global__ __launch_bounds__(256) void agg2_kernel(
    const float* __restrict__ feat, const float* __restrict__ el,
    const float* __restrict__ er, const int* __restrict__ offs,
    const int* __restrict__ srcs, float* __restrict__ out) {
    const int tid = threadIdx.x;
    const int wave = tid >> 6, lane = tid & 63;
    const int node = blockIdx.x * 4 + wave;
    const int start = offs[node];
    const int deg = offs[node + 1] - start;
    if (deg == 0) { out[(size_t)node * 64 + lane] = 0.f; return; }
    const float ern = er[node];

    float acc = 0.f, ws = 0.f;
    for (int base = 0; base < deg; base += 64) {
        const int has = min(64, deg - base);
        const int s = srcs[start + base + min(lane, has - 1)];
        const float w = __expf(lrelu(el[s] + ern));
        int j = 0;
        for (; j + 8 <= has; j += 8) {
            float aq[8]; int sq[8];
#pragma unroll
            for (int q = 0; q < 8; q++) { aq[q] = __shfl(w, j + q); sq[q] = __shfl(s, j + q); }
            float fq[8];
#pragma unroll
            for (int q = 0; q < 8; q++) fq[q] = feat[(size_t)sq[q] * 64 + lane];
#pragma unroll
            for (int q = 0; q < 8; q++) { acc += aq[q] * fq[q]; ws += aq[q]; }
        }
        for (; j < has; j++) {
            const float a = __shfl(w, j);
            const int sj = __shfl(s, j);
            acc += a * feat[(size_t)sj * 64 + lane];
            ws += a;
        }
    }
    out[(size_t)node * 64 + lane] = acc / ws;
}

// ---------------------------------------------------------------------------
extern "C" void kernel_launch(void* const* d_in, const int* in_sizes, int n_in,
                              void* d_out, int out_size, void* d_ws, size_t ws_size,
                              hipStream_t stream) {
    const float* h   = (const float*)d_in[0];
    const int*   src = (const int*)d_in[1];
    const int*   dst = (const int*)d_in[2];
    const float* W1  = (const float*)d_in[3];
    const float* al1 = (const float*)d_in[4];
    const float* ar1 = (const float*)d_in[5];
    const float* W2  = (const float*)d_in[6];
    const float* al2 = (const float*)d_in[7];
    const float* ar2 = (const float*)d_in[8];
    float* out = (float*)d_out;

    // workspace carve (16B-aligned chunks)
    char* p = (char*)d_ws;
    ushort* feat1bf = (ushort*)p; p += (size_t)N_NODES * 512 * 2;  // 10.24 MB
    float* feat2 = (float*)p;  p += (size_t)N_NODES * 64 * 4;      // 2.56 MB
    float* el1   = (float*)p;  p += (size_t)N_NODES * 8 * 4;
    float* er1   = (float*)p;  p += (size_t)N_NODES * 8 * 4;
    float* el2   = (float*)p;  p += (size_t)N_NODES * 4;
    float* er2   = (float*)p;  p += (size_t)N_NODES * 4;
    ushort* xhi  = (ushort*)p; p += (size_t)N_NODES * 512 * 2;     // h_hi -> x1_hi
    ushort* xlo  = (ushort*)p; p += (size_t)N_NODES * 512 * 2;     // h_lo -> x1_lo
    ushort* w1thi = (ushort*)p; p += (size_t)512 * 512 * 2;
    ushort* w1tlo = (ushort*)p; p += (size_t)512 * 512 * 2;
    ushort* w2thi = (ushort*)p; p += (size_t)64 * 512 * 2;
    ushort* w2tlo = (ushort*)p; p += (size_t)64 * 512 * 2;
    float* wl2   = (float*)p;  p += (size_t)512 * 4;
    float* wr2   = (float*)p;  p += (size_t)512 * 4;
    int* counts  = (int*)p;    p += (size_t)N_NODES * 4;
    int* offs    = (int*)p;    p += (size_t)10004 * 4;
    int* rank    = (int*)p;    p += (size_t)N_EDGES * 4;
    int* srcs    = (int*)p;    p += (size_t)N_EDGES * 4;

    // 0: zero counts + wl2/wr2
    zero_kernel<<<NBZ_CNT + 2, 256, 0, stream>>>(counts, W2, al2, ar2, wl2, wr2);

    // 1: fused hist + split/transpose prep
    prep_kernel<<<NB_HIST + NB_SPLIT + NB_T1 + NB_T2, 256, 0, stream>>>(
        (const float4*)h, xhi, xlo, W1, w1thi, w1tlo, W2, w2thi, w2tlo,
        dst, counts, rank);

    // 2: scan
    scan_kernel<<<1, 1024, 0, stream>>>(counts, offs, N_NODES);

    // 3: fused GEMM1(+el/er) + scatter
    gemm1_scatter_kernel<<<NB_GEMM1 + NB_SCAT, 256, 0, stream>>>(
        xhi, xlo, w1thi, w1tlo, feat1bf, N_NODES, al1, ar1, el1, er1,
        src, dst, rank, offs, srcs);

    // 4: layer-1 aggregation (+ fused layer-2 logits)
    agg1_kernel<<<N_NODES / 4, 256, 0, stream>>>(
        feat1bf, el1, er1, offs, srcs, xhi, xlo, wl2, wr2, el2, er2);

    // 5: layer-2 GEMM
    gemm2_kernel<<<(N_NODES + 63) / 64, 256, 0, stream>>>(
        xhi, xlo, w2thi, w2tlo, feat2, N_NODES);

    // 6: layer-2 aggregation -> out
    agg2_kernel<<<N_NODES / 4, 256, 0, stream>>>(feat2, el2, er2, offs, srcs, out);
}

// Round 9
// 209.512 us; speedup vs baseline: 1.6884x; 1.0189x over previous
//
#include <hip/hip_runtime.h>
#include <hip/hip_bf16.h>
#include <math.h>

typedef unsigned int u32;
typedef unsigned short ushort;

constexpr int N_NODES = 10000;
constexpr int N_EDGES = 320000;
constexpr float NEG_SLOPE = 0.2f;

typedef __attribute__((ext_vector_type(8))) short short8;    // 8 x bf16 bits
typedef __attribute__((ext_vector_type(4))) float f32x4;
typedef __attribute__((ext_vector_type(16))) float f32x16;

// ---------------------------------------------------------------------------
// helpers
// ---------------------------------------------------------------------------
__device__ __forceinline__ float lrelu(float x) { return x > 0.f ? x : NEG_SLOPE * x; }
__device__ __forceinline__ float elu(float x)   { return x > 0.f ? x : (expf(x) - 1.f); }

__device__ __forceinline__ ushort f2bf(float x) {
    u32 b = __float_as_uint(x);
    b += 0x7FFFu + ((b >> 16) & 1u);
    return (ushort)(b >> 16);
}
__device__ __forceinline__ float bf2f(ushort u) {
    return __uint_as_float(((u32)u) << 16);
}

__device__ __forceinline__ void gload16(const void* g, void* l) {
    __builtin_amdgcn_global_load_lds(
        (__attribute__((address_space(1))) void*)g,
        (__attribute__((address_space(3))) void*)l, 16, 0, 0);
}

// ---------------------------------------------------------------------------
// kernel 0: zero counts + wl2/wr2 precompute
// ---------------------------------------------------------------------------
constexpr int NBZ_CNT = (N_NODES + 255) / 256;   // 40
__global__ void zero_kernel(int* __restrict__ counts,
                            const float* __restrict__ W2,
                            const float* __restrict__ al2, const float* __restrict__ ar2,
                            float* __restrict__ wl2, float* __restrict__ wr2) {
    const int b = blockIdx.x;
    if (b < NBZ_CNT) {
        const int j = b * 256 + threadIdx.x;
        if (j < N_NODES) counts[j] = 0;
    } else {
        const int k = (b - NBZ_CNT) * 256 + threadIdx.x;  // [0,512)
        float sl = 0.f, sr = 0.f;
#pragma unroll 8
        for (int d = 0; d < 64; d++) {
            const float w = W2[(size_t)k * 64 + d];
            sl += w * al2[d];
            sr += w * ar2[d];
        }
        wl2[k] = sl;
        wr2[k] = sr;
    }
}

// ---------------------------------------------------------------------------
// kernel 1: fused [hist(+rank)] + [split h] + [transpose+split W1 (hi/lo)]
//           + [transpose W2 (hi only — layer 2 runs pure bf16)]
// ---------------------------------------------------------------------------
constexpr int NB_SPLIT = (N_NODES * 512 / 4) / 256;      // 5000
constexpr int NB_T1    = 64;                             // W1: 8x8 tiles of 64x64
constexpr int NB_T2    = 8;                              // W2: 8x1 tiles
constexpr int NB_HIST  = (N_EDGES + 255) / 256;          // 1250

__global__ void prep_kernel(const float4* __restrict__ h4,
                            ushort* __restrict__ hhi, ushort* __restrict__ hlo,
                            const float* __restrict__ W1,
                            ushort* __restrict__ w1thi, ushort* __restrict__ w1tlo,
                            const float* __restrict__ W2,
                            ushort* __restrict__ w2thi,
                            const int* __restrict__ dst, int* __restrict__ counts,
                            int* __restrict__ rank) {
    __shared__ float smem[64][65];
    const int b = blockIdx.x;
    if (b < NB_HIST) {
        const int i = b * 256 + threadIdx.x;
        if (i < N_EDGES) rank[i] = atomicAdd(&counts[dst[i]], 1);
    } else if (b < NB_HIST + NB_SPLIT) {
        const int i = (b - NB_HIST) * 256 + threadIdx.x;
        const float4 v = h4[i];
        ushort h0 = f2bf(v.x), h1 = f2bf(v.y), h2 = f2bf(v.z), h3 = f2bf(v.w);
        *(ushort4*)&hhi[i * 4] = make_ushort4(h0, h1, h2, h3);
        *(ushort4*)&hlo[i * 4] = make_ushort4(
            f2bf(v.x - bf2f(h0)), f2bf(v.y - bf2f(h1)),
            f2bf(v.z - bf2f(h2)), f2bf(v.w - bf2f(h3)));
    } else {
        const bool isW1 = b < NB_HIST + NB_SPLIT + NB_T1;
        const float* W = isW1 ? W1 : W2;
        const int N  = isW1 ? 512 : 64;
        const int t  = isW1 ? (b - NB_HIST - NB_SPLIT) : (b - NB_HIST - NB_SPLIT - NB_T1);
        const int ti = isW1 ? (t & 7) : t;    // K-tile
        const int tj = isW1 ? (t >> 3) : 0;   // N-tile
        const int c  = threadIdx.x & 63;
        const int r0 = threadIdx.x >> 6;      // 0..3
#pragma unroll
        for (int p = 0; p < 16; p++) {
            const int r = p * 4 + r0;
            smem[r][c] = W[(size_t)(ti * 64 + r) * N + tj * 64 + c];
        }
        __syncthreads();
        if (isW1) {
#pragma unroll
            for (int p = 0; p < 16; p++) {
                const int rr = p * 4 + r0;
                const float v = smem[c][rr];
                const ushort hh = f2bf(v);
                w1thi[(size_t)(tj * 64 + rr) * 512 + ti * 64 + c] = hh;
                w1tlo[(size_t)(tj * 64 + rr) * 512 + ti * 64 + c] = f2bf(v - bf2f(hh));
            }
        } else {
#pragma unroll
            for (int p = 0; p < 16; p++) {
                const int rr = p * 4 + r0;
                w2thi[(size_t)(tj * 64 + rr) * 512 + ti * 64 + c] = f2bf(smem[c][rr]);
            }
        }
    }
}

// ---------------------------------------------------------------------------
// scan: single block, 10 elems/thread, shfl-scan
// ---------------------------------------------------------------------------
__global__ __launch_bounds__(1024) void scan_kernel(
    const int* __restrict__ counts, int* __restrict__ offs, int n) {
    __shared__ int wsum[16];
    const int tid = threadIdx.x;
    const int lane = tid & 63, wave = tid >> 6;
    const int base = tid * 10;
    int v[10];
    int s = 0;
#pragma unroll
    for (int i = 0; i < 10; i++) {
        v[i] = (base + i < n) ? counts[base + i] : 0;
        s += v[i];
    }
    int ps = s;
#pragma unroll
    for (int o = 1; o < 64; o <<= 1) {
        const int t = __shfl_up(ps, o);
        if (lane >= o) ps += t;
    }
    if (lane == 63) wsum[wave] = ps;
    __syncthreads();
    if (tid < 16) {
        int t = wsum[tid];
#pragma unroll
        for (int o = 1; o < 16; o <<= 1) {
            const int u = __shfl_up(t, o);
            if (tid >= o) t += u;
        }
        wsum[tid] = t;
    }
    __syncthreads();
    const int wbase = (wave > 0) ? wsum[wave - 1] : 0;
    int run = wbase + ps - s;
#pragma unroll
    for (int i = 0; i < 10; i++) {
        if (base + i < n) offs[base + i + 1] = run + v[i];
        run += v[i];
    }
    if (tid == 0) offs[0] = 0;
}

// ---------------------------------------------------------------------------
// kernel 3: fused [GEMM1 32x32x16 bf16x3 + el/er epilogue] + [scatter].
// ---------------------------------------------------------------------------
constexpr int NB_GEMM1 = ((N_NODES + 63) / 64) * 4;      // 628
constexpr int NB_SCAT  = (N_EDGES + 255) / 256;          // 1250

__global__ __launch_bounds__(256) void gemm1_scatter_kernel(
    const ushort* __restrict__ Ahi, const ushort* __restrict__ Alo,
    const ushort* __restrict__ Bhi, const ushort* __restrict__ Blo,
    ushort* __restrict__ Cout, int M,
    const float* __restrict__ attn_l, const float* __restrict__ attn_r,
    float* __restrict__ elp, float* __restrict__ erp,
    const int* __restrict__ src, const int* __restrict__ dst,
    const int* __restrict__ rank, const int* __restrict__ offs,
    int* __restrict__ srcs) {
    constexpr int BM = 64, BN = 128, BK = 32, K = 512, N = 512;

    if ((int)blockIdx.x >= NB_GEMM1) {
        const int i = ((int)blockIdx.x - NB_GEMM1) * 256 + threadIdx.x;
        if (i < N_EDGES) srcs[offs[dst[i]] + rank[i]] = src[i];
        return;
    }

    __shared__ __align__(16) ushort sAhi[BM * BK];
    __shared__ __align__(16) ushort sAlo[BM * BK];
    __shared__ __align__(16) ushort sBhi[BN * BK];
    __shared__ __align__(16) ushort sBlo[BN * BK];

    const int tid = threadIdx.x;
    const int wave = tid >> 6, lane = tid & 63;
    const int m0 = ((int)blockIdx.x >> 2) * BM, n0 = ((int)blockIdx.x & 3) * BN;
    const int wm = wave >> 1, wn = wave & 1;
    const int l31 = lane & 31, lh = lane >> 5;

    const int fb = wave * 1024 + lane * 16;

    int arow = m0 + (fb >> 6);
    if (arow > M - 1) arow = M - 1;
    const size_t abyte = (size_t)arow * (K * 2) + (fb & 63);
    size_t bbyte[2];
#pragma unroll
    for (int r = 0; r < 2; r++) {
        const int f = fb + r * 4096;
        bbyte[r] = (size_t)(n0 + (f >> 6)) * (K * 2) + (f & 63);
    }

    f32x16 acc[2] = {};

    for (int k0 = 0; k0 < K; k0 += BK) {
        __syncthreads();
        const size_t kb = (size_t)k0 * 2;
        gload16((const char*)Ahi + abyte + kb, (char*)sAhi + fb);
        gload16((const char*)Alo + abyte + kb, (char*)sAlo + fb);
#pragma unroll
        for (int r = 0; r < 2; r++) {
            const int f = fb + r * 4096;
            gload16((const char*)Bhi + bbyte[r] + kb, (char*)sBhi + f);
            gload16((const char*)Blo + bbyte[r] + kb, (char*)sBlo + f);
        }
        __syncthreads();

#pragma unroll
        for (int ks = 0; ks < 2; ks++) {
            const int koff = ks * 16 + lh * 8;
            const int arw = wm * 32 + l31;
            const short8 ah = *(const short8*)&sAhi[arw * BK + koff];
            const short8 al = *(const short8*)&sAlo[arw * BK + koff];
            short8 bh[2], bl[2];
#pragma unroll
            for (int ni = 0; ni < 2; ni++) {
                const int brw = wn * 64 + ni * 32 + l31;
                bh[ni] = *(const short8*)&sBhi[brw * BK + koff];
                bl[ni] = *(const short8*)&sBlo[brw * BK + koff];
            }
#pragma unroll
            for (int ni = 0; ni < 2; ni++) {
                acc[ni] = __builtin_amdgcn_mfma_f32_32x32x16_bf16(ah, bh[ni], acc[ni], 0, 0, 0);
                acc[ni] = __builtin_amdgcn_mfma_f32_32x32x16_bf16(ah, bl[ni], acc[ni], 0, 0, 0);
                acc[ni] = __builtin_amdgcn_mfma_f32_32x32x16_bf16(al, bh[ni], acc[ni], 0, 0, 0);
            }
        }
    }

    // C layout (m74/m101): col=lane&31, row=(reg&3)+8*(reg>>2)+4*(lane>>5)
#pragma unroll
    for (int reg = 0; reg < 16; reg++) {
        const int grow = m0 + wm * 32 + (reg & 3) + 8 * (reg >> 2) + 4 * lh;
        if (grow < M) {
#pragma unroll
            for (int ni = 0; ni < 2; ni++) {
                const int gcol = n0 + wn * 64 + ni * 32 + l31;
                Cout[(size_t)grow * N + gcol] = f2bf(acc[ni][reg]);
            }
        }
    }

    const int head = (n0 + wn * 64) >> 6;
    float alv[2], arv[2];
#pragma unroll
    for (int ni = 0; ni < 2; ni++) {
        alv[ni] = attn_l[head * 64 + ni * 32 + l31];
        arv[ni] = attn_r[head * 64 + ni * 32 + l31];
    }
#pragma unroll
    for (int reg = 0; reg < 16; reg++) {
        float pl = acc[0][reg] * alv[0] + acc[1][reg] * alv[1];
        float pr = acc[0][reg] * arv[0] + acc[1][reg] * arv[1];
#pragma unroll
        for (int o = 1; o < 32; o <<= 1) {
            pl += __shfl_xor(pl, o);
            pr += __shfl_xor(pr, o);
        }
        const int grow = m0 + wm * 32 + (reg & 3) + 8 * (reg >> 2) + 4 * lh;
        if (l31 == 0 && grow < M) {
            elp[grow * 8 + head] = pl;
            erp[grow * 8 + head] = pr;
        }
    }
}

// ---------------------------------------------------------------------------
// GEMM2 (layer 2): PURE bf16 (hi-only), 16x16x32, BM=64 BN=64, fp32 out.
// Error budget: hi-only x1 and W2 each add ~1e-3 to feat2 (absmax margin 2x).
// ---------------------------------------------------------------------------
__global__ __launch_bounds__(256) void gemm2_kernel(
    const ushort* __restrict__ Ahi, const ushort* __restrict__ Bhi,
    float* __restrict__ Cout, int M) {
    constexpr int BM = 64, BN = 64, BK = 32, K = 512, N = 64;
    constexpr int WM = 32, WN = 32, MT_M = 2, MT_N = 2;

    __shared__ __align__(16) ushort sA[BM * BK];
    __shared__ __align__(16) ushort sB[BN * BK];

    const int tid = threadIdx.x;
    const int wave = tid >> 6, lane = tid & 63;
    const int m0 = blockIdx.x * BM;
    const int wm = wave >> 1, wn = wave & 1;
    const int quad = lane >> 4, l15 = lane & 15;

    const int fb = wave * 1024 + lane * 16;

    int arow = m0 + (fb >> 6);
    if (arow > M - 1) arow = M - 1;
    const size_t abyte = (size_t)arow * (K * 2) + (fb & 63);
    const size_t bbyte = (size_t)(fb >> 6) * (K * 2) + (fb & 63);

    f32x4 acc[MT_M][MT_N] = {};

    for (int k0 = 0; k0 < K; k0 += BK) {
        __syncthreads();
        const size_t kb = (size_t)k0 * 2;
        gload16((const char*)Ahi + abyte + kb, (char*)sA + fb);
        gload16((const char*)Bhi + bbyte + kb, (char*)sB + fb);
        __syncthreads();

        short8 ah[MT_M], bh[MT_N];
#pragma unroll
        for (int mi = 0; mi < MT_M; mi++) {
            const int row = wm * WM + mi * 16 + l15;
            ah[mi] = *(const short8*)&sA[row * BK + quad * 8];
        }
#pragma unroll
        for (int ni = 0; ni < MT_N; ni++) {
            const int row = wn * WN + ni * 16 + l15;
            bh[ni] = *(const short8*)&sB[row * BK + quad * 8];
        }
#pragma unroll
        for (int mi = 0; mi < MT_M; mi++)
#pragma unroll
            for (int ni = 0; ni < MT_N; ni++)
                acc[mi][ni] = __builtin_amdgcn_mfma_f32_16x16x32_bf16(ah[mi], bh[ni], acc[mi][ni], 0, 0, 0);
    }

#pragma unroll
    for (int mi = 0; mi < MT_M; mi++) {
#pragma unroll
        for (int r = 0; r < 4; r++) {
            const int grow = m0 + wm * WM + mi * 16 + quad * 4 + r;
            if (grow < M) {
#pragma unroll
                for (int ni = 0; ni < MT_N; ni++) {
                    const int gcol = wn * WN + ni * 16 + l15;
                    Cout[(size_t)grow * N + gcol] = acc[mi][ni][r];
                }
            }
        }
    }
}

// ---------------------------------------------------------------------------
// Layer-1 aggregation: one wave per node, 8-deep pipeline. Fused layer-2
// logits (fp32) + bf16 x1 write (hi only — layer 2 is pure bf16).
// ---------------------------------------------------------------------------
__global__ __launch_bounds__(256) void agg1_kernel(
    const ushort* __restrict__ feat, const float* __restrict__ el,
    const float* __restrict__ er, const int* __restrict__ offs,
    const int* __restrict__ srcs, ushort* __restrict__ xhi,
    const float* __restrict__ wl2, const float* __restrict__ wr2,
    float* __restrict__ el2, float* __restrict__ er2) {
    const int tid = threadIdx.x;
    const int wave = tid >> 6, lane = tid & 63;
    const int node = blockIdx.x * 4 + wave;
    const int start = offs[node];
    const int deg = offs[node + 1] - start;
    const int d0 = lane * 8;
    const int myh = lane >> 3;

    if (deg == 0) {
        const ushort4 z = make_ushort4(0, 0, 0, 0);
        *(ushort4*)&xhi[(size_t)node * 512 + d0] = z;
        *(ushort4*)&xhi[(size_t)node * 512 + d0 + 4] = z;
        if (lane == 0) { el2[node] = 0.f; er2[node] = 0.f; }
        return;
    }

    const float4 ea = *(const float4*)&er[node * 8];
    const float4 eb = *(const float4*)&er[node * 8 + 4];
    const float er_my = (myh & 4) ? ((myh & 2) ? ((myh & 1) ? eb.w : eb.z)
                                              : ((myh & 1) ? eb.y : eb.x))
                                  : ((myh & 2) ? ((myh & 1) ? ea.w : ea.z)
                                              : ((myh & 1) ? ea.y : ea.x));

    float acc[8];
#pragma unroll
    for (int i = 0; i < 8; i++) acc[i] = 0.f;
    float ws = 0.f;

    for (int base = 0; base < deg; base += 64) {
        const int has = min(64, deg - base);
        const int s = srcs[start + base + min(lane, has - 1)];
        int j = 0;
        for (; j + 8 <= has; j += 8) {
            int sq[8];
#pragma unroll
            for (int q = 0; q < 8; q++) sq[q] = __shfl(s, j + q);
            float eq[8];
#pragma unroll
            for (int q = 0; q < 8; q++) eq[q] = el[sq[q] * 8 + myh];
            short8 uq[8];
#pragma unroll
            for (int q = 0; q < 8; q++)
                uq[q] = *(const short8*)&feat[(size_t)sq[q] * 512 + d0];
            float wq[8];
#pragma unroll
            for (int q = 0; q < 8; q++) wq[q] = __expf(lrelu(eq[q] + er_my));
#pragma unroll
            for (int q = 0; q < 8; q++) {
#pragma unroll
                for (int i = 0; i < 8; i++)
                    acc[i] += wq[q] * bf2f((ushort)uq[q][i]);
                ws += wq[q];
            }
        }
        for (; j < has; j++) {
            const int sj = __shfl(s, j);
            const float w = __expf(lrelu(el[sj * 8 + myh] + er_my));
            const short8 u = *(const short8*)&feat[(size_t)sj * 512 + d0];
#pragma unroll
            for (int i = 0; i < 8; i++)
                acc[i] += w * bf2f((ushort)u[i]);
            ws += w;
        }
    }

    const float inv = 1.f / ws;
    float o[8];
#pragma unroll
    for (int i = 0; i < 8; i++) o[i] = elu(acc[i] * inv);

    const float4 wla = *(const float4*)&wl2[d0];
    const float4 wlb = *(const float4*)&wl2[d0 + 4];
    const float4 wra = *(const float4*)&wr2[d0];
    const float4 wrb = *(const float4*)&wr2[d0 + 4];
    float pl = o[0] * wla.x + o[1] * wla.y + o[2] * wla.z + o[3] * wla.w
             + o[4] * wlb.x + o[5] * wlb.y + o[6] * wlb.z + o[7] * wlb.w;
    float pr = o[0] * wra.x + o[1] * wra.y + o[2] * wra.z + o[3] * wra.w
             + o[4] * wrb.x + o[5] * wrb.y + o[6] * wrb.z + o[7] * wrb.w;
#pragma unroll
    for (int off = 32; off > 0; off >>= 1) {
        pl += __shfl_xor(pl, off);
        pr += __shfl_xor(pr, off);
    }
    if (lane == 0) { el2[node] = pl; er2[node] = pr; }

    ushort hi[8];
#pragma unroll
    for (int i = 0; i < 8; i++) hi[i] = f2bf(o[i]);
    *(ushort4*)&xhi[(size_t)node * 512 + d0]     = make_ushort4(hi[0], hi[1], hi[2], hi[3]);
    *(ushort4*)&xhi[(size_t)node * 512 + d0 + 4] = make_ushort4(hi[4], hi[5], hi[6], hi[7]);
}

// ---------------------------------------------------------------------------
// Layer-2 aggregation: one wave per node, 8-deep pipeline.
// ---------------------------------------------------------------------------
__global__ __launch_bounds__(256) void agg2_kernel(
    const float* __restrict__ feat, const float* __restrict__ el,
    const float* __restrict__ er, const int* __restrict__ offs,
    const int* __restrict__ srcs, float* __restrict__ out) {
    const int tid = threadIdx.x;
    const int wave = tid >> 6, lane = tid & 63;
    const int node = blockIdx.x * 4 + wave;
    const int start = offs[node];
    const int deg = offs[node + 1] - start;
    if (deg == 0) { out[(size_t)node * 64 + lane] = 0.f; return; }
    const float ern = er[node];

    float acc = 0.f, ws = 0.f;
    for (int base = 0; base < deg; base += 64) {
        const int has = min(64, deg - base);
        const int s = srcs[start + base + min(lane, has - 1)];
        const float w = __expf(lrelu(el[s] + ern));
        int j = 0;
        for (; j + 8 <= has; j += 8) {
            float aq[8]; int sq[8];
#pragma unroll
            for (int q = 0; q < 8; q++) { aq[q] = __shfl(w, j + q); sq[q] = __shfl(s, j + q); }
            float fq[8];
#pragma unroll
            for (int q = 0; q < 8; q++) fq[q] = feat[(size_t)sq[q] * 64 + lane];
#pragma unroll
            for (int q = 0; q < 8; q++) { acc += aq[q] * fq[q]; ws += aq[q]; }
        }
        for (; j < has; j++) {
            const float a = __shfl(w, j);
            const int sj = __shfl(s, j);
            acc += a * feat[(size_t)sj * 64 + lane];
            ws += a;
        }
    }
    out[(size_t)node * 64 + lane] = acc / ws;
}

// ---------------------------------------------------------------------------
extern "C" void kernel_launch(void* const* d_in, const int* in_sizes, int n_in,
                              void* d_out, int out_size, void* d_ws, size_t ws_size,
                              hipStream_t stream) {
    const float* h   = (const float*)d_in[0];
    const int*   src = (const int*)d_in[1];
    const int*   dst = (const int*)d_in[2];
    const float* W1  = (const float*)d_in[3];
    const float* al1 = (const float*)d_in[4];
    const float* ar1 = (const float*)d_in[5];
    const float* W2  = (const float*)d_in[6];
    const float* al2 = (const float*)d_in[7];
    const float* ar2 = (const float*)d_in[8];
    float* out = (float*)d_out;

    // workspace carve (16B-aligned chunks)
    char* p = (char*)d_ws;
    ushort* feat1bf = (ushort*)p; p += (size_t)N_NODES * 512 * 2;  // 10.24 MB
    float* feat2 = (float*)p;  p += (size_t)N_NODES * 64 * 4;      // 2.56 MB
    float* el1   = (float*)p;  p += (size_t)N_NODES * 8 * 4;
    float* er1   = (float*)p;  p += (size_t)N_NODES * 8 * 4;
    float* el2   = (float*)p;  p += (size_t)N_NODES * 4;
    float* er2   = (float*)p;  p += (size_t)N_NODES * 4;
    ushort* xhi  = (ushort*)p; p += (size_t)N_NODES * 512 * 2;     // h_hi -> x1_hi
    ushort* xlo  = (ushort*)p; p += (size_t)N_NODES * 512 * 2;     // h_lo (layer 1 only)
    ushort* w1thi = (ushort*)p; p += (size_t)512 * 512 * 2;
    ushort* w1tlo = (ushort*)p; p += (size_t)512 * 512 * 2;
    ushort* w2thi = (ushort*)p; p += (size_t)64 * 512 * 2;
    float* wl2   = (float*)p;  p += (size_t)512 * 4;
    float* wr2   = (float*)p;  p += (size_t)512 * 4;
    int* counts  = (int*)p;    p += (size_t)N_NODES * 4;
    int* offs    = (int*)p;    p += (size_t)10004 * 4;
    int* rank    = (int*)p;    p += (size_t)N_EDGES * 4;
    int* srcs    = (int*)p;    p += (size_t)N_EDGES * 4;

    // 0: zero counts + wl2/wr2
    zero_kernel<<<NBZ_CNT + 2, 256, 0, stream>>>(counts, W2, al2, ar2, wl2, wr2);

    // 1: fused hist + split/transpose prep
    prep_kernel<<<NB_HIST + NB_SPLIT + NB_T1 + NB_T2, 256, 0, stream>>>(
        (const float4*)h, xhi, xlo, W1, w1thi, w1tlo, W2, w2thi,
        dst, counts, rank);

    // 2: scan
    scan_kernel<<<1, 1024, 0, stream>>>(counts, offs, N_NODES);

    // 3: fused GEMM1(+el/er) + scatter
    gemm1_scatter_kernel<<<NB_GEMM1 + NB_SCAT, 256, 0, stream>>>(
        xhi, xlo, w1thi, w1tlo, feat1bf, N_NODES, al1, ar1, el1, er1,
        src, dst, rank, offs, srcs);

    // 4: layer-1 aggregation (+ fused layer-2 logits); x1 -> xhi (bf16)
    agg1_kernel<<<N_NODES / 4, 256, 0, stream>>>(
        feat1bf, el1, er1, offs, srcs, xhi, wl2, wr2, el2, er2);

    // 5: layer-2 GEMM (pure bf16)
    gemm2_kernel<<<(N_NODES + 63) / 64, 256, 0, stream>>>(
        xhi, w2thi, feat2, N_NODES);

    // 6: layer-2 aggregation -> out
    agg2_kernel<<<N_NODES / 4, 256, 0, stream>>>(feat2, el2, er2, offs, srcs, out);
}